// Round 14
// baseline (678.711 us; speedup 1.0000x reference)
//
#include <hip/hip_runtime.h>
#include <stdint.h>
#include <math.h>

typedef __attribute__((ext_vector_type(8))) short s8v;
typedef __attribute__((ext_vector_type(4))) short s4v;
typedef __attribute__((ext_vector_type(4))) float f4v;

#define DEV static __device__ __forceinline__

DEV short f2bf(float f) {
  uint32_t u = __builtin_bit_cast(uint32_t, f);
  u += 0x7FFFu + ((u >> 16) & 1u);   // round-to-nearest-even
  return (short)(u >> 16);
}
DEV float bf2f(short s) {
  uint32_t u = ((uint32_t)(uint16_t)s) << 16;
  return __builtin_bit_cast(float, u);
}

#define GLD16(g, l) __builtin_amdgcn_global_load_lds( \
    (const __attribute__((address_space(1))) void*)(g), \
    (__attribute__((address_space(3))) void*)(l), 16, 0, 0)

// ================= 128x128 GEMM (m97 structure) for small/odd/batched shapes =========
__global__ __launch_bounds__(256) void gemm_bt(
    const short* __restrict__ A, const short* __restrict__ B,
    float* Cf, short* Cb,
    const float* __restrict__ bias, const float* resid,
    int M, int N, int K, int lda, int ldb, int ldc,
    long long sAo, long long sAi, long long sBo, long long sBi,
    long long sCo, long long sCi, float alpha, int relu)
{
  __shared__ __align__(16) short lA[128*32];
  __shared__ __align__(16) short lB[128*32];
  const int z = blockIdx.z, zo = z >> 3, zi = z & 7;
  const short* Ab = A + zo*sAo + zi*sAi;
  const short* Bb = B + zo*sBo + zi*sBi;
  const long long cOff = zo*sCo + zi*sCi;

  const int m0 = blockIdx.y*128, n0 = blockIdx.x*128;
  const int tid = threadIdx.x, lane = tid & 63, wv = tid >> 6;
  const int wm = (wv >> 1)*64, wn = (wv & 1)*64;
  const int fr = lane & 15, fq = lane >> 4;

  f4v acc[4][4] = {};

  const int rA0 = min(m0 + (tid >> 2), M - 1);
  const int rA1 = min(m0 + 64 + (tid >> 2), M - 1);
  const int rB0 = min(n0 + (tid >> 2), N - 1);
  const int rB1 = min(n0 + 64 + (tid >> 2), N - 1);
  const int pc = (tid & 3) * 8;
  const short* gA0 = Ab + (size_t)rA0*lda + pc;
  const short* gA1 = Ab + (size_t)rA1*lda + pc;
  const short* gB0 = Bb + (size_t)rB0*ldb + pc;
  const short* gB1 = Bb + (size_t)rB1*ldb + pc;
  short* dA0 = lA + (wv*64)*8;
  short* dA1 = lA + (256 + wv*64)*8;
  short* dB0 = lB + (wv*64)*8;
  short* dB1 = lB + (256 + wv*64)*8;

  for (int k0 = 0; k0 < K; k0 += 32) {
    GLD16(gA0 + k0, dA0);
    GLD16(gA1 + k0, dA1);
    GLD16(gB0 + k0, dB0);
    GLD16(gB1 + k0, dB1);
    __syncthreads();
    s8v af[4], bg[4];
#pragma unroll
    for (int i = 0; i < 4; i++) {
      af[i] = *(const s8v*)&lA[(wm + i*16 + fr)*32 + fq*8];
      bg[i] = *(const s8v*)&lB[(wn + i*16 + fr)*32 + fq*8];
    }
#pragma unroll
    for (int mi = 0; mi < 4; mi++)
#pragma unroll
      for (int ni = 0; ni < 4; ni++)
        acc[mi][ni] = __builtin_amdgcn_mfma_f32_16x16x32_bf16(af[mi], bg[ni], acc[mi][ni], 0, 0, 0);
    __syncthreads();
  }

#pragma unroll
  for (int mi = 0; mi < 4; mi++) {
    const int row = m0 + wm + mi*16 + fq*4;
#pragma unroll
    for (int ni = 0; ni < 4; ni++) {
      const int col = n0 + wn + ni*16 + fr;
      if (col >= N) continue;
      const float bv = bias ? bias[col] : 0.f;
#pragma unroll
      for (int r = 0; r < 4; r++) {
        if (row + r >= M) continue;
        float v = acc[mi][ni][r] * alpha + bv;
        const long long idx = cOff + (long long)(row + r)*ldc + col;
        if (resid) v += resid[idx];
        if (relu) v = fmaxf(v, 0.f);
        if (Cf) Cf[idx] = v;
        if (Cb) Cb[idx] = f2bf(v);
      }
    }
  }
}

// ================= pv_k: out1 = attn@v2 and out2 = attn^T@v1 in ONE launch ======
__global__ __launch_bounds__(256) void pv_k(
    const short* __restrict__ attnb, const short* __restrict__ v2T, short* __restrict__ out1,
    const short* __restrict__ attnT, const short* __restrict__ v1T, short* __restrict__ out2)
{
  __shared__ __align__(16) short lA[128*32];
  __shared__ __align__(16) short lB[128*32];
  const int z = blockIdx.z, b = z >> 3, h = z & 7;
  const short* A; const short* B; short* C; int M, K, lda, m0;
  if (blockIdx.y < 8) {
    A = attnb + (size_t)z*786432; B = v2T + (size_t)z*147456;
    C = out1 + ((size_t)b*1024)*1536 + h*192;
    M = 1024; K = 768; lda = 768; m0 = blockIdx.y*128;
  } else {
    A = attnT + (size_t)z*786432; B = v1T + (size_t)z*196608;
    C = out2 + ((size_t)b*768)*1536 + h*192;
    M = 768; K = 1024; lda = 1024; m0 = (blockIdx.y - 8)*128;
  }
  const int N = 192, ldc = 1536, ldb = lda;
  const int n0 = blockIdx.x*128;
  const int tid = threadIdx.x, lane = tid & 63, wv = tid >> 6;
  const int wm = (wv >> 1)*64, wn = (wv & 1)*64;
  const int fr = lane & 15, fq = lane >> 4;

  f4v acc[4][4] = {};

  const int rA0 = m0 + (tid >> 2);
  const int rA1 = m0 + 64 + (tid >> 2);
  const int rB0 = min(n0 + (tid >> 2), N - 1);
  const int rB1 = min(n0 + 64 + (tid >> 2), N - 1);
  const int pc = (tid & 3) * 8;
  const short* gA0 = A + (size_t)rA0*lda + pc;
  const short* gA1 = A + (size_t)rA1*lda + pc;
  const short* gB0 = B + (size_t)rB0*ldb + pc;
  const short* gB1 = B + (size_t)rB1*ldb + pc;
  short* dA0 = lA + (wv*64)*8;
  short* dA1 = lA + (256 + wv*64)*8;
  short* dB0 = lB + (wv*64)*8;
  short* dB1 = lB + (256 + wv*64)*8;

  for (int k0 = 0; k0 < K; k0 += 32) {
    GLD16(gA0 + k0, dA0);
    GLD16(gA1 + k0, dA1);
    GLD16(gB0 + k0, dB0);
    GLD16(gB1 + k0, dB1);
    __syncthreads();
    s8v af[4], bg[4];
#pragma unroll
    for (int i = 0; i < 4; i++) {
      af[i] = *(const s8v*)&lA[(wm + i*16 + fr)*32 + fq*8];
      bg[i] = *(const s8v*)&lB[(wn + i*16 + fr)*32 + fq*8];
    }
#pragma unroll
    for (int mi = 0; mi < 4; mi++)
#pragma unroll
      for (int ni = 0; ni < 4; ni++)
        acc[mi][ni] = __builtin_amdgcn_mfma_f32_16x16x32_bf16(af[mi], bg[ni], acc[mi][ni], 0, 0, 0);
    __syncthreads();
  }

#pragma unroll
  for (int mi = 0; mi < 4; mi++) {
    const int row = m0 + wm + mi*16 + fq*4;
#pragma unroll
    for (int ni = 0; ni < 4; ni++) {
      const int col = n0 + wn + ni*16 + fr;
      if (col >= N) continue;
#pragma unroll
      for (int r = 0; r < 4; r++)
        C[(size_t)(row + r)*ldc + col] = f2bf(acc[mi][ni][r]);
    }
  }
}

// ================= 256x256 8-phase GEMM (r6 single-barrier schedule) ======
#define ST_A(buf, ks, tt) do { const int ko = ((tt)<<6) + ((ks)<<5); \
    GLD16(gA0 + ko, ldA + ((buf)*2+(ks))*8192); \
    GLD16(gA1 + ko, ldA + ((buf)*2+(ks))*8192 + 4096); } while(0)
#define ST_B(buf, ks, tt) do { const int ko = ((tt)<<6) + ((ks)<<5); \
    GLD16(gB0 + ko, ldB + ((buf)*2+(ks))*8192); \
    GLD16(gB1 + ko, ldB + ((buf)*2+(ks))*8192 + 4096); } while(0)

#define PH256(buf, ks, mig, READB, DOWAIT, ...) do { \
    s8v av[4]; \
    const int rb = ((buf)*2+(ks))*8192; \
    _Pragma("unroll") for (int q2 = 0; q2 < 4; q2++) av[q2] = *(const s8v*)&smem[rb + aoff[(mig)*4+q2]]; \
    if (READB) { _Pragma("unroll") for (int q2 = 0; q2 < 4; q2++) bv[q2] = *(const s8v*)&smem[32768 + rb + boff[q2]]; } \
    __VA_ARGS__; \
    if (DOWAIT == 1) asm volatile("s_waitcnt vmcnt(6)" ::: "memory"); \
    if (DOWAIT == 2) asm volatile("s_waitcnt vmcnt(0)" ::: "memory"); \
    __builtin_amdgcn_s_barrier(); \
    asm volatile("s_waitcnt lgkmcnt(0)" ::: "memory"); \
    __builtin_amdgcn_s_setprio(1); \
    _Pragma("unroll") for (int q2 = 0; q2 < 4; q2++) \
      _Pragma("unroll") for (int u2 = 0; u2 < 4; u2++) \
        acc[(mig)*4+q2][u2] = __builtin_amdgcn_mfma_f32_16x16x32_bf16(av[q2], bv[u2], acc[(mig)*4+q2][u2], 0, 0, 0); \
    __builtin_amdgcn_s_setprio(0); \
  } while(0)

__global__ __launch_bounds__(512) void gemm256(
    const short* __restrict__ A0p, const short* __restrict__ B0p,
    float* C0f, short* C0b, const float* __restrict__ bias0, const float* res0,
    int nb0, int nbm0, int N0, float al0,
    const short* __restrict__ A1p, const short* __restrict__ B1p,
    float* C1f, short* C1b, const float* __restrict__ bias1, const float* res1,
    int nb01, int nbm1, int N1, float al1,
    const short* __restrict__ A2p, const short* __restrict__ B2p,
    float* C2f, short* C2b, const float* __restrict__ bias2, const float* res2,
    int nbm2, int N2, float al2,
    int K, int relu)
{
  __shared__ __align__(16) short smem[65536];   // 128 KiB
  const int total = gridDim.x;
  int bid = blockIdx.x;
  if ((total & 7) == 0) bid = (bid & 7)*(total >> 3) + (bid >> 3);   // bijective XCD swizzle
  const short* A; const short* B; float* Cf; short* Cb; const float* bias; const float* resid;
  int tile, nbm, N; float alpha;
  if (bid < nb0)       { A = A0p; B = B0p; Cf = C0f; Cb = C0b; bias = bias0; resid = res0;
                         tile = bid; nbm = nbm0; N = N0; alpha = al0; }
  else if (bid < nb01) { A = A1p; B = B1p; Cf = C1f; Cb = C1b; bias = bias1; resid = res1;
                         tile = bid - nb0; nbm = nbm1; N = N1; alpha = al1; }
  else                 { A = A2p; B = B2p; Cf = C2f; Cb = C2b; bias = bias2; resid = res2;
                         tile = bid - nb01; nbm = nbm2; N = N2; alpha = al2; }
  const int bm = tile % nbm, bn = tile / nbm;   // col-major: consecutive tiles share B panel
  const int m0 = bm << 8, n0 = bn << 8;
  const int t = threadIdx.x, lane = t & 63, w = t >> 6;
  const int wm = w >> 2, wn = w & 3;
  const int fr = lane & 15, fq = lane >> 4;
  const int ntk = K >> 6;                        // requires K % 128 == 0, K >= 256

  const int r0 = t >> 2, r1 = 128 + (t >> 2), gsw = t & 3;
  const int cs0 = (gsw ^ ((r0 >> 1) & 3)) << 3;
  const int cs1 = (gsw ^ ((r1 >> 1) & 3)) << 3;
  const short* gA0 = A + (size_t)(m0 + r0)*K + cs0;
  const short* gA1 = A + (size_t)(m0 + r1)*K + cs1;
  const short* gB0 = B + (size_t)(n0 + r0)*K + cs0;
  const short* gB1 = B + (size_t)(n0 + r1)*K + cs1;
  short* const ldA = smem + w*512;
  short* const ldB = smem + 32768 + w*512;

  int aoff[8], boff[4];
#pragma unroll
  for (int mi = 0; mi < 8; mi++) { const int r = wm*128 + mi*16 + fr; aoff[mi] = r*32 + ((fq ^ ((r >> 1) & 3)) << 3); }
#pragma unroll
  for (int ni = 0; ni < 4; ni++) { const int r = wn*64 + ni*16 + fr; boff[ni] = r*32 + ((fq ^ ((r >> 1) & 3)) << 3); }

  f4v acc[8][4] = {};
  s8v bv[4];

  ST_A(0,0,0); ST_B(0,0,0); ST_A(0,1,0); ST_B(0,1,0);
  ST_B(1,0,1); ST_A(1,0,1); ST_B(1,1,1);
  asm volatile("s_waitcnt vmcnt(6)" ::: "memory");
  __builtin_amdgcn_s_barrier();
  asm volatile("" ::: "memory");

  for (int it = 0, nit = (ntk >> 1) - 1; it < nit; ++it) {
    const int t1 = 2*it + 1, t2 = 2*it + 2, t3 = 2*it + 3;
    PH256(0,0,0, 1,0, ST_A(1,1,t1));   // ph1
    PH256(0,0,1, 0,0, ST_B(0,0,t2));   // ph2
    PH256(0,1,0, 1,0, ST_A(0,0,t2));   // ph3
    PH256(0,1,1, 0,1, ST_B(0,1,t2));   // ph4 + vmcnt(6)
    PH256(1,0,0, 1,0, ST_A(0,1,t2));   // ph5
    PH256(1,0,1, 0,0, ST_B(1,0,t3));   // ph6
    PH256(1,1,0, 1,0, ST_A(1,0,t3));   // ph7
    PH256(1,1,1, 0,1, ST_B(1,1,t3));   // ph8 + vmcnt(6)
  }
  PH256(0,0,0, 1,0, ST_A(1,1,ntk-1));
  PH256(0,0,1, 0,0, );
  PH256(0,1,0, 1,0, );
  PH256(0,1,1, 0,2, );                 // vmcnt(0): buf1 fully resident
  PH256(1,0,0, 1,0, );
  PH256(1,0,1, 0,0, );
  PH256(1,1,0, 1,0, );
  PH256(1,1,1, 0,0, );

#pragma unroll
  for (int mi = 0; mi < 8; mi++) {
    const int row = m0 + wm*128 + mi*16 + fq*4;
#pragma unroll
    for (int ni = 0; ni < 4; ni++) {
      const int col = n0 + wn*64 + ni*16 + fr;
      const float bvv = bias ? bias[col] : 0.f;
#pragma unroll
      for (int r = 0; r < 4; r++) {
        float v = acc[mi][ni][r]*alpha + bvv;
        const size_t idx = (size_t)(row + r)*N + col;
        if (resid) v += resid[idx];
        if (relu) v = fmaxf(v, 0.f);
        if (Cf) Cf[idx] = v;
        else Cb[idx] = f2bf(v);
      }
    }
  }
}

// ============ batched weight transpose: up to 8 f32[R,C] -> bf16[C,R], 1 tile/block ======
struct WTB {
  const float* src[8]; short* dst[8];
  int R[8], C[8], start[8];
  int NT;
};

__global__ __launch_bounds__(256) void wtransN(WTB b)
{
  __shared__ float t[32][33];
  const int id = blockIdx.x;
  if (id >= b.NT) return;
  int op = 0;
#pragma unroll
  for (int o = 1; o < 8; o++) if (id >= b.start[o]) op = o;
  const int loc = id - b.start[op];
  const int Cd = b.C[op], Rd = b.R[op];
  const int ncx = Cd >> 5;
  const int cx = (loc % ncx) << 5, ry = (loc / ncx) << 5;
  const float* s = b.src[op];
  short* d = b.dst[op];
  const int tx = threadIdx.x, ty = threadIdx.y;
#pragma unroll
  for (int k = 0; k < 4; k++)
    t[ty + k*8][tx] = s[(size_t)(ry + ty + k*8)*Cd + cx + tx];
  __syncthreads();
#pragma unroll
  for (int k = 0; k < 4; k++)
    d[(size_t)(cx + ty + k*8)*Rd + ry + tx] = f2bf(t[tx][ty + k*8]);
}

// ============ btrans2: v1b -> v1T and v2b -> v2T in one launch ============
__global__ __launch_bounds__(256) void btrans2(
    const short* __restrict__ v1b, short* __restrict__ v1T,
    const short* __restrict__ v2b, short* __restrict__ v2T)
{
  __shared__ short t[32][33];
  const int z = blockIdx.z, b = z >> 3, h = z & 7;
  int y = blockIdx.y;
  const short* S; short* D; int ld_;
  if (y < 32) { S = v1b + ((size_t)b*1024)*1536 + h*192; D = v1T + (size_t)z*196608; ld_ = 1024; }
  else { y -= 32; S = v2b + ((size_t)b*768)*1536 + h*192; D = v2T + (size_t)z*147456; ld_ = 768; }
  const int c0 = blockIdx.x*32, r0 = y*32;
  const int tx = threadIdx.x, ty = threadIdx.y;
#pragma unroll
  for (int k = 0; k < 4; k++)
    t[ty + k*8][tx] = S[(size_t)(r0 + ty + k*8)*1536 + c0 + tx];
  __syncthreads();
#pragma unroll
  for (int k = 0; k < 4; k++)
    D[(size_t)(c0 + ty + k*8)*ld_ + r0 + tx] = t[tx][ty + k*8];
}

// ============ f32 -> bf16 convert ============
__global__ __launch_bounds__(256) void conv_bf(const float* __restrict__ src,
                                               short* __restrict__ dst, long long n)
{
  const long long i = ((long long)blockIdx.x*256 + threadIdx.x)*4;
  if (i >= n) return;
  const float4 v = *(const float4*)(src + i);
  s4v o = { f2bf(v.x), f2bf(v.y), f2bf(v.z), f2bf(v.w) };
  *(s4v*)(dst + i) = o;
}

// ============ LayerNorm over 1536 cols, f32 in -> bf16 out ============
__global__ __launch_bounds__(256) void ln_k(const float* __restrict__ in,
    const float* __restrict__ gam, const float* __restrict__ bet, short* __restrict__ out)
{
  const long long row = blockIdx.x;
  const float* r = in + row*1536;
  const int tid = threadIdx.x;
  float v[6], s = 0.f, s2 = 0.f;
#pragma unroll
  for (int i = 0; i < 6; i++) { v[i] = r[tid + i*256]; s += v[i]; s2 += v[i]*v[i]; }
  for (int m = 1; m < 64; m <<= 1) { s += __shfl_xor(s, m); s2 += __shfl_xor(s2, m); }
  __shared__ float rs[4], rs2[4];
  if ((tid & 63) == 0) { rs[tid>>6] = s; rs2[tid>>6] = s2; }
  __syncthreads();
  s = rs[0]+rs[1]+rs[2]+rs[3]; s2 = rs2[0]+rs2[1]+rs2[2]+rs2[3];
  const float mu  = s * (1.f/1536.f);
  const float var = s2 * (1.f/1536.f) - mu*mu;
  const float inv = rsqrtf(var + 1e-5f);
  short* o = out + row*1536;
#pragma unroll
  for (int i = 0; i < 6; i++) { int c = tid + i*256; o[c] = f2bf((v[i]-mu)*inv*gam[c] + bet[c]); }
}

// ============ ln2_k: both FFN layernorms in one launch ====
__global__ __launch_bounds__(256) void ln2_k(
    const float* __restrict__ in1, const float* __restrict__ g1, const float* __restrict__ b1,
    short* __restrict__ o1,
    const float* __restrict__ in2, const float* __restrict__ g2, const float* __restrict__ b2,
    short* __restrict__ o2)
{
  long long row = blockIdx.x;
  const float* in; const float* gam; const float* bet; short* out;
  if (row < 4096) { in = in1; gam = g1; bet = b1; out = o1; }
  else { row -= 4096; in = in2; gam = g2; bet = b2; out = o2; }
  const float* r = in + row*1536;
  const int tid = threadIdx.x;
  float v[6], s = 0.f, s2 = 0.f;
#pragma unroll
  for (int i = 0; i < 6; i++) { v[i] = r[tid + i*256]; s += v[i]; s2 += v[i]*v[i]; }
  for (int m = 1; m < 64; m <<= 1) { s += __shfl_xor(s, m); s2 += __shfl_xor(s2, m); }
  __shared__ float rs[4], rs2[4];
  if ((tid & 63) == 0) { rs[tid>>6] = s; rs2[tid>>6] = s2; }
  __syncthreads();
  s = rs[0]+rs[1]+rs[2]+rs[3]; s2 = rs2[0]+rs2[1]+rs2[2]+rs2[3];
  const float mu  = s * (1.f/1536.f);
  const float var = s2 * (1.f/1536.f) - mu*mu;
  const float inv = rsqrtf(var + 1e-5f);
  short* o = out + row*1536;
#pragma unroll
  for (int i = 0; i < 6; i++) { int c = tid + i*256; o[c] = f2bf((v[i]-mu)*inv*gam[c] + bet[c]); }
}

// ============ positional features: out bf16 [2047][192] ============
__global__ __launch_bounds__(64) void posemb(short* __restrict__ out)
{
  const int i = blockIdx.x;
  const int j = threadIdx.x;
  const float dist = (float)(i - 1023);
  const float absd = fabsf(dist);
  float fe = 0.f, fc = 0.f, prob = 0.f;
  if (j < 32) {
    const float hl = exp2f(3.f + 7.f*(float)j/31.f);
    fe = expf(-0.6931471805599453f/hl * absd);
    const float width = exp2f((float)(j+1)) - 1.f;
    fc = (width > absd) ? 1.f : 0.f;
    const float m = 32.f*(float)(j+1);
    const float conc = (m/16.f)*(m/16.f);
    const float rate = m/256.f;
    const float logp = (absd > 0.f ? (conc-1.f)*logf(absd) : -INFINITY) - rate*absd;
    const float logn = lgammaf(conc) - conc*logf(rate);
    prob = expf(logp - logn) + 1e-8f;
  }
  float mx = prob;
  for (int m = 1; m < 32; m <<= 1) mx = fmaxf(mx, __shfl_xor(mx, m));
  if (j < 32) {
    const float fg = prob / mx;
    const float sg = dist > 0.f ? 1.f : (dist < 0.f ? -1.f : 0.f);
    const size_t base = (size_t)i*192;
    out[base + j]       = f2bf(fe);
    out[base + 32 + j]  = f2bf(fc);
    out[base + 64 + j]  = f2bf(fg);
    out[base + 96 + j]  = f2bf(sg*fe);
    out[base + 128 + j] = f2bf(sg*fc);
    out[base + 160 + j] = f2bf(sg*fg);
  }
}

// ============ rel bias table: T[h][n] = dot64(rpb[h], relq[n,h*64:]) ============
__global__ __launch_bounds__(256) void relbias_k(const float* __restrict__ rpb,
    const short* __restrict__ relq, float* __restrict__ T)
{
  const int n = blockIdx.x;
  const int tid = threadIdx.x;
  const int h = tid >> 5, l = tid & 31;
  const int d = l*2;
  float s = rpb[h*64+d]   * bf2f(relq[(size_t)n*512 + h*64 + d])
          + rpb[h*64+d+1] * bf2f(relq[(size_t)n*512 + h*64 + d+1]);
  for (int m = 1; m < 32; m <<= 1) s += __shfl_xor(s, m);
  if (l == 0) T[h*2047 + n] = s;
}

// ============ fsm_k: fused scores + softmax -> attnb + attnT (no global logits) ============
// block = (i-chunk of 64 rows, z=(b,h)); 256 threads, 4 waves.
// LDS: lg [64][776] bf16 (99,328B) | kt [64][72] (9,216B) | rqt/P overlay (33,792B) = 142,336B
__global__ __launch_bounds__(256) void fsm_k(
    const short* __restrict__ qb, const short* __restrict__ kb,
    const short* __restrict__ relq, const float* __restrict__ T,
    short* __restrict__ attnb, short* __restrict__ attnT)
{
  __shared__ __align__(16) short smem[71168];
  short* lg  = smem;                    // 64 x 776
  short* kt  = smem + 49664;            // 64 x 72
  short* rqt = smem + 54272;            // 128 x 72 (overlaid with P)
  float* P   = (float*)(smem + 54272);  // 64 x 132 f32

  const int z = blockIdx.y, b = z >> 3, h = z & 7;
  const int i0 = blockIdx.x*64;
  const int tid = threadIdx.x, lane = tid & 63, wv = tid >> 6;
  const int fr = lane & 15, fq = lane >> 4;
  const int wi = (wv & 1)*32, wj = (wv >> 1)*32;
  const int wj2 = (wv & 1)*32, wn2 = (wv >> 1)*64;

  // preload q fragments into registers (reused across all 12 j-tiles)
  s8v aq[2][2];
  {
    const short* qg = qb + (size_t)(b*1024 + i0)*512 + h*64;
#pragma unroll
    for (int mi = 0; mi < 2; mi++)
#pragma unroll
      for (int ks = 0; ks < 2; ks++)
        aq[mi][ks] = *(const s8v*)&qg[(size_t)(wi + mi*16 + fr)*512 + ks*32 + fq*8];
  }
  const short* kgb = kb + (size_t)(b*768)*512 + h*64;
  const float* Th = T + h*2047;

  for (int jt = 0; jt < 12; ++jt) {
    const int j0 = jt*64;
    const int nbase = 704 + i0 - j0;
    __syncthreads();                       // protect kt / rqt(P) from prior-iter reads
    {
      const short* kg = kgb + (size_t)j0*512;
      const short* rg = relq + (size_t)nbase*512 + h*64;
      for (int c = tid; c < 512; c += 256) {
        const int r = c >> 3, ch = (c & 7)*8;
        *(s8v*)&kt[r*72 + ch] = *(const s8v*)&kg[(size_t)r*512 + ch];
      }
      for (int c = tid; c < 1024; c += 256) {
        const int r = c >> 3, ch = (c & 7)*8;
        *(s8v*)&rqt[r*72 + ch] = *(const s8v*)&rg[(size_t)r*512 + ch];
      }
    }
    __syncthreads();

    // content MFMA: c2[i-half][j-half]
    f4v c2[2][2] = {};
#pragma unroll
    for (int ks = 0; ks < 2; ks++) {
      s8v bk[2];
#pragma unroll
      for (int ni = 0; ni < 2; ni++) bk[ni] = *(const s8v*)&kt[(wj + ni*16 + fr)*72 + ks*32 + fq*8];
#pragma unroll
      for (int mi = 0; mi < 2; mi++)
#pragma unroll
        for (int ni = 0; ni < 2; ni++)
          c2[mi][ni] = __builtin_amdgcn_mfma_f32_16x16x32_bf16(aq[mi][ks], bk[ni], c2[mi][ni], 0, 0, 0);
    }

    // rel MFMA: P[j][n]
    f4v pr[2][4] = {};
#pragma unroll
    for (int ks = 0; ks < 2; ks++) {
      s8v a2[2], b2[4];
#pragma unroll
      for (int mi = 0; mi < 2; mi++) a2[mi] = *(const s8v*)&kt[(wj2 + mi*16 + fr)*72 + ks*32 + fq*8];
#pragma unroll
      for (int ni = 0; ni < 4; ni++) b2[ni] = *(const s8v*)&rqt[(wn2 + ni*16 + fr)*72 + ks*32 + fq*8];
#pragma unroll
      for (int mi = 0; mi < 2; mi++)
#pragma unroll
        for (int ni = 0; ni < 4; ni++)
          pr[mi][ni] = __builtin_amdgcn_mfma_f32_16x16x32_bf16(a2[mi], b2[ni], pr[mi][ni], 0, 0, 0);
    }
    __syncthreads();                       // rqt reads done

#pragma unroll
    for (int mi = 0; mi < 2; mi++)
#pragma unroll
      for (int ni = 0; ni < 4; ni++)
#pragma unroll
        for (int r = 0; r < 4; r++)
          P[(wj2 + mi*16 + fq*4 + r)*132 + wn2 + ni*16 + fr] = pr[mi][ni][r];
    __syncthreads();

    const float* Tt = Th + nbase;
#pragma unroll
    for (int mi = 0; mi < 2; mi++)
#pragma unroll
      for (int ni = 0; ni < 2; ni++)
#pragma unroll
        for (int r = 0; r < 4; r++) {
          const int il = wi + mi*16 + fq*4 + r;
          const int jl = wj + ni*16 + fr;
          const int nl = 63 + il - jl;
          lg[il*776 + j0 + jl] = f2bf(c2[mi][ni][r] + 0.125f*P[jl*132 + nl] + Tt[nl]);
        }
  }
  __syncthreads();

  // ---- softmax over the 64 x 768 LDS tile; 4 threads per row ----
  const int rr = tid >> 2, qq = tid & 3;
  short* lr = lg + rr*776 + qq*192;
  float mx = -1e30f;
  for (int k = 0; k < 24; k++) {
    const int kk = ((k + qq*6) % 24)*8;    // bank-rotated across the 4 col-segments
    const s8v v = *(const s8v*)&lr[kk];
#pragma unroll
    for (int e = 0; e < 8; e++) mx = fmaxf(mx, bf2f(v[e]));
  }
  mx = fmaxf(mx, __shfl_xor(mx, 1));
  mx = fmaxf(mx, __shfl_xor(mx, 2));
  float s = 0.f;
  for (int k = 0; k < 24; k++) {
    const int kk = ((k + qq*6) % 24)*8;
    const s8v v = *(const s8v*)&lr[kk];
#pragma unroll
    for (int e = 0; e < 8; e++) s += __expf(bf2f(v[e]) - mx);
  }
  s += __shfl_xor(s, 1);
  s += __shfl_xor(s, 2);
  const float inv = 1.f / s;

  short* ab = attnb + ((size_t)z*1024 + i0 + rr)*768 + qq*192;
  for (int k = 0; k < 24; k++) {
    const int kk = ((k + qq*6) % 24)*8;
    const s8v v = *(const s8v*)&lr[kk];
    s8v o;
#pragma unroll
    for (int e = 0; e < 8; e++) o[e] = f2bf(__expf(bf2f(v[e]) - mx) * inv);
    *(s8v*)&ab[kk] = o;
    *(s8v*)&lr[kk] = o;                    // normalized back into LDS for transpose
  }
  __syncthreads();

  // ---- transposed writes: attnT[z][j][i0..i0+63] ----
  short* aT = attnT + (size_t)z*786432 + (size_t)i0;
  const int i4 = (lane & 15)*4, jb = lane >> 4;
  for (int jj = 0; jj < 48; jj++) {
    const int j = wv*192 + jj*4 + jb;
    s4v o;
#pragma unroll
    for (int e = 0; e < 4; e++) o[e] = lg[(i4 + e)*776 + j];
    *(s4v*)&aT[(size_t)j*1024 + i4] = o;
  }
}

// ======================= host =======================
static void gemm(hipStream_t st, const short* A, const short* B, float* Cf, short* Cb,
                 const float* bias, const float* resid,
                 int M, int N, int K, int lda, int ldb, int ldc,
                 int batches = 1,
                 long long sAo = 0, long long sAi = 0, long long sBo = 0, long long sBi = 0,
                 long long sCo = 0, long long sCi = 0, float alpha = 1.f, int relu = 0)
{
  dim3 g((N + 127)/128, (M + 127)/128, batches);
  gemm_bt<<<g, dim3(256), 0, st>>>(A, B, Cf, Cb, bias, resid, M, N, K, lda, ldb, ldc,
                                   sAo, sAi, sBo, sBi, sCo, sCi, alpha, relu);
}

static void g256_3(hipStream_t st,
    const short* A0, const short* B0, float* C0f, short* C0b, const float* bias0, const float* res0,
    int M0, int N0, float al0,
    const short* A1, const short* B1, float* C1f, short* C1b, const float* bias1, const float* res1,
    int M1, int N1, float al1,
    const short* A2, const short* B2, float* C2f, short* C2b, const float* bias2, const float* res2,
    int M2, int N2, float al2,
    int K, int relu)
{
  const int nbm0 = M0 >> 8, nb0 = nbm0*(N0 >> 8);
  const int nbm1 = M1 >> 8, nb1 = nbm1*(N1 >> 8);
  const int nbm2 = M2 >> 8, nb2 = M2 ? nbm2*(N2 >> 8) : 0;
  gemm256<<<dim3(nb0 + nb1 + nb2), dim3(512), 0, st>>>(
      A0, B0, C0f, C0b, bias0, res0, nb0, nbm0, N0, al0,
      A1, B1, C1f, C1b, bias1, res1, nb0 + nb1, nbm1, N1, al1,
      A2, B2, C2f, C2b, bias2, res2, nbm2, N2, al2, K, relu);
}

static void g256(hipStream_t st,
    const short* A0, const short* B0, float* C0f, short* C0b, const float* bias0, const float* res0,
    int M0, int N0, float al0,
    const short* A1, const short* B1, float* C1f, short* C1b, const float* bias1, const float* res1,
    int M1, int N1, float al1,
    int K, int relu)
{
  g256_3(st, A0, B0, C0f, C0b, bias0, res0, M0, N0, al0,
         A1, B1, C1f, C1b, bias1, res1, M1, N1, al1,
         nullptr, nullptr, nullptr, nullptr, nullptr, nullptr, 0, 256, 1.f, K, relu);
}

extern "C" void kernel_launch(void* const* d_in, const int* in_sizes, int n_in,
                              void* d_out, int out_size, void* d_ws, size_t ws_size,
                              hipStream_t stream)
{
  (void)in_sizes; (void)n_in; (void)out_size; (void)ws_size;
  const float* x     = (const float*)d_in[0];
  const float* y0    = (const float*)d_in[1];
  const float* lnxg  = (const float*)d_in[3];
  const float* lnxb  = (const float*)d_in[4];
  const float* lnyg  = (const float*)d_in[5];
  const float* lnyb  = (const float*)d_in[6];
  const float* rpb   = (const float*)d_in[12];
  const float* bo1   = (const float*)d_in[14];
  const float* bo2   = (const float*)d_in[16];
  const float* fxg   = (const float*)d_in[17];
  const float* fxbb  = (const float*)d_in[18];
  const float* fxb1  = (const float*)d_in[20];
  const float* fxb2  = (const float*)d_in[22];
  const float* fyg   = (const float*)d_in[23];
  const float* fybb  = (const float*)d_in[24];
  const float* fyb1  = (const float*)d_in[26];
  const float* fyb2  = (const float*)d_in[28];

  char* base = (char*)d_ws;
  size_t off = 0;
  auto bump = [&](size_t b) -> char* { char* p = base + off; off += (b + 255) & ~(size_t)255; return p; };

  // ---- pooled weight buffers (bf16, transposed [N,K]) ----
  short* W_A  = (short*)bump(4718592);   // resT -> wo1T           (1536x1536)
  short* W_B  = (short*)bump(1572864);   // wqT                    (512x1536)
  short* W_B2 = (short*)bump(1572864);   // wkT                    (512x1536)
  short* W_C  = (short*)bump(4718592);   // wv1T -> wo2T           (1536x1536)
  short* W_D  = (short*)bump(196608);    // relT                   (512x192)
  short* W_E  = (short*)bump(9437184);   // fx1T                   (3072x1536)
  short* W_F  = (short*)bump(9437184);   // fx2T                   (1536x3072)

  char*  uB = bump(12582912);
  short* x1   = (short*)uB;
  short* v1T  = (short*)uB;
  char*  uC = bump(9437184);
  short* y1   = (short*)uC;
  short* out2 = (short*)uC;
  char*  uD = bump(9437184);
  short* y0b = (short*)uD;
  short* qb  = (short*)uD;
  short* kbB = (short*)(uD + 4194304);
  short* v2T = (short*)uD;
  float* Tbl   = (float*)bump(262016);
  short* posb  = (short*)bump(786048);
  short* relqb = (short*)bump(2096128);
  char*  uG = bump(12582912);
  short* v1b  = (short*)uG;
  short* out1 = (short*)uG;
  short* x4ln = (short*)uG;
  char*  uH = bump(9437184);   short* v2b = (short*)uH;  short* y4ln = (short*)uH;
  char*  uI = bump(100663296);
  short* wv2T    = (short*)uI;                 // B1, dead before fsm_k
  short* attnT   = (short*)(uI + 50331648);    // fsm_k -> pv_k
  short* hx      = (short*)uI;                 // ffn
  short* hy      = (short*)(uI + 25165824);
  short* fy1T    = (short*)(uI + 46137344);    // B3
  short* fy2T    = (short*)(uI + 55574528);    // B3
  char*  U2 = bump(50331648);
  short* attnb = (short*)U2;                   // fsm_k -> pv_k
  float* y4    = (float*)U2;                   // wo-pair onward

  float* outx = (float*)d_out;
  float* outy = (float*)d_out + 6291456;
  float* x4  = outx;
  float* y_f = outy;

  auto addop = [&](WTB& b, int i, int idx, short* dst, int R, int C) {
    b.src[i] = (const float*)d_in[idx]; b.dst[i] = dst;
    b.R[i] = R; b.C[i] = C; b.start[i] = b.NT; b.NT += (R >> 5)*(C >> 5);
  };
  auto finwtb = [&](WTB& b, int n) {
    for (int i = n; i < 8; i++) { b.start[i] = 0x7fffffff; b.src[i] = nullptr; b.dst[i] = nullptr; b.R[i] = 32; b.C[i] = 32; }
  };

  // B1: all weights needed through v2qk + ffn-x
  WTB b1{}; b1.NT = 0;
  addop(b1, 0, 2,  W_A,  1536, 1536);   // res_w
  addop(b1, 1, 11, W_D,  192,  512);    // wrel
  addop(b1, 2, 9,  W_C,  1536, 1536);   // wv1
  addop(b1, 3, 10, wv2T, 1536, 1536);   // wv2
  addop(b1, 4, 7,  W_B,  1536, 512);    // wq
  addop(b1, 5, 8,  W_B2, 1536, 512);    // wk
  addop(b1, 6, 19, W_E,  1536, 3072);   // fx_w1
  addop(b1, 7, 21, W_F,  3072, 1536);   // fx_w2
  wtransN<<<dim3(b1.NT), dim3(32,8), 0, stream>>>(b1);

  // prep: y0 -> bf16 ; positional features ; ln_x
  conv_bf<<<4608, 256, 0, stream>>>(y0, y0b, 4718592LL);
  posemb<<<2047, 64, 0, stream>>>(posb);
  ln_k<<<4096, 256, 0, stream>>>(x, lnxg, lnxb, x1);
  // relq = pos @ wrel ; rel bias table
  gemm(stream, posb, W_D, nullptr, relqb, nullptr, nullptr, 2047, 512, 192, 192, 192, 512);
  relbias_k<<<2047, 256, 0, stream>>>(rpb, relqb, Tbl);
  // launch1: res = y0@res_w -> y_f + v1 = x1@wv1
  g256(stream, y0b, W_A, y_f, nullptr, nullptr, nullptr, 3072, 1536, 1.f,
       x1, W_C, nullptr, v1b, nullptr, nullptr, 4096, 1536, 1.f, 1536, 0);
  // B2: wo1 -> W_A, wo2 -> W_C
  WTB b2{}; b2.NT = 0;
  addop(b2, 0, 13, W_A, 1536, 1536);
  addop(b2, 1, 15, W_C, 1536, 1536);
  finwtb(b2, 2);
  wtransN<<<dim3(b2.NT), dim3(32,8), 0, stream>>>(b2);
  // ln_y
  ln_k<<<3072, 256, 0, stream>>>(y_f, lnyg, lnyb, y1);
  // v2 + q + k
  g256_3(stream, y1, wv2T, nullptr, v2b, nullptr, nullptr, 3072, 1536, 1.f,
         x1, W_B, nullptr, qb, nullptr, nullptr, 4096, 512, 0.125f,
         y1, W_B2, nullptr, kbB, nullptr, nullptr, 3072, 512, 1.f, 1536, 0);
  // fused scores + softmax -> attnb + attnT (no global logits)
  fsm_k<<<dim3(16,32), 256, 0, stream>>>(qb, kbB, relqb, Tbl, attnb, attnT);
  // btrans2: v1T (uB) + v2T (uD) in one launch
  btrans2<<<dim3(6,56,32), dim3(32,8), 0, stream>>>(v1b, v1T, v2b, v2T);
  // pv_k: out1 = attn@v2 (-> uG) and out2 = attn^T@v1 (-> uC) in one launch
  pv_k<<<dim3(2,14,32), 256, 0, stream>>>(attnb, v2T, out1, attnT, v1T, out2);
  // B3: fy1 -> fy1T, fy2 -> fy2T (uI attn regions dead)
  WTB b3{}; b3.NT = 0;
  addop(b3, 0, 25, fy1T, 1536, 3072);
  addop(b3, 1, 27, fy2T, 3072, 1536);
  finwtb(b3, 2);
  wtransN<<<dim3(b3.NT), dim3(32,8), 0, stream>>>(b3);
  // wo-pair: x4 = x + out1@wo1 + bo1 ; y4 = y + out2@wo2 + bo2
  g256(stream, out1, W_A, x4, nullptr, bo1, x, 4096, 1536, 1.f,
       out2, W_C, y4, nullptr, bo2, y_f, 3072, 1536, 1.f, 1536, 0);
  // merged FFN LayerNorms
  ln2_k<<<7168, 256, 0, stream>>>(x4, fxg, fxbb, x4ln, y4, fyg, fybb, y4ln);
  // ffn1: hidden = relu(ln @ w1 + b1)
  g256(stream, x4ln, W_E, nullptr, hx, fxb1, nullptr, 4096, 3072, 1.f,
       y4ln, fy1T, nullptr, hy, fyb1, nullptr, 3072, 3072, 1.f, 1536, 1);
  // ffn2: out = resid + h @ w2 + b2  (in-place on outx)
  g256(stream, hx, W_F, outx, nullptr, fxb2, x4, 4096, 1536, 1.f,
       hy, fy2T, outy, nullptr, fyb2, y4, 3072, 1536, 1.f, 3072, 0);
}

// Round 15
// 651.175 us; speedup vs baseline: 1.0423x; 1.0423x over previous
//
#include <hip/hip_runtime.h>
#include <stdint.h>
#include <math.h>

typedef __attribute__((ext_vector_type(8))) short s8v;
typedef __attribute__((ext_vector_type(4))) short s4v;
typedef __attribute__((ext_vector_type(4))) float f4v;

#define DEV static __device__ __forceinline__

DEV short f2bf(float f) {
  uint32_t u = __builtin_bit_cast(uint32_t, f);
  u += 0x7FFFu + ((u >> 16) & 1u);   // round-to-nearest-even
  return (short)(u >> 16);
}
DEV float bf2f(short s) {
  uint32_t u = ((uint32_t)(uint16_t)s) << 16;
  return __builtin_bit_cast(float, u);
}

#define GLD16(g, l) __builtin_amdgcn_global_load_lds( \
    (const __attribute__((address_space(1))) void*)(g), \
    (__attribute__((address_space(3))) void*)(l), 16, 0, 0)

// ================= 128x128 GEMM (m97 structure) for small/odd/batched shapes =========
__global__ __launch_bounds__(256) void gemm_bt(
    const short* __restrict__ A, const short* __restrict__ B,
    float* Cf, short* Cb,
    const float* __restrict__ bias, const float* resid,
    int M, int N, int K, int lda, int ldb, int ldc,
    long long sAo, long long sAi, long long sBo, long long sBi,
    long long sCo, long long sCi, float alpha, int relu)
{
  __shared__ __align__(16) short lA[128*32];
  __shared__ __align__(16) short lB[128*32];
  const int z = blockIdx.z, zo = z >> 3, zi = z & 7;
  const short* Ab = A + zo*sAo + zi*sAi;
  const short* Bb = B + zo*sBo + zi*sBi;
  const long long cOff = zo*sCo + zi*sCi;

  const int m0 = blockIdx.y*128, n0 = blockIdx.x*128;
  const int tid = threadIdx.x, lane = tid & 63, wv = tid >> 6;
  const int wm = (wv >> 1)*64, wn = (wv & 1)*64;
  const int fr = lane & 15, fq = lane >> 4;

  f4v acc[4][4] = {};

  const int rA0 = min(m0 + (tid >> 2), M - 1);
  const int rA1 = min(m0 + 64 + (tid >> 2), M - 1);
  const int rB0 = min(n0 + (tid >> 2), N - 1);
  const int rB1 = min(n0 + 64 + (tid >> 2), N - 1);
  const int pc = (tid & 3) * 8;
  const short* gA0 = Ab + (size_t)rA0*lda + pc;
  const short* gA1 = Ab + (size_t)rA1*lda + pc;
  const short* gB0 = Bb + (size_t)rB0*ldb + pc;
  const short* gB1 = Bb + (size_t)rB1*ldb + pc;
  short* dA0 = lA + (wv*64)*8;
  short* dA1 = lA + (256 + wv*64)*8;
  short* dB0 = lB + (wv*64)*8;
  short* dB1 = lB + (256 + wv*64)*8;

  for (int k0 = 0; k0 < K; k0 += 32) {
    GLD16(gA0 + k0, dA0);
    GLD16(gA1 + k0, dA1);
    GLD16(gB0 + k0, dB0);
    GLD16(gB1 + k0, dB1);
    __syncthreads();
    s8v af[4], bg[4];
#pragma unroll
    for (int i = 0; i < 4; i++) {
      af[i] = *(const s8v*)&lA[(wm + i*16 + fr)*32 + fq*8];
      bg[i] = *(const s8v*)&lB[(wn + i*16 + fr)*32 + fq*8];
    }
#pragma unroll
    for (int mi = 0; mi < 4; mi++)
#pragma unroll
      for (int ni = 0; ni < 4; ni++)
        acc[mi][ni] = __builtin_amdgcn_mfma_f32_16x16x32_bf16(af[mi], bg[ni], acc[mi][ni], 0, 0, 0);
    __syncthreads();
  }

#pragma unroll
  for (int mi = 0; mi < 4; mi++) {
    const int row = m0 + wm + mi*16 + fq*4;
#pragma unroll
    for (int ni = 0; ni < 4; ni++) {
      const int col = n0 + wn + ni*16 + fr;
      if (col >= N) continue;
      const float bv = bias ? bias[col] : 0.f;
#pragma unroll
      for (int r = 0; r < 4; r++) {
        if (row + r >= M) continue;
        float v = acc[mi][ni][r] * alpha + bv;
        const long long idx = cOff + (long long)(row + r)*ldc + col;
        if (resid) v += resid[idx];
        if (relu) v = fmaxf(v, 0.f);
        if (Cf) Cf[idx] = v;
        if (Cb) Cb[idx] = f2bf(v);
      }
    }
  }
}

// ================= pv_k: out1 = attn@v2 and out2 = attn^T@v1 in ONE launch ======
__global__ __launch_bounds__(256) void pv_k(
    const short* __restrict__ attnb, const short* __restrict__ v2T, short* __restrict__ out1,
    const short* __restrict__ attnT, const short* __restrict__ v1T, short* __restrict__ out2)
{
  __shared__ __align__(16) short lA[128*32];
  __shared__ __align__(16) short lB[128*32];
  const int z = blockIdx.z, b = z >> 3, h = z & 7;
  const short* A; const short* B; short* C; int M, K, lda, m0;
  if (blockIdx.y < 8) {
    A = attnb + (size_t)z*786432; B = v2T + (size_t)z*147456;
    C = out1 + ((size_t)b*1024)*1536 + h*192;
    M = 1024; K = 768; lda = 768; m0 = blockIdx.y*128;
  } else {
    A = attnT + (size_t)z*786432; B = v1T + (size_t)z*196608;
    C = out2 + ((size_t)b*768)*1536 + h*192;
    M = 768; K = 1024; lda = 1024; m0 = (blockIdx.y - 8)*128;
  }
  const int N = 192, ldc = 1536, ldb = lda;
  const int n0 = blockIdx.x*128;
  const int tid = threadIdx.x, lane = tid & 63, wv = tid >> 6;
  const int wm = (wv >> 1)*64, wn = (wv & 1)*64;
  const int fr = lane & 15, fq = lane >> 4;

  f4v acc[4][4] = {};

  const int rA0 = m0 + (tid >> 2);
  const int rA1 = m0 + 64 + (tid >> 2);
  const int rB0 = min(n0 + (tid >> 2), N - 1);
  const int rB1 = min(n0 + 64 + (tid >> 2), N - 1);
  const int pc = (tid & 3) * 8;
  const short* gA0 = A + (size_t)rA0*lda + pc;
  const short* gA1 = A + (size_t)rA1*lda + pc;
  const short* gB0 = B + (size_t)rB0*ldb + pc;
  const short* gB1 = B + (size_t)rB1*ldb + pc;
  short* dA0 = lA + (wv*64)*8;
  short* dA1 = lA + (256 + wv*64)*8;
  short* dB0 = lB + (wv*64)*8;
  short* dB1 = lB + (256 + wv*64)*8;

  for (int k0 = 0; k0 < K; k0 += 32) {
    GLD16(gA0 + k0, dA0);
    GLD16(gA1 + k0, dA1);
    GLD16(gB0 + k0, dB0);
    GLD16(gB1 + k0, dB1);
    __syncthreads();
    s8v af[4], bg[4];
#pragma unroll
    for (int i = 0; i < 4; i++) {
      af[i] = *(const s8v*)&lA[(wm + i*16 + fr)*32 + fq*8];
      bg[i] = *(const s8v*)&lB[(wn + i*16 + fr)*32 + fq*8];
    }
#pragma unroll
    for (int mi = 0; mi < 4; mi++)
#pragma unroll
      for (int ni = 0; ni < 4; ni++)
        acc[mi][ni] = __builtin_amdgcn_mfma_f32_16x16x32_bf16(af[mi], bg[ni], acc[mi][ni], 0, 0, 0);
    __syncthreads();
  }

#pragma unroll
  for (int mi = 0; mi < 4; mi++) {
    const int row = m0 + wm + mi*16 + fq*4;
#pragma unroll
    for (int ni = 0; ni < 4; ni++) {
      const int col = n0 + wn + ni*16 + fr;
      if (col >= N) continue;
#pragma unroll
      for (int r = 0; r < 4; r++)
        C[(size_t)(row + r)*ldc + col] = f2bf(acc[mi][ni][r]);
    }
  }
}

// ================= 256x256 8-phase GEMM (r6 single-barrier schedule) ======
#define ST_A(buf, ks, tt) do { const int ko = ((tt)<<6) + ((ks)<<5); \
    GLD16(gA0 + ko, ldA + ((buf)*2+(ks))*8192); \
    GLD16(gA1 + ko, ldA + ((buf)*2+(ks))*8192 + 4096); } while(0)
#define ST_B(buf, ks, tt) do { const int ko = ((tt)<<6) + ((ks)<<5); \
    GLD16(gB0 + ko, ldB + ((buf)*2+(ks))*8192); \
    GLD16(gB1 + ko, ldB + ((buf)*2+(ks))*8192 + 4096); } while(0)

#define PH256(buf, ks, mig, READB, DOWAIT, ...) do { \
    s8v av[4]; \
    const int rb = ((buf)*2+(ks))*8192; \
    _Pragma("unroll") for (int q2 = 0; q2 < 4; q2++) av[q2] = *(const s8v*)&smem[rb + aoff[(mig)*4+q2]]; \
    if (READB) { _Pragma("unroll") for (int q2 = 0; q2 < 4; q2++) bv[q2] = *(const s8v*)&smem[32768 + rb + boff[q2]]; } \
    __VA_ARGS__; \
    if (DOWAIT == 1) asm volatile("s_waitcnt vmcnt(6)" ::: "memory"); \
    if (DOWAIT == 2) asm volatile("s_waitcnt vmcnt(0)" ::: "memory"); \
    __builtin_amdgcn_s_barrier(); \
    asm volatile("s_waitcnt lgkmcnt(0)" ::: "memory"); \
    __builtin_amdgcn_s_setprio(1); \
    _Pragma("unroll") for (int q2 = 0; q2 < 4; q2++) \
      _Pragma("unroll") for (int u2 = 0; u2 < 4; u2++) \
        acc[(mig)*4+q2][u2] = __builtin_amdgcn_mfma_f32_16x16x32_bf16(av[q2], bv[u2], acc[(mig)*4+q2][u2], 0, 0, 0); \
    __builtin_amdgcn_s_setprio(0); \
  } while(0)

__global__ __launch_bounds__(512) void gemm256(
    const short* __restrict__ A0p, const short* __restrict__ B0p,
    float* C0f, short* C0b, const float* __restrict__ bias0, const float* res0,
    int nb0, int nbm0, int N0, float al0,
    const short* __restrict__ A1p, const short* __restrict__ B1p,
    float* C1f, short* C1b, const float* __restrict__ bias1, const float* res1,
    int nb01, int nbm1, int N1, float al1,
    const short* __restrict__ A2p, const short* __restrict__ B2p,
    float* C2f, short* C2b, const float* __restrict__ bias2, const float* res2,
    int nbm2, int N2, float al2,
    int K, int relu)
{
  __shared__ __align__(16) short smem[65536];   // 128 KiB
  const int total = gridDim.x;
  int bid = blockIdx.x;
  if ((total & 7) == 0) bid = (bid & 7)*(total >> 3) + (bid >> 3);   // bijective XCD swizzle
  const short* A; const short* B; float* Cf; short* Cb; const float* bias; const float* resid;
  int tile, nbm, N; float alpha;
  if (bid < nb0)       { A = A0p; B = B0p; Cf = C0f; Cb = C0b; bias = bias0; resid = res0;
                         tile = bid; nbm = nbm0; N = N0; alpha = al0; }
  else if (bid < nb01) { A = A1p; B = B1p; Cf = C1f; Cb = C1b; bias = bias1; resid = res1;
                         tile = bid - nb0; nbm = nbm1; N = N1; alpha = al1; }
  else                 { A = A2p; B = B2p; Cf = C2f; Cb = C2b; bias = bias2; resid = res2;
                         tile = bid - nb01; nbm = nbm2; N = N2; alpha = al2; }
  const int bm = tile % nbm, bn = tile / nbm;   // col-major: consecutive tiles share B panel
  const int m0 = bm << 8, n0 = bn << 8;
  const int t = threadIdx.x, lane = t & 63, w = t >> 6;
  const int wm = w >> 2, wn = w & 3;
  const int fr = lane & 15, fq = lane >> 4;
  const int ntk = K >> 6;                        // requires K % 128 == 0, K >= 256

  const int r0 = t >> 2, r1 = 128 + (t >> 2), gsw = t & 3;
  const int cs0 = (gsw ^ ((r0 >> 1) & 3)) << 3;
  const int cs1 = (gsw ^ ((r1 >> 1) & 3)) << 3;
  const short* gA0 = A + (size_t)(m0 + r0)*K + cs0;
  const short* gA1 = A + (size_t)(m0 + r1)*K + cs1;
  const short* gB0 = B + (size_t)(n0 + r0)*K + cs0;
  const short* gB1 = B + (size_t)(n0 + r1)*K + cs1;
  short* const ldA = smem + w*512;
  short* const ldB = smem + 32768 + w*512;

  int aoff[8], boff[4];
#pragma unroll
  for (int mi = 0; mi < 8; mi++) { const int r = wm*128 + mi*16 + fr; aoff[mi] = r*32 + ((fq ^ ((r >> 1) & 3)) << 3); }
#pragma unroll
  for (int ni = 0; ni < 4; ni++) { const int r = wn*64 + ni*16 + fr; boff[ni] = r*32 + ((fq ^ ((r >> 1) & 3)) << 3); }

  f4v acc[8][4] = {};
  s8v bv[4];

  ST_A(0,0,0); ST_B(0,0,0); ST_A(0,1,0); ST_B(0,1,0);
  ST_B(1,0,1); ST_A(1,0,1); ST_B(1,1,1);
  asm volatile("s_waitcnt vmcnt(6)" ::: "memory");
  __builtin_amdgcn_s_barrier();
  asm volatile("" ::: "memory");

  for (int it = 0, nit = (ntk >> 1) - 1; it < nit; ++it) {
    const int t1 = 2*it + 1, t2 = 2*it + 2, t3 = 2*it + 3;
    PH256(0,0,0, 1,0, ST_A(1,1,t1));   // ph1
    PH256(0,0,1, 0,0, ST_B(0,0,t2));   // ph2
    PH256(0,1,0, 1,0, ST_A(0,0,t2));   // ph3
    PH256(0,1,1, 0,1, ST_B(0,1,t2));   // ph4 + vmcnt(6)
    PH256(1,0,0, 1,0, ST_A(0,1,t2));   // ph5
    PH256(1,0,1, 0,0, ST_B(1,0,t3));   // ph6
    PH256(1,1,0, 1,0, ST_A(1,0,t3));   // ph7
    PH256(1,1,1, 0,1, ST_B(1,1,t3));   // ph8 + vmcnt(6)
  }
  PH256(0,0,0, 1,0, ST_A(1,1,ntk-1));
  PH256(0,0,1, 0,0, );
  PH256(0,1,0, 1,0, );
  PH256(0,1,1, 0,2, );                 // vmcnt(0): buf1 fully resident
  PH256(1,0,0, 1,0, );
  PH256(1,0,1, 0,0, );
  PH256(1,1,0, 1,0, );
  PH256(1,1,1, 0,0, );

#pragma unroll
  for (int mi = 0; mi < 8; mi++) {
    const int row = m0 + wm*128 + mi*16 + fq*4;
#pragma unroll
    for (int ni = 0; ni < 4; ni++) {
      const int col = n0 + wn*64 + ni*16 + fr;
      const float bvv = bias ? bias[col] : 0.f;
#pragma unroll
      for (int r = 0; r < 4; r++) {
        float v = acc[mi][ni][r]*alpha + bvv;
        const size_t idx = (size_t)(row + r)*N + col;
        if (resid) v += resid[idx];
        if (relu) v = fmaxf(v, 0.f);
        if (Cf) Cf[idx] = v;
        else Cb[idx] = f2bf(v);
      }
    }
  }
}

// ============ batched weight transpose: up to 8 f32[R,C] -> bf16[C,R], 1 tile/block ======
struct WTB {
  const float* src[8]; short* dst[8];
  int R[8], C[8], start[8];
  int NT;
};

__global__ __launch_bounds__(256) void wtransN(WTB b)
{
  __shared__ float t[32][33];
  const int id = blockIdx.x;
  if (id >= b.NT) return;
  int op = 0;
#pragma unroll
  for (int o = 1; o < 8; o++) if (id >= b.start[o]) op = o;
  const int loc = id - b.start[op];
  const int Cd = b.C[op], Rd = b.R[op];
  const int ncx = Cd >> 5;
  const int cx = (loc % ncx) << 5, ry = (loc / ncx) << 5;
  const float* s = b.src[op];
  short* d = b.dst[op];
  const int tx = threadIdx.x, ty = threadIdx.y;
#pragma unroll
  for (int k = 0; k < 4; k++)
    t[ty + k*8][tx] = s[(size_t)(ry + ty + k*8)*Cd + cx + tx];
  __syncthreads();
#pragma unroll
  for (int k = 0; k < 4; k++)
    d[(size_t)(cx + ty + k*8)*Rd + ry + tx] = f2bf(t[tx][ty + k*8]);
}

// ============ btrans2: v1b -> v1T and v2b -> v2T in one launch ============
__global__ __launch_bounds__(256) void btrans2(
    const short* __restrict__ v1b, short* __restrict__ v1T,
    const short* __restrict__ v2b, short* __restrict__ v2T)
{
  __shared__ short t[32][33];
  const int z = blockIdx.z, b = z >> 3, h = z & 7;
  int y = blockIdx.y;
  const short* S; short* D; int ld_;
  if (y < 32) { S = v1b + ((size_t)b*1024)*1536 + h*192; D = v1T + (size_t)z*196608; ld_ = 1024; }
  else { y -= 32; S = v2b + ((size_t)b*768)*1536 + h*192; D = v2T + (size_t)z*147456; ld_ = 768; }
  const int c0 = blockIdx.x*32, r0 = y*32;
  const int tx = threadIdx.x, ty = threadIdx.y;
#pragma unroll
  for (int k = 0; k < 4; k++)
    t[ty + k*8][tx] = S[(size_t)(r0 + ty + k*8)*1536 + c0 + tx];
  __syncthreads();
#pragma unroll
  for (int k = 0; k < 4; k++)
    D[(size_t)(c0 + ty + k*8)*ld_ + r0 + tx] = t[tx][ty + k*8];
}

// ============ f32 -> bf16 convert ============
__global__ __launch_bounds__(256) void conv_bf(const float* __restrict__ src,
                                               short* __restrict__ dst, long long n)
{
  const long long i = ((long long)blockIdx.x*256 + threadIdx.x)*4;
  if (i >= n) return;
  const float4 v = *(const float4*)(src + i);
  s4v o = { f2bf(v.x), f2bf(v.y), f2bf(v.z), f2bf(v.w) };
  *(s4v*)(dst + i) = o;
}

// ============ LayerNorm over 1536 cols, f32 in -> bf16 out ============
__global__ __launch_bounds__(256) void ln_k(const float* __restrict__ in,
    const float* __restrict__ gam, const float* __restrict__ bet, short* __restrict__ out)
{
  const long long row = blockIdx.x;
  const float* r = in + row*1536;
  const int tid = threadIdx.x;
  float v[6], s = 0.f, s2 = 0.f;
#pragma unroll
  for (int i = 0; i < 6; i++) { v[i] = r[tid + i*256]; s += v[i]; s2 += v[i]*v[i]; }
  for (int m = 1; m < 64; m <<= 1) { s += __shfl_xor(s, m); s2 += __shfl_xor(s2, m); }
  __shared__ float rs[4], rs2[4];
  if ((tid & 63) == 0) { rs[tid>>6] = s; rs2[tid>>6] = s2; }
  __syncthreads();
  s = rs[0]+rs[1]+rs[2]+rs[3]; s2 = rs2[0]+rs2[1]+rs2[2]+rs2[3];
  const float mu  = s * (1.f/1536.f);
  const float var = s2 * (1.f/1536.f) - mu*mu;
  const float inv = rsqrtf(var + 1e-5f);
  short* o = out + row*1536;
#pragma unroll
  for (int i = 0; i < 6; i++) { int c = tid + i*256; o[c] = f2bf((v[i]-mu)*inv*gam[c] + bet[c]); }
}

// ============ ln2_k: both FFN layernorms in one launch ====
__global__ __launch_bounds__(256) void ln2_k(
    const float* __restrict__ in1, const float* __restrict__ g1, const float* __restrict__ b1,
    short* __restrict__ o1,
    const float* __restrict__ in2, const float* __restrict__ g2, const float* __restrict__ b2,
    short* __restrict__ o2)
{
  long long row = blockIdx.x;
  const float* in; const float* gam; const float* bet; short* out;
  if (row < 4096) { in = in1; gam = g1; bet = b1; out = o1; }
  else { row -= 4096; in = in2; gam = g2; bet = b2; out = o2; }
  const float* r = in + row*1536;
  const int tid = threadIdx.x;
  float v[6], s = 0.f, s2 = 0.f;
#pragma unroll
  for (int i = 0; i < 6; i++) { v[i] = r[tid + i*256]; s += v[i]; s2 += v[i]*v[i]; }
  for (int m = 1; m < 64; m <<= 1) { s += __shfl_xor(s, m); s2 += __shfl_xor(s2, m); }
  __shared__ float rs[4], rs2[4];
  if ((tid & 63) == 0) { rs[tid>>6] = s; rs2[tid>>6] = s2; }
  __syncthreads();
  s = rs[0]+rs[1]+rs[2]+rs[3]; s2 = rs2[0]+rs2[1]+rs2[2]+rs2[3];
  const float mu  = s * (1.f/1536.f);
  const float var = s2 * (1.f/1536.f) - mu*mu;
  const float inv = rsqrtf(var + 1e-5f);
  short* o = out + row*1536;
#pragma unroll
  for (int i = 0; i < 6; i++) { int c = tid + i*256; o[c] = f2bf((v[i]-mu)*inv*gam[c] + bet[c]); }
}

// ============ positional features: out bf16 [2047][192] ============
__global__ __launch_bounds__(64) void posemb(short* __restrict__ out)
{
  const int i = blockIdx.x;
  const int j = threadIdx.x;
  const float dist = (float)(i - 1023);
  const float absd = fabsf(dist);
  float fe = 0.f, fc = 0.f, prob = 0.f;
  if (j < 32) {
    const float hl = exp2f(3.f + 7.f*(float)j/31.f);
    fe = expf(-0.6931471805599453f/hl * absd);
    const float width = exp2f((float)(j+1)) - 1.f;
    fc = (width > absd) ? 1.f : 0.f;
    const float m = 32.f*(float)(j+1);
    const float conc = (m/16.f)*(m/16.f);
    const float rate = m/256.f;
    const float logp = (absd > 0.f ? (conc-1.f)*logf(absd) : -INFINITY) - rate*absd;
    const float logn = lgammaf(conc) - conc*logf(rate);
    prob = expf(logp - logn) + 1e-8f;
  }
  float mx = prob;
  for (int m = 1; m < 32; m <<= 1) mx = fmaxf(mx, __shfl_xor(mx, m));
  if (j < 32) {
    const float fg = prob / mx;
    const float sg = dist > 0.f ? 1.f : (dist < 0.f ? -1.f : 0.f);
    const size_t base = (size_t)i*192;
    out[base + j]       = f2bf(fe);
    out[base + 32 + j]  = f2bf(fc);
    out[base + 64 + j]  = f2bf(fg);
    out[base + 96 + j]  = f2bf(sg*fe);
    out[base + 128 + j] = f2bf(sg*fc);
    out[base + 160 + j] = f2bf(sg*fg);
  }
}

// ============ rel bias table: T[h][n] = dot64(rpb[h], relq[n,h*64:]) ============
__global__ __launch_bounds__(256) void relbias_k(const float* __restrict__ rpb,
    const short* __restrict__ relq, float* __restrict__ T)
{
  const int n = blockIdx.x;
  const int tid = threadIdx.x;
  const int h = tid >> 5, l = tid & 31;
  const int d = l*2;
  float s = rpb[h*64+d]   * bf2f(relq[(size_t)n*512 + h*64 + d])
          + rpb[h*64+d+1] * bf2f(relq[(size_t)n*512 + h*64 + d+1]);
  for (int m = 1; m < 32; m <<= 1) s += __shfl_xor(s, m);
  if (l == 0) T[h*2047 + n] = s;
}

// ============ fused scores -> BF16 logits =====
__global__ __launch_bounds__(256) void scores_k(
    const short* __restrict__ qb, const short* __restrict__ kb,
    const short* __restrict__ relq, const float* __restrict__ T,
    short* __restrict__ L)
{
  __shared__ __align__(16) short smem[21504];
  short* kt  = smem;                 // 64*72
  short* qt  = smem + 4608;          // 64*72
  short* rqt = smem + 4608;          // 128*72 (over qt)
  float* P   = (float*)(smem + 4608);// 64*132 f32 (over rqt)

  const int z = blockIdx.z, b = z >> 3, h = z & 7;
  const int j0 = blockIdx.x*64, i0 = blockIdx.y*64;
  const int tid = threadIdx.x, lane = tid & 63, wv = tid >> 6;
  const int fr = lane & 15, fq = lane >> 4;

  {
    const short* kg = kb + (size_t)(b*768  + j0)*512 + h*64;
    const short* qg = qb + (size_t)(b*1024 + i0)*512 + h*64;
    for (int c = tid; c < 512; c += 256) {
      const int r = c >> 3, ch = (c & 7)*8;
      *(s8v*)&kt[r*72 + ch] = *(const s8v*)&kg[(size_t)r*512 + ch];
      *(s8v*)&qt[r*72 + ch] = *(const s8v*)&qg[(size_t)r*512 + ch];
    }
  }
  __syncthreads();

  const int wi = (wv & 1)*32, wj = (wv >> 1)*32;
  f4v c2[2][2] = {};
#pragma unroll
  for (int ks = 0; ks < 2; ks++) {
    s8v aq[2], bk[2];
#pragma unroll
    for (int mi = 0; mi < 2; mi++) aq[mi] = *(const s8v*)&qt[(wi + mi*16 + fr)*72 + ks*32 + fq*8];
#pragma unroll
    for (int ni = 0; ni < 2; ni++) bk[ni] = *(const s8v*)&kt[(wj + ni*16 + fr)*72 + ks*32 + fq*8];
#pragma unroll
    for (int mi = 0; mi < 2; mi++)
#pragma unroll
      for (int ni = 0; ni < 2; ni++)
        c2[mi][ni] = __builtin_amdgcn_mfma_f32_16x16x32_bf16(aq[mi], bk[ni], c2[mi][ni], 0, 0, 0);
  }
  __syncthreads();

  const int nbase = 704 + i0 - j0;
  {
    const short* rg = relq + (size_t)nbase*512 + h*64;
    for (int c = tid; c < 1024; c += 256) {
      const int r = c >> 3, ch = (c & 7)*8;
      *(s8v*)&rqt[r*72 + ch] = *(const s8v*)&rg[(size_t)r*512 + ch];
    }
  }
  __syncthreads();

  const int wj2 = (wv & 1)*32, wn2 = (wv >> 1)*64;
  f4v pr[2][4] = {};
#pragma unroll
  for (int ks = 0; ks < 2; ks++) {
    s8v a2[2], b2[4];
#pragma unroll
    for (int mi = 0; mi < 2; mi++) a2[mi] = *(const s8v*)&kt[(wj2 + mi*16 + fr)*72 + ks*32 + fq*8];
#pragma unroll
    for (int ni = 0; ni < 4; ni++) b2[ni] = *(const s8v*)&rqt[(wn2 + ni*16 + fr)*72 + ks*32 + fq*8];
#pragma unroll
    for (int mi = 0; mi < 2; mi++)
#pragma unroll
      for (int ni = 0; ni < 4; ni++)
        pr[mi][ni] = __builtin_amdgcn_mfma_f32_16x16x32_bf16(a2[mi], b2[ni], pr[mi][ni], 0, 0, 0);
  }
  __syncthreads();

#pragma unroll
  for (int mi = 0; mi < 2; mi++)
#pragma unroll
    for (int ni = 0; ni < 4; ni++)
#pragma unroll
      for (int r = 0; r < 4; r++)
        P[(wj2 + mi*16 + fq*4 + r)*132 + wn2 + ni*16 + fr] = pr[mi][ni][r];
  __syncthreads();

  const float* Tt = T + h*2047 + nbase;
  short* Lb = L + ((size_t)z*1024 + i0)*768 + j0;
#pragma unroll
  for (int mi = 0; mi < 2; mi++)
#pragma unroll
    for (int ni = 0; ni < 2; ni++)
#pragma unroll
      for (int r = 0; r < 4; r++) {
        const int il = wi + mi*16 + fq*4 + r;
        const int jl = wj + ni*16 + fr;
        const int nl = 63 + il - jl;
        Lb[(size_t)il*768 + jl] = f2bf(c2[mi][ni][r] + 0.125f*P[jl*132 + nl] + Tt[nl]);
      }
}

// ============ softmax2d: bf16 logits -> attnb (row-major) + attnT (transposed) ============
__global__ __launch_bounds__(256) void softmax2d(const short* __restrict__ L,
    short* __restrict__ attnb, short* __restrict__ attnT)
{
  __shared__ __align__(16) short pt[32*776];    // 49,664 B; stride 776
  const int ic = blockIdx.x, z = blockIdx.y;
  const int t = threadIdx.x, wv = t >> 6, lane = t & 63;
  const int rl = wv*8 + (lane >> 3);            // local row 0..31
  const int cs = (lane & 7)*96;                 // col segment start
  const size_t rowg = ((size_t)z*1024 + ic*32 + rl)*768;

  s8v v[12];
#pragma unroll
  for (int k = 0; k < 12; k++) v[k] = *(const s8v*)&L[rowg + cs + k*8];

  float mx = -1e30f;
#pragma unroll
  for (int k = 0; k < 12; k++)
#pragma unroll
    for (int e = 0; e < 8; e++) mx = fmaxf(mx, bf2f(v[k][e]));
  mx = fmaxf(mx, __shfl_xor(mx, 1));
  mx = fmaxf(mx, __shfl_xor(mx, 2));
  mx = fmaxf(mx, __shfl_xor(mx, 4));

  float s = 0.f;
#pragma unroll
  for (int k = 0; k < 12; k++)
#pragma unroll
    for (int e = 0; e < 8; e++) s += __expf(bf2f(v[k][e]) - mx);
  s += __shfl_xor(s, 1);
  s += __shfl_xor(s, 2);
  s += __shfl_xor(s, 4);
  const float inv = 1.f / s;

  short* ab = attnb + rowg;
#pragma unroll
  for (int k = 0; k < 12; k++) {
    s8v o;
#pragma unroll
    for (int e = 0; e < 8; e++) o[e] = f2bf(__expf(bf2f(v[k][e]) - mx) * inv);
    *(s8v*)&ab[cs + k*8] = o;
    *(s8v*)&pt[rl*776 + cs + k*8] = o;
  }
  __syncthreads();

  short* aT = attnT + (size_t)z*786432 + (size_t)ic*32;
  const int i4 = (lane & 7)*4, jb = lane >> 3;
  for (int jj = 0; jj < 24; jj++) {
    const int j = wv*192 + jj*8 + jb;
    s4v o;
#pragma unroll
    for (int e = 0; e < 4; e++) o[e] = pt[(i4 + e)*776 + j];
    *(s4v*)&aT[(size_t)j*1024 + i4] = o;
  }
}

// ======================= host =======================
static void gemm(hipStream_t st, const short* A, const short* B, float* Cf, short* Cb,
                 const float* bias, const float* resid,
                 int M, int N, int K, int lda, int ldb, int ldc,
                 int batches = 1,
                 long long sAo = 0, long long sAi = 0, long long sBo = 0, long long sBi = 0,
                 long long sCo = 0, long long sCi = 0, float alpha = 1.f, int relu = 0)
{
  dim3 g((N + 127)/128, (M + 127)/128, batches);
  gemm_bt<<<g, dim3(256), 0, st>>>(A, B, Cf, Cb, bias, resid, M, N, K, lda, ldb, ldc,
                                   sAo, sAi, sBo, sBi, sCo, sCi, alpha, relu);
}

static void g256_3(hipStream_t st,
    const short* A0, const short* B0, float* C0f, short* C0b, const float* bias0, const float* res0,
    int M0, int N0, float al0,
    const short* A1, const short* B1, float* C1f, short* C1b, const float* bias1, const float* res1,
    int M1, int N1, float al1,
    const short* A2, const short* B2, float* C2f, short* C2b, const float* bias2, const float* res2,
    int M2, int N2, float al2,
    int K, int relu)
{
  const int nbm0 = M0 >> 8, nb0 = nbm0*(N0 >> 8);
  const int nbm1 = M1 >> 8, nb1 = nbm1*(N1 >> 8);
  const int nbm2 = M2 >> 8, nb2 = M2 ? nbm2*(N2 >> 8) : 0;
  gemm256<<<dim3(nb0 + nb1 + nb2), dim3(512), 0, st>>>(
      A0, B0, C0f, C0b, bias0, res0, nb0, nbm0, N0, al0,
      A1, B1, C1f, C1b, bias1, res1, nb0 + nb1, nbm1, N1, al1,
      A2, B2, C2f, C2b, bias2, res2, nbm2, N2, al2, K, relu);
}

static void g256(hipStream_t st,
    const short* A0, const short* B0, float* C0f, short* C0b, const float* bias0, const float* res0,
    int M0, int N0, float al0,
    const short* A1, const short* B1, float* C1f, short* C1b, const float* bias1, const float* res1,
    int M1, int N1, float al1,
    int K, int relu)
{
  g256_3(st, A0, B0, C0f, C0b, bias0, res0, M0, N0, al0,
         A1, B1, C1f, C1b, bias1, res1, M1, N1, al1,
         nullptr, nullptr, nullptr, nullptr, nullptr, nullptr, 0, 256, 1.f, K, relu);
}

extern "C" void kernel_launch(void* const* d_in, const int* in_sizes, int n_in,
                              void* d_out, int out_size, void* d_ws, size_t ws_size,
                              hipStream_t stream)
{
  (void)in_sizes; (void)n_in; (void)out_size; (void)ws_size;
  const float* x     = (const float*)d_in[0];
  const float* y0    = (const float*)d_in[1];
  const float* lnxg  = (const float*)d_in[3];
  const float* lnxb  = (const float*)d_in[4];
  const float* lnyg  = (const float*)d_in[5];
  const float* lnyb  = (const float*)d_in[6];
  const float* rpb   = (const float*)d_in[12];
  const float* bo1   = (const float*)d_in[14];
  const float* bo2   = (const float*)d_in[16];
  const float* fxg   = (const float*)d_in[17];
  const float* fxbb  = (const float*)d_in[18];
  const float* fxb1  = (const float*)d_in[20];
  const float* fxb2  = (const float*)d_in[22];
  const float* fyg   = (const float*)d_in[23];
  const float* fybb  = (const float*)d_in[24];
  const float* fyb1  = (const float*)d_in[26];
  const float* fyb2  = (const float*)d_in[28];

  char* base = (char*)d_ws;
  size_t off = 0;
  auto bump = [&](size_t b) -> char* { char* p = base + off; off += (b + 255) & ~(size_t)255; return p; };

  // ---- pooled weight buffers (bf16, transposed [N,K]) ----
  short* W_A  = (short*)bump(4718592);   // resT -> wo1T           (1536x1536)
  short* W_B  = (short*)bump(1572864);   // wqT                    (512x1536)
  short* W_B2 = (short*)bump(1572864);   // wkT                    (512x1536)
  short* W_C  = (short*)bump(4718592);   // wv1T -> wo2T           (1536x1536)
  short* W_D  = (short*)bump(196608);    // relT                   (512x192)
  short* W_E  = (short*)bump(9437184);   // fx1T                   (3072x1536)
  short* W_F  = (short*)bump(9437184);   // fx2T                   (1536x3072)

  char*  uB = bump(12582912);
  short* x1   = (short*)uB;
  short* v1T  = (short*)uB;
  char*  uC = bump(9437184);
  short* y1   = (short*)uC;
  short* out2 = (short*)uC;
  char*  uD = bump(9437184);
  short* y0b = (short*)uD;
  short* qb  = (short*)uD;
  short* kbB = (short*)(uD + 4194304);
  short* v2T = (short*)uD;
  float* Tbl   = (float*)bump(262016);
  short* posb  = (short*)bump(786048);
  short* relqb = (short*)bump(2096128);
  char*  uG = bump(12582912);
  short* v1b  = (short*)uG;
  short* out1 = (short*)uG;
  short* x4ln = (short*)uG;
  char*  uH = bump(9437184);   short* v2b = (short*)uH;  short* y4ln = (short*)uH;
  char*  uI = bump(100663296);
  short* wv2T    = (short*)uI;
  short* logits16 = (short*)uI;
  short* attnT   = (short*)(uI + 50331648);
  short* hx      = (short*)uI;
  short* hy      = (short*)(uI + 25165824);
  short* fy1T    = (short*)(uI + 46137344);
  short* fy2T    = (short*)(uI + 55574528);
  char*  U2 = bump(50331648);
  short* attnb = (short*)U2;
  float* y4    = (float*)U2;

  float* outx = (float*)d_out;
  float* outy = (float*)d_out + 6291456;
  float* x4  = outx;
  float* y_f = outy;

  auto addop = [&](WTB& b, int i, int idx, short* dst, int R, int C) {
    b.src[i] = (const float*)d_in[idx]; b.dst[i] = dst;
    b.R[i] = R; b.C[i] = C; b.start[i] = b.NT; b.NT += (R >> 5)*(C >> 5);
  };
  auto finwtb = [&](WTB& b, int n) {
    for (int i = n; i < 8; i++) { b.start[i] = 0x7fffffff; b.src[i] = nullptr; b.dst[i] = nullptr; b.R[i] = 32; b.C[i] = 32; }
  };

  // B1: all weights needed through v2qk + ffn-x
  WTB b1{}; b1.NT = 0;
  addop(b1, 0, 2,  W_A,  1536, 1536);   // res_w
  addop(b1, 1, 11, W_D,  192,  512);    // wrel
  addop(b1, 2, 9,  W_C,  1536, 1536);   // wv1
  addop(b1, 3, 10, wv2T, 1536, 1536);   // wv2
  addop(b1, 4, 7,  W_B,  1536, 512);    // wq
  addop(b1, 5, 8,  W_B2, 1536, 512);    // wk
  addop(b1, 6, 19, W_E,  1536, 3072);   // fx_w1
  addop(b1, 7, 21, W_F,  3072, 1536);   // fx_w2
  wtransN<<<dim3(b1.NT), dim3(32,8), 0, stream>>>(b1);

  // prep: y0 -> bf16 ; positional features ; ln_x
  conv_bf<<<4608, 256, 0, stream>>>(y0, y0b, 4718592LL);
  posemb<<<2047, 64, 0, stream>>>(posb);
  ln_k<<<4096, 256, 0, stream>>>(x, lnxg, lnxb, x1);
  // relq = pos @ wrel ; rel bias table
  gemm(stream, posb, W_D, nullptr, relqb, nullptr, nullptr, 2047, 512, 192, 192, 192, 512);
  relbias_k<<<2047, 256, 0, stream>>>(rpb, relqb, Tbl);
  // launch1: res = y0@res_w -> y_f + v1 = x1@wv1
  g256(stream, y0b, W_A, y_f, nullptr, nullptr, nullptr, 3072, 1536, 1.f,
       x1, W_C, nullptr, v1b, nullptr, nullptr, 4096, 1536, 1.f, 1536, 0);
  // B2: wo1 -> W_A, wo2 -> W_C
  WTB b2{}; b2.NT = 0;
  addop(b2, 0, 13, W_A, 1536, 1536);
  addop(b2, 1, 15, W_C, 1536, 1536);
  finwtb(b2, 2);
  wtransN<<<dim3(b2.NT), dim3(32,8), 0, stream>>>(b2);
  // ln_y
  ln_k<<<3072, 256, 0, stream>>>(y_f, lnyg, lnyb, y1);
  // v2 + q + k
  g256_3(stream, y1, wv2T, nullptr, v2b, nullptr, nullptr, 3072, 1536, 1.f,
         x1, W_B, nullptr, qb, nullptr, nullptr, 4096, 512, 0.125f,
         y1, W_B2, nullptr, kbB, nullptr, nullptr, 3072, 512, 1.f, 1536, 0);
  // fused scores -> bf16 logits
  scores_k<<<dim3(12,16,32), 256, 0, stream>>>(qb, kbB, relqb, Tbl, logits16);
  // softmax2d -> attnb + attnT
  softmax2d<<<dim3(32,32), 256, 0, stream>>>(logits16, attnb, attnT);
  // btrans2: v1T (uB) + v2T (uD) in one launch
  btrans2<<<dim3(6,56,32), dim3(32,8), 0, stream>>>(v1b, v1T, v2b, v2T);
  // pv_k: out1 = attn@v2 (-> uG) and out2 = attn^T@v1 (-> uC) in one launch
  pv_k<<<dim3(2,14,32), 256, 0, stream>>>(attnb, v2T, out1, attnT, v1T, out2);
  // B3: fy1 -> fy1T, fy2 -> fy2T (uI attn regions dead)
  WTB b3{}; b3.NT = 0;
  addop(b3, 0, 25, fy1T, 1536, 3072);
  addop(b3, 1, 27, fy2T, 3072, 1536);
  finwtb(b3, 2);
  wtransN<<<dim3(b3.NT), dim3(32,8), 0, stream>>>(b3);
  // wo-pair: x4 = x + out1@wo1 + bo1 ; y4 = y + out2@wo2 + bo2
  g256(stream, out1, W_A, x4, nullptr, bo1, x, 4096, 1536, 1.f,
       out2, W_C, y4, nullptr, bo2, y_f, 3072, 1536, 1.f, 1536, 0);
  // merged FFN LayerNorms
  ln2_k<<<7168, 256, 0, stream>>>(x4, fxg, fxbb, x4ln, y4, fyg, fybb, y4ln);
  // ffn1: hidden = relu(ln @ w1 + b1)
  g256(stream, x4ln, W_E, nullptr, hx, fxb1, nullptr, 4096, 3072, 1.f,
       y4ln, fy1T, nullptr, hy, fyb1, nullptr, 3072, 3072, 1.f, 1536, 1);
  // ffn2: out = resid + h @ w2 + b2  (in-place on outx)
  g256(stream, hx, W_F, outx, nullptr, fxb2, x4, 4096, 1536, 1.f,
       hy, fy2T, outy, nullptr, fyb2, y4, 3072, 1536, 1.f, 3072, 0);
}

// Round 16
// 645.725 us; speedup vs baseline: 1.0511x; 1.0084x over previous
//
#include <hip/hip_runtime.h>
#include <stdint.h>
#include <math.h>

typedef __attribute__((ext_vector_type(8))) short s8v;
typedef __attribute__((ext_vector_type(4))) short s4v;
typedef __attribute__((ext_vector_type(4))) float f4v;

#define DEV static __device__ __forceinline__

DEV short f2bf(float f) {
  uint32_t u = __builtin_bit_cast(uint32_t, f);
  u += 0x7FFFu + ((u >> 16) & 1u);   // round-to-nearest-even
  return (short)(u >> 16);
}
DEV float bf2f(short s) {
  uint32_t u = ((uint32_t)(uint16_t)s) << 16;
  return __builtin_bit_cast(float, u);
}

#define GLD16(g, l) __builtin_amdgcn_global_load_lds( \
    (const __attribute__((address_space(1))) void*)(g), \
    (__attribute__((address_space(3))) void*)(l), 16, 0, 0)

// ================= 128x128 GEMM (m97 structure) for small/odd/batched shapes =========
__global__ __launch_bounds__(256) void gemm_bt(
    const short* __restrict__ A, const short* __restrict__ B,
    float* Cf, short* Cb,
    const float* __restrict__ bias, const float* resid,
    int M, int N, int K, int lda, int ldb, int ldc,
    long long sAo, long long sAi, long long sBo, long long sBi,
    long long sCo, long long sCi, float alpha, int relu)
{
  __shared__ __align__(16) short lA[128*32];
  __shared__ __align__(16) short lB[128*32];
  const int z = blockIdx.z, zo = z >> 3, zi = z & 7;
  const short* Ab = A + zo*sAo + zi*sAi;
  const short* Bb = B + zo*sBo + zi*sBi;
  const long long cOff = zo*sCo + zi*sCi;

  const int m0 = blockIdx.y*128, n0 = blockIdx.x*128;
  const int tid = threadIdx.x, lane = tid & 63, wv = tid >> 6;
  const int wm = (wv >> 1)*64, wn = (wv & 1)*64;
  const int fr = lane & 15, fq = lane >> 4;

  f4v acc[4][4] = {};

  const int rA0 = min(m0 + (tid >> 2), M - 1);
  const int rA1 = min(m0 + 64 + (tid >> 2), M - 1);
  const int rB0 = min(n0 + (tid >> 2), N - 1);
  const int rB1 = min(n0 + 64 + (tid >> 2), N - 1);
  const int pc = (tid & 3) * 8;
  const short* gA0 = Ab + (size_t)rA0*lda + pc;
  const short* gA1 = Ab + (size_t)rA1*lda + pc;
  const short* gB0 = Bb + (size_t)rB0*ldb + pc;
  const short* gB1 = Bb + (size_t)rB1*ldb + pc;
  short* dA0 = lA + (wv*64)*8;
  short* dA1 = lA + (256 + wv*64)*8;
  short* dB0 = lB + (wv*64)*8;
  short* dB1 = lB + (256 + wv*64)*8;

  for (int k0 = 0; k0 < K; k0 += 32) {
    GLD16(gA0 + k0, dA0);
    GLD16(gA1 + k0, dA1);
    GLD16(gB0 + k0, dB0);
    GLD16(gB1 + k0, dB1);
    __syncthreads();
    s8v af[4], bg[4];
#pragma unroll
    for (int i = 0; i < 4; i++) {
      af[i] = *(const s8v*)&lA[(wm + i*16 + fr)*32 + fq*8];
      bg[i] = *(const s8v*)&lB[(wn + i*16 + fr)*32 + fq*8];
    }
#pragma unroll
    for (int mi = 0; mi < 4; mi++)
#pragma unroll
      for (int ni = 0; ni < 4; ni++)
        acc[mi][ni] = __builtin_amdgcn_mfma_f32_16x16x32_bf16(af[mi], bg[ni], acc[mi][ni], 0, 0, 0);
    __syncthreads();
  }

#pragma unroll
  for (int mi = 0; mi < 4; mi++) {
    const int row = m0 + wm + mi*16 + fq*4;
#pragma unroll
    for (int ni = 0; ni < 4; ni++) {
      const int col = n0 + wn + ni*16 + fr;
      if (col >= N) continue;
      const float bv = bias ? bias[col] : 0.f;
#pragma unroll
      for (int r = 0; r < 4; r++) {
        if (row + r >= M) continue;
        float v = acc[mi][ni][r] * alpha + bv;
        const long long idx = cOff + (long long)(row + r)*ldc + col;
        if (resid) v += resid[idx];
        if (relu) v = fmaxf(v, 0.f);
        if (Cf) Cf[idx] = v;
        if (Cb) Cb[idx] = f2bf(v);
      }
    }
  }
}

// ================= pv_k: out1 = attn@v2 and out2 = attn^T@v1 in ONE launch ======
__global__ __launch_bounds__(256) void pv_k(
    const short* __restrict__ attnb, const short* __restrict__ v2T, short* __restrict__ out1,
    const short* __restrict__ attnT, const short* __restrict__ v1T, short* __restrict__ out2)
{
  __shared__ __align__(16) short lA[128*32];
  __shared__ __align__(16) short lB[128*32];
  const int z = blockIdx.z, b = z >> 3, h = z & 7;
  const short* A; const short* B; short* C; int M, K, lda, m0;
  if (blockIdx.y < 8) {
    A = attnb + (size_t)z*786432; B = v2T + (size_t)z*147456;
    C = out1 + ((size_t)b*1024)*1536 + h*192;
    M = 1024; K = 768; lda = 768; m0 = blockIdx.y*128;
  } else {
    A = attnT + (size_t)z*786432; B = v1T + (size_t)z*196608;
    C = out2 + ((size_t)b*768)*1536 + h*192;
    M = 768; K = 1024; lda = 1024; m0 = (blockIdx.y - 8)*128;
  }
  const int N = 192, ldc = 1536, ldb = lda;
  const int n0 = blockIdx.x*128;
  const int tid = threadIdx.x, lane = tid & 63, wv = tid >> 6;
  const int wm = (wv >> 1)*64, wn = (wv & 1)*64;
  const int fr = lane & 15, fq = lane >> 4;

  f4v acc[4][4] = {};

  const int rA0 = m0 + (tid >> 2);
  const int rA1 = m0 + 64 + (tid >> 2);
  const int rB0 = min(n0 + (tid >> 2), N - 1);
  const int rB1 = min(n0 + 64 + (tid >> 2), N - 1);
  const int pc = (tid & 3) * 8;
  const short* gA0 = A + (size_t)rA0*lda + pc;
  const short* gA1 = A + (size_t)rA1*lda + pc;
  const short* gB0 = B + (size_t)rB0*ldb + pc;
  const short* gB1 = B + (size_t)rB1*ldb + pc;
  short* dA0 = lA + (wv*64)*8;
  short* dA1 = lA + (256 + wv*64)*8;
  short* dB0 = lB + (wv*64)*8;
  short* dB1 = lB + (256 + wv*64)*8;

  for (int k0 = 0; k0 < K; k0 += 32) {
    GLD16(gA0 + k0, dA0);
    GLD16(gA1 + k0, dA1);
    GLD16(gB0 + k0, dB0);
    GLD16(gB1 + k0, dB1);
    __syncthreads();
    s8v af[4], bg[4];
#pragma unroll
    for (int i = 0; i < 4; i++) {
      af[i] = *(const s8v*)&lA[(wm + i*16 + fr)*32 + fq*8];
      bg[i] = *(const s8v*)&lB[(wn + i*16 + fr)*32 + fq*8];
    }
#pragma unroll
    for (int mi = 0; mi < 4; mi++)
#pragma unroll
      for (int ni = 0; ni < 4; ni++)
        acc[mi][ni] = __builtin_amdgcn_mfma_f32_16x16x32_bf16(af[mi], bg[ni], acc[mi][ni], 0, 0, 0);
    __syncthreads();
  }

#pragma unroll
  for (int mi = 0; mi < 4; mi++) {
    const int row = m0 + wm + mi*16 + fq*4;
#pragma unroll
    for (int ni = 0; ni < 4; ni++) {
      const int col = n0 + wn + ni*16 + fr;
      if (col >= N) continue;
#pragma unroll
      for (int r = 0; r < 4; r++)
        C[(size_t)(row + r)*ldc + col] = f2bf(acc[mi][ni][r]);
    }
  }
}

// ================= 256x256 8-phase GEMM (r6 single-barrier schedule) ======
#define ST_A(buf, ks, tt) do { const int ko = ((tt)<<6) + ((ks)<<5); \
    GLD16(gA0 + ko, ldA + ((buf)*2+(ks))*8192); \
    GLD16(gA1 + ko, ldA + ((buf)*2+(ks))*8192 + 4096); } while(0)
#define ST_B(buf, ks, tt) do { const int ko = ((tt)<<6) + ((ks)<<5); \
    GLD16(gB0 + ko, ldB + ((buf)*2+(ks))*8192); \
    GLD16(gB1 + ko, ldB + ((buf)*2+(ks))*8192 + 4096); } while(0)

#define PH256(buf, ks, mig, READB, DOWAIT, ...) do { \
    s8v av[4]; \
    const int rb = ((buf)*2+(ks))*8192; \
    _Pragma("unroll") for (int q2 = 0; q2 < 4; q2++) av[q2] = *(const s8v*)&smem[rb + aoff[(mig)*4+q2]]; \
    if (READB) { _Pragma("unroll") for (int q2 = 0; q2 < 4; q2++) bv[q2] = *(const s8v*)&smem[32768 + rb + boff[q2]]; } \
    __VA_ARGS__; \
    if (DOWAIT == 1) asm volatile("s_waitcnt vmcnt(6)" ::: "memory"); \
    if (DOWAIT == 2) asm volatile("s_waitcnt vmcnt(0)" ::: "memory"); \
    __builtin_amdgcn_s_barrier(); \
    asm volatile("s_waitcnt lgkmcnt(0)" ::: "memory"); \
    __builtin_amdgcn_s_setprio(1); \
    _Pragma("unroll") for (int q2 = 0; q2 < 4; q2++) \
      _Pragma("unroll") for (int u2 = 0; u2 < 4; u2++) \
        acc[(mig)*4+q2][u2] = __builtin_amdgcn_mfma_f32_16x16x32_bf16(av[q2], bv[u2], acc[(mig)*4+q2][u2], 0, 0, 0); \
    __builtin_amdgcn_s_setprio(0); \
  } while(0)

__global__ __launch_bounds__(512) void gemm256(
    const short* __restrict__ A0p, const short* __restrict__ B0p,
    float* C0f, short* C0b, const float* __restrict__ bias0, const float* res0,
    int nb0, int nbm0, int N0, float al0,
    const short* __restrict__ A1p, const short* __restrict__ B1p,
    float* C1f, short* C1b, const float* __restrict__ bias1, const float* res1,
    int nb01, int nbm1, int N1, float al1,
    const short* __restrict__ A2p, const short* __restrict__ B2p,
    float* C2f, short* C2b, const float* __restrict__ bias2, const float* res2,
    int nbm2, int N2, float al2,
    int K, int relu)
{
  __shared__ __align__(16) short smem[65536];   // 128 KiB
  const int total = gridDim.x;
  int bid = blockIdx.x;
  if ((total & 7) == 0) bid = (bid & 7)*(total >> 3) + (bid >> 3);   // bijective XCD swizzle
  const short* A; const short* B; float* Cf; short* Cb; const float* bias; const float* resid;
  int tile, nbm, N; float alpha;
  if (bid < nb0)       { A = A0p; B = B0p; Cf = C0f; Cb = C0b; bias = bias0; resid = res0;
                         tile = bid; nbm = nbm0; N = N0; alpha = al0; }
  else if (bid < nb01) { A = A1p; B = B1p; Cf = C1f; Cb = C1b; bias = bias1; resid = res1;
                         tile = bid - nb0; nbm = nbm1; N = N1; alpha = al1; }
  else                 { A = A2p; B = B2p; Cf = C2f; Cb = C2b; bias = bias2; resid = res2;
                         tile = bid - nb01; nbm = nbm2; N = N2; alpha = al2; }
  const int bm = tile % nbm, bn = tile / nbm;   // col-major: consecutive tiles share B panel
  const int m0 = bm << 8, n0 = bn << 8;
  const int t = threadIdx.x, lane = t & 63, w = t >> 6;
  const int wm = w >> 2, wn = w & 3;
  const int fr = lane & 15, fq = lane >> 4;
  const int ntk = K >> 6;                        // requires K % 128 == 0, K >= 256

  const int r0 = t >> 2, r1 = 128 + (t >> 2), gsw = t & 3;
  const int cs0 = (gsw ^ ((r0 >> 1) & 3)) << 3;
  const int cs1 = (gsw ^ ((r1 >> 1) & 3)) << 3;
  const short* gA0 = A + (size_t)(m0 + r0)*K + cs0;
  const short* gA1 = A + (size_t)(m0 + r1)*K + cs1;
  const short* gB0 = B + (size_t)(n0 + r0)*K + cs0;
  const short* gB1 = B + (size_t)(n0 + r1)*K + cs1;
  short* const ldA = smem + w*512;
  short* const ldB = smem + 32768 + w*512;

  int aoff[8], boff[4];
#pragma unroll
  for (int mi = 0; mi < 8; mi++) { const int r = wm*128 + mi*16 + fr; aoff[mi] = r*32 + ((fq ^ ((r >> 1) & 3)) << 3); }
#pragma unroll
  for (int ni = 0; ni < 4; ni++) { const int r = wn*64 + ni*16 + fr; boff[ni] = r*32 + ((fq ^ ((r >> 1) & 3)) << 3); }

  f4v acc[8][4] = {};
  s8v bv[4];

  ST_A(0,0,0); ST_B(0,0,0); ST_A(0,1,0); ST_B(0,1,0);
  ST_B(1,0,1); ST_A(1,0,1); ST_B(1,1,1);
  asm volatile("s_waitcnt vmcnt(6)" ::: "memory");
  __builtin_amdgcn_s_barrier();
  asm volatile("" ::: "memory");

  for (int it = 0, nit = (ntk >> 1) - 1; it < nit; ++it) {
    const int t1 = 2*it + 1, t2 = 2*it + 2, t3 = 2*it + 3;
    PH256(0,0,0, 1,0, ST_A(1,1,t1));   // ph1
    PH256(0,0,1, 0,0, ST_B(0,0,t2));   // ph2
    PH256(0,1,0, 1,0, ST_A(0,0,t2));   // ph3
    PH256(0,1,1, 0,1, ST_B(0,1,t2));   // ph4 + vmcnt(6)
    PH256(1,0,0, 1,0, ST_A(0,1,t2));   // ph5
    PH256(1,0,1, 0,0, ST_B(1,0,t3));   // ph6
    PH256(1,1,0, 1,0, ST_A(1,0,t3));   // ph7
    PH256(1,1,1, 0,1, ST_B(1,1,t3));   // ph8 + vmcnt(6)
  }
  PH256(0,0,0, 1,0, ST_A(1,1,ntk-1));
  PH256(0,0,1, 0,0, );
  PH256(0,1,0, 1,0, );
  PH256(0,1,1, 0,2, );                 // vmcnt(0): buf1 fully resident
  PH256(1,0,0, 1,0, );
  PH256(1,0,1, 0,0, );
  PH256(1,1,0, 1,0, );
  PH256(1,1,1, 0,0, );

#pragma unroll
  for (int mi = 0; mi < 8; mi++) {
    const int row = m0 + wm*128 + mi*16 + fq*4;
#pragma unroll
    for (int ni = 0; ni < 4; ni++) {
      const int col = n0 + wn*64 + ni*16 + fr;
      const float bvv = bias ? bias[col] : 0.f;
#pragma unroll
      for (int r = 0; r < 4; r++) {
        float v = acc[mi][ni][r]*alpha + bvv;
        const size_t idx = (size_t)(row + r)*N + col;
        if (resid) v += resid[idx];
        if (relu) v = fmaxf(v, 0.f);
        if (Cf) Cf[idx] = v;
        else Cb[idx] = f2bf(v);
      }
    }
  }
}

// ============ batched weight transpose: up to 8 f32[R,C] -> bf16[C,R], 1 tile/block ======
struct WTB {
  const float* src[8]; short* dst[8];
  int R[8], C[8], start[8];
  int NT;
};

__global__ __launch_bounds__(256) void wtransN(WTB b)
{
  __shared__ float t[32][33];
  const int id = blockIdx.x;
  if (id >= b.NT) return;
  int op = 0;
#pragma unroll
  for (int o = 1; o < 8; o++) if (id >= b.start[o]) op = o;
  const int loc = id - b.start[op];
  const int Cd = b.C[op], Rd = b.R[op];
  const int ncx = Cd >> 5;
  const int cx = (loc % ncx) << 5, ry = (loc / ncx) << 5;
  const float* s = b.src[op];
  short* d = b.dst[op];
  const int tx = threadIdx.x, ty = threadIdx.y;
#pragma unroll
  for (int k = 0; k < 4; k++)
    t[ty + k*8][tx] = s[(size_t)(ry + ty + k*8)*Cd + cx + tx];
  __syncthreads();
#pragma unroll
  for (int k = 0; k < 4; k++)
    d[(size_t)(cx + ty + k*8)*Rd + ry + tx] = f2bf(t[tx][ty + k*8]);
}

// ============ btrans2: v1b -> v1T and v2b -> v2T in one launch ============
__global__ __launch_bounds__(256) void btrans2(
    const short* __restrict__ v1b, short* __restrict__ v1T,
    const short* __restrict__ v2b, short* __restrict__ v2T)
{
  __shared__ short t[32][33];
  const int z = blockIdx.z, b = z >> 3, h = z & 7;
  int y = blockIdx.y;
  const short* S; short* D; int ld_;
  if (y < 32) { S = v1b + ((size_t)b*1024)*1536 + h*192; D = v1T + (size_t)z*196608; ld_ = 1024; }
  else { y -= 32; S = v2b + ((size_t)b*768)*1536 + h*192; D = v2T + (size_t)z*147456; ld_ = 768; }
  const int c0 = blockIdx.x*32, r0 = y*32;
  const int tx = threadIdx.x, ty = threadIdx.y;
#pragma unroll
  for (int k = 0; k < 4; k++)
    t[ty + k*8][tx] = S[(size_t)(r0 + ty + k*8)*1536 + c0 + tx];
  __syncthreads();
#pragma unroll
  for (int k = 0; k < 4; k++)
    D[(size_t)(c0 + ty + k*8)*ld_ + r0 + tx] = t[tx][ty + k*8];
}

// ============ prep3: y0->bf16 (blocks 0..4607) | posemb (4608..5119) | ln_x (5120..9215) ====
__global__ __launch_bounds__(256) void prep3(
    const float* __restrict__ y0, short* __restrict__ y0b,
    short* __restrict__ posb,
    const float* __restrict__ x, const float* __restrict__ lnxg,
    const float* __restrict__ lnxb, short* __restrict__ x1)
{
  __shared__ float rs[4], rs2[4];
  int bid = blockIdx.x;
  const int tid = threadIdx.x;
  if (bid < 4608) {
    // f32 -> bf16 convert, 1024 elements per block
    const long long i = ((long long)bid*256 + tid)*4;
    const float4 v = *(const float4*)(y0 + i);
    s4v o = { f2bf(v.x), f2bf(v.y), f2bf(v.z), f2bf(v.w) };
    *(s4v*)(y0b + i) = o;
    return;
  }
  bid -= 4608;
  if (bid < 512) {
    // positional features: 4 rows per block, one 64-lane wave each
    const int i = bid*4 + (tid >> 6);
    const int j = tid & 63;
    if (i >= 2047) return;
    const float dist = (float)(i - 1023);
    const float absd = fabsf(dist);
    float fe = 0.f, fc = 0.f, prob = 0.f;
    if (j < 32) {
      const float hl = exp2f(3.f + 7.f*(float)j/31.f);
      fe = expf(-0.6931471805599453f/hl * absd);
      const float width = exp2f((float)(j+1)) - 1.f;
      fc = (width > absd) ? 1.f : 0.f;
      const float m = 32.f*(float)(j+1);
      const float conc = (m/16.f)*(m/16.f);
      const float rate = m/256.f;
      const float logp = (absd > 0.f ? (conc-1.f)*logf(absd) : -INFINITY) - rate*absd;
      const float logn = lgammaf(conc) - conc*logf(rate);
      prob = expf(logp - logn) + 1e-8f;
    }
    float mx = prob;
    for (int m = 1; m < 32; m <<= 1) mx = fmaxf(mx, __shfl_xor(mx, m));
    if (j < 32) {
      const float fg = prob / mx;
      const float sg = dist > 0.f ? 1.f : (dist < 0.f ? -1.f : 0.f);
      const size_t base = (size_t)i*192;
      posb[base + j]       = f2bf(fe);
      posb[base + 32 + j]  = f2bf(fc);
      posb[base + 64 + j]  = f2bf(fg);
      posb[base + 96 + j]  = f2bf(sg*fe);
      posb[base + 128 + j] = f2bf(sg*fc);
      posb[base + 160 + j] = f2bf(sg*fg);
    }
    return;
  }
  bid -= 512;
  // ln_x: one row per block
  const long long row = bid;
  const float* r = x + row*1536;
  float v[6], s = 0.f, s2 = 0.f;
#pragma unroll
  for (int i = 0; i < 6; i++) { v[i] = r[tid + i*256]; s += v[i]; s2 += v[i]*v[i]; }
  for (int m = 1; m < 64; m <<= 1) { s += __shfl_xor(s, m); s2 += __shfl_xor(s2, m); }
  if ((tid & 63) == 0) { rs[tid>>6] = s; rs2[tid>>6] = s2; }
  __syncthreads();
  s = rs[0]+rs[1]+rs[2]+rs[3]; s2 = rs2[0]+rs2[1]+rs2[2]+rs2[3];
  const float mu  = s * (1.f/1536.f);
  const float var = s2 * (1.f/1536.f) - mu*mu;
  const float inv = rsqrtf(var + 1e-5f);
  short* o = x1 + row*1536;
#pragma unroll
  for (int i = 0; i < 6; i++) { int c = tid + i*256; o[c] = f2bf((v[i]-mu)*inv*lnxg[c] + lnxb[c]); }
}

// ============ LayerNorm over 1536 cols, f32 in -> bf16 out ============
__global__ __launch_bounds__(256) void ln_k(const float* __restrict__ in,
    const float* __restrict__ gam, const float* __restrict__ bet, short* __restrict__ out)
{
  const long long row = blockIdx.x;
  const float* r = in + row*1536;
  const int tid = threadIdx.x;
  float v[6], s = 0.f, s2 = 0.f;
#pragma unroll
  for (int i = 0; i < 6; i++) { v[i] = r[tid + i*256]; s += v[i]; s2 += v[i]*v[i]; }
  for (int m = 1; m < 64; m <<= 1) { s += __shfl_xor(s, m); s2 += __shfl_xor(s2, m); }
  __shared__ float rs[4], rs2[4];
  if ((tid & 63) == 0) { rs[tid>>6] = s; rs2[tid>>6] = s2; }
  __syncthreads();
  s = rs[0]+rs[1]+rs[2]+rs[3]; s2 = rs2[0]+rs2[1]+rs2[2]+rs2[3];
  const float mu  = s * (1.f/1536.f);
  const float var = s2 * (1.f/1536.f) - mu*mu;
  const float inv = rsqrtf(var + 1e-5f);
  short* o = out + row*1536;
#pragma unroll
  for (int i = 0; i < 6; i++) { int c = tid + i*256; o[c] = f2bf((v[i]-mu)*inv*gam[c] + bet[c]); }
}

// ============ ln2_k: both FFN layernorms in one launch ====
__global__ __launch_bounds__(256) void ln2_k(
    const float* __restrict__ in1, const float* __restrict__ g1, const float* __restrict__ b1,
    short* __restrict__ o1,
    const float* __restrict__ in2, const float* __restrict__ g2, const float* __restrict__ b2,
    short* __restrict__ o2)
{
  long long row = blockIdx.x;
  const float* in; const float* gam; const float* bet; short* out;
  if (row < 4096) { in = in1; gam = g1; bet = b1; out = o1; }
  else { row -= 4096; in = in2; gam = g2; bet = b2; out = o2; }
  const float* r = in + row*1536;
  const int tid = threadIdx.x;
  float v[6], s = 0.f, s2 = 0.f;
#pragma unroll
  for (int i = 0; i < 6; i++) { v[i] = r[tid + i*256]; s += v[i]; s2 += v[i]*v[i]; }
  for (int m = 1; m < 64; m <<= 1) { s += __shfl_xor(s, m); s2 += __shfl_xor(s2, m); }
  __shared__ float rs[4], rs2[4];
  if ((tid & 63) == 0) { rs[tid>>6] = s; rs2[tid>>6] = s2; }
  __syncthreads();
  s = rs[0]+rs[1]+rs[2]+rs[3]; s2 = rs2[0]+rs2[1]+rs2[2]+rs2[3];
  const float mu  = s * (1.f/1536.f);
  const float var = s2 * (1.f/1536.f) - mu*mu;
  const float inv = rsqrtf(var + 1e-5f);
  short* o = out + row*1536;
#pragma unroll
  for (int i = 0; i < 6; i++) { int c = tid + i*256; o[c] = f2bf((v[i]-mu)*inv*gam[c] + bet[c]); }
}

// ============ rel bias table: T[h][n] = dot64(rpb[h], relq[n,h*64:]) ============
__global__ __launch_bounds__(256) void relbias_k(const float* __restrict__ rpb,
    const short* __restrict__ relq, float* __restrict__ T)
{
  const int n = blockIdx.x;
  const int tid = threadIdx.x;
  const int h = tid >> 5, l = tid & 31;
  const int d = l*2;
  float s = rpb[h*64+d]   * bf2f(relq[(size_t)n*512 + h*64 + d])
          + rpb[h*64+d+1] * bf2f(relq[(size_t)n*512 + h*64 + d+1]);
  for (int m = 1; m < 32; m <<= 1) s += __shfl_xor(s, m);
  if (l == 0) T[h*2047 + n] = s;
}

// ============ fused scores -> BF16 logits =====
__global__ __launch_bounds__(256) void scores_k(
    const short* __restrict__ qb, const short* __restrict__ kb,
    const short* __restrict__ relq, const float* __restrict__ T,
    short* __restrict__ L)
{
  __shared__ __align__(16) short smem[21504];
  short* kt  = smem;                 // 64*72
  short* qt  = smem + 4608;          // 64*72
  short* rqt = smem + 4608;          // 128*72 (over qt)
  float* P   = (float*)(smem + 4608);// 64*132 f32 (over rqt)

  const int z = blockIdx.z, b = z >> 3, h = z & 7;
  const int j0 = blockIdx.x*64, i0 = blockIdx.y*64;
  const int tid = threadIdx.x, lane = tid & 63, wv = tid >> 6;
  const int fr = lane & 15, fq = lane >> 4;

  {
    const short* kg = kb + (size_t)(b*768  + j0)*512 + h*64;
    const short* qg = qb + (size_t)(b*1024 + i0)*512 + h*64;
    for (int c = tid; c < 512; c += 256) {
      const int r = c >> 3, ch = (c & 7)*8;
      *(s8v*)&kt[r*72 + ch] = *(const s8v*)&kg[(size_t)r*512 + ch];
      *(s8v*)&qt[r*72 + ch] = *(const s8v*)&qg[(size_t)r*512 + ch];
    }
  }
  __syncthreads();

  const int wi = (wv & 1)*32, wj = (wv >> 1)*32;
  f4v c2[2][2] = {};
#pragma unroll
  for (int ks = 0; ks < 2; ks++) {
    s8v aq[2], bk[2];
#pragma unroll
    for (int mi = 0; mi < 2; mi++) aq[mi] = *(const s8v*)&qt[(wi + mi*16 + fr)*72 + ks*32 + fq*8];
#pragma unroll
    for (int ni = 0; ni < 2; ni++) bk[ni] = *(const s8v*)&kt[(wj + ni*16 + fr)*72 + ks*32 + fq*8];
#pragma unroll
    for (int mi = 0; mi < 2; mi++)
#pragma unroll
      for (int ni = 0; ni < 2; ni++)
        c2[mi][ni] = __builtin_amdgcn_mfma_f32_16x16x32_bf16(aq[mi], bk[ni], c2[mi][ni], 0, 0, 0);
  }
  __syncthreads();

  const int nbase = 704 + i0 - j0;
  {
    const short* rg = relq + (size_t)nbase*512 + h*64;
    for (int c = tid; c < 1024; c += 256) {
      const int r = c >> 3, ch = (c & 7)*8;
      *(s8v*)&rqt[r*72 + ch] = *(const s8v*)&rg[(size_t)r*512 + ch];
    }
  }
  __syncthreads();

  const int wj2 = (wv & 1)*32, wn2 = (wv >> 1)*64;
  f4v pr[2][4] = {};
#pragma unroll
  for (int ks = 0; ks < 2; ks++) {
    s8v a2[2], b2[4];
#pragma unroll
    for (int mi = 0; mi < 2; mi++) a2[mi] = *(const s8v*)&kt[(wj2 + mi*16 + fr)*72 + ks*32 + fq*8];
#pragma unroll
    for (int ni = 0; ni < 4; ni++) b2[ni] = *(const s8v*)&rqt[(wn2 + ni*16 + fr)*72 + ks*32 + fq*8];
#pragma unroll
    for (int mi = 0; mi < 2; mi++)
#pragma unroll
      for (int ni = 0; ni < 4; ni++)
        pr[mi][ni] = __builtin_amdgcn_mfma_f32_16x16x32_bf16(a2[mi], b2[ni], pr[mi][ni], 0, 0, 0);
  }
  __syncthreads();

#pragma unroll
  for (int mi = 0; mi < 2; mi++)
#pragma unroll
    for (int ni = 0; ni < 4; ni++)
#pragma unroll
      for (int r = 0; r < 4; r++)
        P[(wj2 + mi*16 + fq*4 + r)*132 + wn2 + ni*16 + fr] = pr[mi][ni][r];
  __syncthreads();

  const float* Tt = T + h*2047 + nbase;
  short* Lb = L + ((size_t)z*1024 + i0)*768 + j0;
#pragma unroll
  for (int mi = 0; mi < 2; mi++)
#pragma unroll
    for (int ni = 0; ni < 2; ni++)
#pragma unroll
      for (int r = 0; r < 4; r++) {
        const int il = wi + mi*16 + fq*4 + r;
        const int jl = wj + ni*16 + fr;
        const int nl = 63 + il - jl;
        Lb[(size_t)il*768 + jl] = f2bf(c2[mi][ni][r] + 0.125f*P[jl*132 + nl] + Tt[nl]);
      }
}

// ============ softmax2d: bf16 logits -> attnb (row-major) + attnT (transposed) ============
__global__ __launch_bounds__(256) void softmax2d(const short* __restrict__ L,
    short* __restrict__ attnb, short* __restrict__ attnT)
{
  __shared__ __align__(16) short pt[32*776];    // 49,664 B; stride 776
  const int ic = blockIdx.x, z = blockIdx.y;
  const int t = threadIdx.x, wv = t >> 6, lane = t & 63;
  const int rl = wv*8 + (lane >> 3);            // local row 0..31
  const int cs = (lane & 7)*96;                 // col segment start
  const size_t rowg = ((size_t)z*1024 + ic*32 + rl)*768;

  s8v v[12];
#pragma unroll
  for (int k = 0; k < 12; k++) v[k] = *(const s8v*)&L[rowg + cs + k*8];

  float mx = -1e30f;
#pragma unroll
  for (int k = 0; k < 12; k++)
#pragma unroll
    for (int e = 0; e < 8; e++) mx = fmaxf(mx, bf2f(v[k][e]));
  mx = fmaxf(mx, __shfl_xor(mx, 1));
  mx = fmaxf(mx, __shfl_xor(mx, 2));
  mx = fmaxf(mx, __shfl_xor(mx, 4));

  float s = 0.f;
#pragma unroll
  for (int k = 0; k < 12; k++)
#pragma unroll
    for (int e = 0; e < 8; e++) s += __expf(bf2f(v[k][e]) - mx);
  s += __shfl_xor(s, 1);
  s += __shfl_xor(s, 2);
  s += __shfl_xor(s, 4);
  const float inv = 1.f / s;

  short* ab = attnb + rowg;
#pragma unroll
  for (int k = 0; k < 12; k++) {
    s8v o;
#pragma unroll
    for (int e = 0; e < 8; e++) o[e] = f2bf(__expf(bf2f(v[k][e]) - mx) * inv);
    *(s8v*)&ab[cs + k*8] = o;
    *(s8v*)&pt[rl*776 + cs + k*8] = o;
  }
  __syncthreads();

  short* aT = attnT + (size_t)z*786432 + (size_t)ic*32;
  const int i4 = (lane & 7)*4, jb = lane >> 3;
  for (int jj = 0; jj < 24; jj++) {
    const int j = wv*192 + jj*8 + jb;
    s4v o;
#pragma unroll
    for (int e = 0; e < 4; e++) o[e] = pt[(i4 + e)*776 + j];
    *(s4v*)&aT[(size_t)j*1024 + i4] = o;
  }
}

// ======================= host =======================
static void gemm(hipStream_t st, const short* A, const short* B, float* Cf, short* Cb,
                 const float* bias, const float* resid,
                 int M, int N, int K, int lda, int ldb, int ldc,
                 int batches = 1,
                 long long sAo = 0, long long sAi = 0, long long sBo = 0, long long sBi = 0,
                 long long sCo = 0, long long sCi = 0, float alpha = 1.f, int relu = 0)
{
  dim3 g((N + 127)/128, (M + 127)/128, batches);
  gemm_bt<<<g, dim3(256), 0, st>>>(A, B, Cf, Cb, bias, resid, M, N, K, lda, ldb, ldc,
                                   sAo, sAi, sBo, sBi, sCo, sCi, alpha, relu);
}

static void g256_3(hipStream_t st,
    const short* A0, const short* B0, float* C0f, short* C0b, const float* bias0, const float* res0,
    int M0, int N0, float al0,
    const short* A1, const short* B1, float* C1f, short* C1b, const float* bias1, const float* res1,
    int M1, int N1, float al1,
    const short* A2, const short* B2, float* C2f, short* C2b, const float* bias2, const float* res2,
    int M2, int N2, float al2,
    int K, int relu)
{
  const int nbm0 = M0 >> 8, nb0 = nbm0*(N0 >> 8);
  const int nbm1 = M1 >> 8, nb1 = nbm1*(N1 >> 8);
  const int nbm2 = M2 >> 8, nb2 = M2 ? nbm2*(N2 >> 8) : 0;
  gemm256<<<dim3(nb0 + nb1 + nb2), dim3(512), 0, st>>>(
      A0, B0, C0f, C0b, bias0, res0, nb0, nbm0, N0, al0,
      A1, B1, C1f, C1b, bias1, res1, nb0 + nb1, nbm1, N1, al1,
      A2, B2, C2f, C2b, bias2, res2, nbm2, N2, al2, K, relu);
}

static void g256(hipStream_t st,
    const short* A0, const short* B0, float* C0f, short* C0b, const float* bias0, const float* res0,
    int M0, int N0, float al0,
    const short* A1, const short* B1, float* C1f, short* C1b, const float* bias1, const float* res1,
    int M1, int N1, float al1,
    int K, int relu)
{
  g256_3(st, A0, B0, C0f, C0b, bias0, res0, M0, N0, al0,
         A1, B1, C1f, C1b, bias1, res1, M1, N1, al1,
         nullptr, nullptr, nullptr, nullptr, nullptr, nullptr, 0, 256, 1.f, K, relu);
}

extern "C" void kernel_launch(void* const* d_in, const int* in_sizes, int n_in,
                              void* d_out, int out_size, void* d_ws, size_t ws_size,
                              hipStream_t stream)
{
  (void)in_sizes; (void)n_in; (void)out_size; (void)ws_size;
  const float* x     = (const float*)d_in[0];
  const float* y0    = (const float*)d_in[1];
  const float* lnxg  = (const float*)d_in[3];
  const float* lnxb  = (const float*)d_in[4];
  const float* lnyg  = (const float*)d_in[5];
  const float* lnyb  = (const float*)d_in[6];
  const float* rpb   = (const float*)d_in[12];
  const float* bo1   = (const float*)d_in[14];
  const float* bo2   = (const float*)d_in[16];
  const float* fxg   = (const float*)d_in[17];
  const float* fxbb  = (const float*)d_in[18];
  const float* fxb1  = (const float*)d_in[20];
  const float* fxb2  = (const float*)d_in[22];
  const float* fyg   = (const float*)d_in[23];
  const float* fybb  = (const float*)d_in[24];
  const float* fyb1  = (const float*)d_in[26];
  const float* fyb2  = (const float*)d_in[28];

  char* base = (char*)d_ws;
  size_t off = 0;
  auto bump = [&](size_t b) -> char* { char* p = base + off; off += (b + 255) & ~(size_t)255; return p; };

  // ---- pooled weight buffers (bf16, transposed [N,K]) ----
  short* W_A  = (short*)bump(4718592);   // resT -> wo1T           (1536x1536)
  short* W_B  = (short*)bump(1572864);   // wqT                    (512x1536)
  short* W_B2 = (short*)bump(1572864);   // wkT                    (512x1536)
  short* W_C  = (short*)bump(4718592);   // wv1T -> wo2T           (1536x1536)
  short* W_D  = (short*)bump(196608);    // relT                   (512x192)
  short* W_E  = (short*)bump(9437184);   // fx1T                   (3072x1536)
  short* W_F  = (short*)bump(9437184);   // fx2T                   (1536x3072)

  char*  uB = bump(12582912);
  short* x1   = (short*)uB;
  short* v1T  = (short*)uB;
  char*  uC = bump(9437184);
  short* y1   = (short*)uC;
  short* out2 = (short*)uC;
  char*  uD = bump(9437184);
  short* y0b = (short*)uD;
  short* qb  = (short*)uD;
  short* kbB = (short*)(uD + 4194304);
  short* v2T = (short*)uD;
  float* Tbl   = (float*)bump(262016);
  short* posb  = (short*)bump(786048);
  short* relqb = (short*)bump(2096128);
  char*  uG = bump(12582912);
  short* v1b  = (short*)uG;
  short* out1 = (short*)uG;
  short* x4ln = (short*)uG;
  char*  uH = bump(9437184);   short* v2b = (short*)uH;  short* y4ln = (short*)uH;
  char*  uI = bump(100663296);
  short* wv2T    = (short*)uI;
  short* logits16 = (short*)uI;
  short* attnT   = (short*)(uI + 50331648);
  short* hx      = (short*)uI;
  short* hy      = (short*)(uI + 25165824);
  short* fy1T    = (short*)(uI + 46137344);
  short* fy2T    = (short*)(uI + 55574528);
  char*  U2 = bump(50331648);
  short* attnb = (short*)U2;
  float* y4    = (float*)U2;

  float* outx = (float*)d_out;
  float* outy = (float*)d_out + 6291456;
  float* x4  = outx;
  float* y_f = outy;

  auto addop = [&](WTB& b, int i, int idx, short* dst, int R, int C) {
    b.src[i] = (const float*)d_in[idx]; b.dst[i] = dst;
    b.R[i] = R; b.C[i] = C; b.start[i] = b.NT; b.NT += (R >> 5)*(C >> 5);
  };
  auto finwtb = [&](WTB& b, int n) {
    for (int i = n; i < 8; i++) { b.start[i] = 0x7fffffff; b.src[i] = nullptr; b.dst[i] = nullptr; b.R[i] = 32; b.C[i] = 32; }
  };

  // B1: all weights needed through v2qk + ffn-x
  WTB b1{}; b1.NT = 0;
  addop(b1, 0, 2,  W_A,  1536, 1536);   // res_w
  addop(b1, 1, 11, W_D,  192,  512);    // wrel
  addop(b1, 2, 9,  W_C,  1536, 1536);   // wv1
  addop(b1, 3, 10, wv2T, 1536, 1536);   // wv2
  addop(b1, 4, 7,  W_B,  1536, 512);    // wq
  addop(b1, 5, 8,  W_B2, 1536, 512);    // wk
  addop(b1, 6, 19, W_E,  1536, 3072);   // fx_w1
  addop(b1, 7, 21, W_F,  3072, 1536);   // fx_w2
  wtransN<<<dim3(b1.NT), dim3(32,8), 0, stream>>>(b1);

  // prep3: y0 -> bf16 | positional features | ln_x   (one launch)
  prep3<<<dim3(9216), dim3(256), 0, stream>>>(y0, y0b, posb, x, lnxg, lnxb, x1);
  // relq = pos @ wrel ; rel bias table
  gemm(stream, posb, W_D, nullptr, relqb, nullptr, nullptr, 2047, 512, 192, 192, 192, 512);
  relbias_k<<<2047, 256, 0, stream>>>(rpb, relqb, Tbl);
  // launch1: res = y0@res_w -> y_f + v1 = x1@wv1
  g256(stream, y0b, W_A, y_f, nullptr, nullptr, nullptr, 3072, 1536, 1.f,
       x1, W_C, nullptr, v1b, nullptr, nullptr, 4096, 1536, 1.f, 1536, 0);
  // B2: wo1 -> W_A, wo2 -> W_C
  WTB b2{}; b2.NT = 0;
  addop(b2, 0, 13, W_A, 1536, 1536);
  addop(b2, 1, 15, W_C, 1536, 1536);
  finwtb(b2, 2);
  wtransN<<<dim3(b2.NT), dim3(32,8), 0, stream>>>(b2);
  // ln_y
  ln_k<<<3072, 256, 0, stream>>>(y_f, lnyg, lnyb, y1);
  // v2 + q + k
  g256_3(stream, y1, wv2T, nullptr, v2b, nullptr, nullptr, 3072, 1536, 1.f,
         x1, W_B, nullptr, qb, nullptr, nullptr, 4096, 512, 0.125f,
         y1, W_B2, nullptr, kbB, nullptr, nullptr, 3072, 512, 1.f, 1536, 0);
  // fused scores -> bf16 logits
  scores_k<<<dim3(12,16,32), 256, 0, stream>>>(qb, kbB, relqb, Tbl, logits16);
  // softmax2d -> attnb + attnT
  softmax2d<<<dim3(32,32), 256, 0, stream>>>(logits16, attnb, attnT);
  // btrans2: v1T (uB) + v2T (uD) in one launch
  btrans2<<<dim3(6,56,32), dim3(32,8), 0, stream>>>(v1b, v1T, v2b, v2T);
  // pv_k: out1 = attn@v2 (-> uG) and out2 = attn^T@v1 (-> uC) in one launch
  pv_k<<<dim3(2,14,32), 256, 0, stream>>>(attnb, v2T, out1, attnT, v1T, out2);
  // B3: fy1 -> fy1T, fy2 -> fy2T (uI attn regions dead)
  WTB b3{}; b3.NT = 0;
  addop(b3, 0, 25, fy1T, 1536, 3072);
  addop(b3, 1, 27, fy2T, 3072, 1536);
  finwtb(b3, 2);
  wtransN<<<dim3(b3.NT), dim3(32,8), 0, stream>>>(b3);
  // wo-pair: x4 = x + out1@wo1 + bo1 ; y4 = y + out2@wo2 + bo2
  g256(stream, out1, W_A, x4, nullptr, bo1, x, 4096, 1536, 1.f,
       out2, W_C, y4, nullptr, bo2, y_f, 3072, 1536, 1.f, 1536, 0);
  // merged FFN LayerNorms
  ln2_k<<<7168, 256, 0, stream>>>(x4, fxg, fxbb, x4ln, y4, fyg, fybb, y4ln);
  // ffn1: hidden = relu(ln @ w1 + b1)
  g256(stream, x4ln, W_E, nullptr, hx, fxb1, nullptr, 4096, 3072, 1.f,
       y4ln, fy1T, nullptr, hy, fyb1, nullptr, 3072, 3072, 1.f, 1536, 1);
  // ffn2: out = resid + h @ w2 + b2  (in-place on outx)
  g256(stream, hx, W_F, outx, nullptr, fxb2, x4, 4096, 1536, 1.f,
       hy, fy2T, outy, nullptr, fyb2, y4, 3072, 1536, 1.f, 3072, 0);
}

// Round 17
// 642.665 us; speedup vs baseline: 1.0561x; 1.0048x over previous
//
#include <hip/hip_runtime.h>
#include <stdint.h>
#include <math.h>

typedef __attribute__((ext_vector_type(8))) short s8v;
typedef __attribute__((ext_vector_type(4))) short s4v;
typedef __attribute__((ext_vector_type(4))) float f4v;

#define DEV static __device__ __forceinline__

DEV short f2bf(float f) {
  uint32_t u = __builtin_bit_cast(uint32_t, f);
  u += 0x7FFFu + ((u >> 16) & 1u);   // round-to-nearest-even
  return (short)(u >> 16);
}
DEV float bf2f(short s) {
  uint32_t u = ((uint32_t)(uint16_t)s) << 16;
  return __builtin_bit_cast(float, u);
}

#define GLD16(g, l) __builtin_amdgcn_global_load_lds( \
    (const __attribute__((address_space(1))) void*)(g), \
    (__attribute__((address_space(3))) void*)(l), 16, 0, 0)

// ================= 128x128 GEMM (m97 structure) for small/odd/batched shapes =========
__global__ __launch_bounds__(256) void gemm_bt(
    const short* __restrict__ A, const short* __restrict__ B,
    float* Cf, short* Cb,
    const float* __restrict__ bias, const float* resid,
    int M, int N, int K, int lda, int ldb, int ldc,
    long long sAo, long long sAi, long long sBo, long long sBi,
    long long sCo, long long sCi, float alpha, int relu)
{
  __shared__ __align__(16) short lA[128*32];
  __shared__ __align__(16) short lB[128*32];
  const int z = blockIdx.z, zo = z >> 3, zi = z & 7;
  const short* Ab = A + zo*sAo + zi*sAi;
  const short* Bb = B + zo*sBo + zi*sBi;
  const long long cOff = zo*sCo + zi*sCi;

  const int m0 = blockIdx.y*128, n0 = blockIdx.x*128;
  const int tid = threadIdx.x, lane = tid & 63, wv = tid >> 6;
  const int wm = (wv >> 1)*64, wn = (wv & 1)*64;
  const int fr = lane & 15, fq = lane >> 4;

  f4v acc[4][4] = {};

  const int rA0 = min(m0 + (tid >> 2), M - 1);
  const int rA1 = min(m0 + 64 + (tid >> 2), M - 1);
  const int rB0 = min(n0 + (tid >> 2), N - 1);
  const int rB1 = min(n0 + 64 + (tid >> 2), N - 1);
  const int pc = (tid & 3) * 8;
  const short* gA0 = Ab + (size_t)rA0*lda + pc;
  const short* gA1 = Ab + (size_t)rA1*lda + pc;
  const short* gB0 = Bb + (size_t)rB0*ldb + pc;
  const short* gB1 = Bb + (size_t)rB1*ldb + pc;
  short* dA0 = lA + (wv*64)*8;
  short* dA1 = lA + (256 + wv*64)*8;
  short* dB0 = lB + (wv*64)*8;
  short* dB1 = lB + (256 + wv*64)*8;

  for (int k0 = 0; k0 < K; k0 += 32) {
    GLD16(gA0 + k0, dA0);
    GLD16(gA1 + k0, dA1);
    GLD16(gB0 + k0, dB0);
    GLD16(gB1 + k0, dB1);
    __syncthreads();
    s8v af[4], bg[4];
#pragma unroll
    for (int i = 0; i < 4; i++) {
      af[i] = *(const s8v*)&lA[(wm + i*16 + fr)*32 + fq*8];
      bg[i] = *(const s8v*)&lB[(wn + i*16 + fr)*32 + fq*8];
    }
#pragma unroll
    for (int mi = 0; mi < 4; mi++)
#pragma unroll
      for (int ni = 0; ni < 4; ni++)
        acc[mi][ni] = __builtin_amdgcn_mfma_f32_16x16x32_bf16(af[mi], bg[ni], acc[mi][ni], 0, 0, 0);
    __syncthreads();
  }

#pragma unroll
  for (int mi = 0; mi < 4; mi++) {
    const int row = m0 + wm + mi*16 + fq*4;
#pragma unroll
    for (int ni = 0; ni < 4; ni++) {
      const int col = n0 + wn + ni*16 + fr;
      if (col >= N) continue;
      const float bv = bias ? bias[col] : 0.f;
#pragma unroll
      for (int r = 0; r < 4; r++) {
        if (row + r >= M) continue;
        float v = acc[mi][ni][r] * alpha + bv;
        const long long idx = cOff + (long long)(row + r)*ldc + col;
        if (resid) v += resid[idx];
        if (relu) v = fmaxf(v, 0.f);
        if (Cf) Cf[idx] = v;
        if (Cb) Cb[idx] = f2bf(v);
      }
    }
  }
}

// ================= pv_k: out1 = attn@v2 and out2 = attn^T@v1 in ONE launch ======
__global__ __launch_bounds__(256) void pv_k(
    const short* __restrict__ attnb, const short* __restrict__ v2T, short* __restrict__ out1,
    const short* __restrict__ attnT, const short* __restrict__ v1T, short* __restrict__ out2)
{
  __shared__ __align__(16) short lA[128*32];
  __shared__ __align__(16) short lB[128*32];
  const int z = blockIdx.z, b = z >> 3, h = z & 7;
  const short* A; const short* B; short* C; int M, K, lda, m0;
  if (blockIdx.y < 8) {
    A = attnb + (size_t)z*786432; B = v2T + (size_t)z*147456;
    C = out1 + ((size_t)b*1024)*1536 + h*192;
    M = 1024; K = 768; lda = 768; m0 = blockIdx.y*128;
  } else {
    A = attnT + (size_t)z*786432; B = v1T + (size_t)z*196608;
    C = out2 + ((size_t)b*768)*1536 + h*192;
    M = 768; K = 1024; lda = 1024; m0 = (blockIdx.y - 8)*128;
  }
  const int N = 192, ldc = 1536, ldb = lda;
  const int n0 = blockIdx.x*128;
  const int tid = threadIdx.x, lane = tid & 63, wv = tid >> 6;
  const int wm = (wv >> 1)*64, wn = (wv & 1)*64;
  const int fr = lane & 15, fq = lane >> 4;

  f4v acc[4][4] = {};

  const int rA0 = m0 + (tid >> 2);
  const int rA1 = m0 + 64 + (tid >> 2);
  const int rB0 = min(n0 + (tid >> 2), N - 1);
  const int rB1 = min(n0 + 64 + (tid >> 2), N - 1);
  const int pc = (tid & 3) * 8;
  const short* gA0 = A + (size_t)rA0*lda + pc;
  const short* gA1 = A + (size_t)rA1*lda + pc;
  const short* gB0 = B + (size_t)rB0*ldb + pc;
  const short* gB1 = B + (size_t)rB1*ldb + pc;
  short* dA0 = lA + (wv*64)*8;
  short* dA1 = lA + (256 + wv*64)*8;
  short* dB0 = lB + (wv*64)*8;
  short* dB1 = lB + (256 + wv*64)*8;

  for (int k0 = 0; k0 < K; k0 += 32) {
    GLD16(gA0 + k0, dA0);
    GLD16(gA1 + k0, dA1);
    GLD16(gB0 + k0, dB0);
    GLD16(gB1 + k0, dB1);
    __syncthreads();
    s8v af[4], bg[4];
#pragma unroll
    for (int i = 0; i < 4; i++) {
      af[i] = *(const s8v*)&lA[(wm + i*16 + fr)*32 + fq*8];
      bg[i] = *(const s8v*)&lB[(wn + i*16 + fr)*32 + fq*8];
    }
#pragma unroll
    for (int mi = 0; mi < 4; mi++)
#pragma unroll
      for (int ni = 0; ni < 4; ni++)
        acc[mi][ni] = __builtin_amdgcn_mfma_f32_16x16x32_bf16(af[mi], bg[ni], acc[mi][ni], 0, 0, 0);
    __syncthreads();
  }

#pragma unroll
  for (int mi = 0; mi < 4; mi++) {
    const int row = m0 + wm + mi*16 + fq*4;
#pragma unroll
    for (int ni = 0; ni < 4; ni++) {
      const int col = n0 + wn + ni*16 + fr;
      if (col >= N) continue;
#pragma unroll
      for (int r = 0; r < 4; r++)
        C[(size_t)(row + r)*ldc + col] = f2bf(acc[mi][ni][r]);
    }
  }
}

// ================= 256x256 8-phase GEMM (r6 single-barrier schedule) ======
#define ST_A(buf, ks, tt) do { const int ko = ((tt)<<6) + ((ks)<<5); \
    GLD16(gA0 + ko, ldA + ((buf)*2+(ks))*8192); \
    GLD16(gA1 + ko, ldA + ((buf)*2+(ks))*8192 + 4096); } while(0)
#define ST_B(buf, ks, tt) do { const int ko = ((tt)<<6) + ((ks)<<5); \
    GLD16(gB0 + ko, ldB + ((buf)*2+(ks))*8192); \
    GLD16(gB1 + ko, ldB + ((buf)*2+(ks))*8192 + 4096); } while(0)

#define PH256(buf, ks, mig, READB, DOWAIT, ...) do { \
    s8v av[4]; \
    const int rb = ((buf)*2+(ks))*8192; \
    _Pragma("unroll") for (int q2 = 0; q2 < 4; q2++) av[q2] = *(const s8v*)&smem[rb + aoff[(mig)*4+q2]]; \
    if (READB) { _Pragma("unroll") for (int q2 = 0; q2 < 4; q2++) bv[q2] = *(const s8v*)&smem[32768 + rb + boff[q2]]; } \
    __VA_ARGS__; \
    if (DOWAIT == 1) asm volatile("s_waitcnt vmcnt(6)" ::: "memory"); \
    if (DOWAIT == 2) asm volatile("s_waitcnt vmcnt(0)" ::: "memory"); \
    __builtin_amdgcn_s_barrier(); \
    asm volatile("s_waitcnt lgkmcnt(0)" ::: "memory"); \
    __builtin_amdgcn_s_setprio(1); \
    _Pragma("unroll") for (int q2 = 0; q2 < 4; q2++) \
      _Pragma("unroll") for (int u2 = 0; u2 < 4; u2++) \
        acc[(mig)*4+q2][u2] = __builtin_amdgcn_mfma_f32_16x16x32_bf16(av[q2], bv[u2], acc[(mig)*4+q2][u2], 0, 0, 0); \
    __builtin_amdgcn_s_setprio(0); \
  } while(0)

__global__ __launch_bounds__(512) void gemm256(
    const short* __restrict__ A0p, const short* __restrict__ B0p,
    float* C0f, short* C0b, const float* __restrict__ bias0, const float* res0,
    int nb0, int nbm0, int N0, float al0,
    const short* __restrict__ A1p, const short* __restrict__ B1p,
    float* C1f, short* C1b, const float* __restrict__ bias1, const float* res1,
    int nb01, int nbm1, int N1, float al1,
    const short* __restrict__ A2p, const short* __restrict__ B2p,
    float* C2f, short* C2b, const float* __restrict__ bias2, const float* res2,
    int nbm2, int N2, float al2,
    int K, int relu)
{
  __shared__ __align__(16) short smem[65536];   // 128 KiB
  const int total = gridDim.x;
  int bid = blockIdx.x;
  if ((total & 7) == 0) bid = (bid & 7)*(total >> 3) + (bid >> 3);   // bijective XCD swizzle
  const short* A; const short* B; float* Cf; short* Cb; const float* bias; const float* resid;
  int tile, nbm, N; float alpha;
  if (bid < nb0)       { A = A0p; B = B0p; Cf = C0f; Cb = C0b; bias = bias0; resid = res0;
                         tile = bid; nbm = nbm0; N = N0; alpha = al0; }
  else if (bid < nb01) { A = A1p; B = B1p; Cf = C1f; Cb = C1b; bias = bias1; resid = res1;
                         tile = bid - nb0; nbm = nbm1; N = N1; alpha = al1; }
  else                 { A = A2p; B = B2p; Cf = C2f; Cb = C2b; bias = bias2; resid = res2;
                         tile = bid - nb01; nbm = nbm2; N = N2; alpha = al2; }
  const int bm = tile % nbm, bn = tile / nbm;   // col-major: consecutive tiles share B panel
  const int m0 = bm << 8, n0 = bn << 8;
  const int t = threadIdx.x, lane = t & 63, w = t >> 6;
  const int wm = w >> 2, wn = w & 3;
  const int fr = lane & 15, fq = lane >> 4;
  const int ntk = K >> 6;                        // requires K % 128 == 0, K >= 256

  const int r0 = t >> 2, r1 = 128 + (t >> 2), gsw = t & 3;
  const int cs0 = (gsw ^ ((r0 >> 1) & 3)) << 3;
  const int cs1 = (gsw ^ ((r1 >> 1) & 3)) << 3;
  const short* gA0 = A + (size_t)(m0 + r0)*K + cs0;
  const short* gA1 = A + (size_t)(m0 + r1)*K + cs1;
  const short* gB0 = B + (size_t)(n0 + r0)*K + cs0;
  const short* gB1 = B + (size_t)(n0 + r1)*K + cs1;
  short* const ldA = smem + w*512;
  short* const ldB = smem + 32768 + w*512;

  int aoff[8], boff[4];
#pragma unroll
  for (int mi = 0; mi < 8; mi++) { const int r = wm*128 + mi*16 + fr; aoff[mi] = r*32 + ((fq ^ ((r >> 1) & 3)) << 3); }
#pragma unroll
  for (int ni = 0; ni < 4; ni++) { const int r = wn*64 + ni*16 + fr; boff[ni] = r*32 + ((fq ^ ((r >> 1) & 3)) << 3); }

  f4v acc[8][4] = {};
  s8v bv[4];

  ST_A(0,0,0); ST_B(0,0,0); ST_A(0,1,0); ST_B(0,1,0);
  ST_B(1,0,1); ST_A(1,0,1); ST_B(1,1,1);
  asm volatile("s_waitcnt vmcnt(6)" ::: "memory");
  __builtin_amdgcn_s_barrier();
  asm volatile("" ::: "memory");

  for (int it = 0, nit = (ntk >> 1) - 1; it < nit; ++it) {
    const int t1 = 2*it + 1, t2 = 2*it + 2, t3 = 2*it + 3;
    PH256(0,0,0, 1,0, ST_A(1,1,t1));   // ph1
    PH256(0,0,1, 0,0, ST_B(0,0,t2));   // ph2
    PH256(0,1,0, 1,0, ST_A(0,0,t2));   // ph3
    PH256(0,1,1, 0,1, ST_B(0,1,t2));   // ph4 + vmcnt(6)
    PH256(1,0,0, 1,0, ST_A(0,1,t2));   // ph5
    PH256(1,0,1, 0,0, ST_B(1,0,t3));   // ph6
    PH256(1,1,0, 1,0, ST_A(1,0,t3));   // ph7
    PH256(1,1,1, 0,1, ST_B(1,1,t3));   // ph8 + vmcnt(6)
  }
  PH256(0,0,0, 1,0, ST_A(1,1,ntk-1));
  PH256(0,0,1, 0,0, );
  PH256(0,1,0, 1,0, );
  PH256(0,1,1, 0,2, );                 // vmcnt(0): buf1 fully resident
  PH256(1,0,0, 1,0, );
  PH256(1,0,1, 0,0, );
  PH256(1,1,0, 1,0, );
  PH256(1,1,1, 0,0, );

#pragma unroll
  for (int mi = 0; mi < 8; mi++) {
    const int row = m0 + wm*128 + mi*16 + fq*4;
#pragma unroll
    for (int ni = 0; ni < 4; ni++) {
      const int col = n0 + wn*64 + ni*16 + fr;
      const float bvv = bias ? bias[col] : 0.f;
#pragma unroll
      for (int r = 0; r < 4; r++) {
        float v = acc[mi][ni][r]*alpha + bvv;
        const size_t idx = (size_t)(row + r)*N + col;
        if (resid) v += resid[idx];
        if (relu) v = fmaxf(v, 0.f);
        if (Cf) Cf[idx] = v;
        else Cb[idx] = f2bf(v);
      }
    }
  }
}

// ============ batched weight transpose: up to 8 f32[R,C] -> bf16[C,R], 1 tile/block ======
struct WTB {
  const float* src[8]; short* dst[8];
  int R[8], C[8], start[8];
  int NT;
};

__global__ __launch_bounds__(256) void wtransN(WTB b)
{
  __shared__ float t[32][33];
  const int id = blockIdx.x;
  if (id >= b.NT) return;
  int op = 0;
#pragma unroll
  for (int o = 1; o < 8; o++) if (id >= b.start[o]) op = o;
  const int loc = id - b.start[op];
  const int Cd = b.C[op], Rd = b.R[op];
  const int ncx = Cd >> 5;
  const int cx = (loc % ncx) << 5, ry = (loc / ncx) << 5;
  const float* s = b.src[op];
  short* d = b.dst[op];
  const int tx = threadIdx.x, ty = threadIdx.y;
#pragma unroll
  for (int k = 0; k < 4; k++)
    t[ty + k*8][tx] = s[(size_t)(ry + ty + k*8)*Cd + cx + tx];
  __syncthreads();
#pragma unroll
  for (int k = 0; k < 4; k++)
    d[(size_t)(cx + ty + k*8)*Rd + ry + tx] = f2bf(t[tx][ty + k*8]);
}

// ============ postl1_k: ln_y (0..3071) | B2 wtrans (next b.NT) | relbias (last 2047) ======
__global__ __launch_bounds__(256) void postl1_k(
    const float* __restrict__ in, const float* __restrict__ gam,
    const float* __restrict__ bet, short* __restrict__ out,
    WTB b,
    const float* __restrict__ rpb, const short* __restrict__ relq, float* __restrict__ T)
{
  __shared__ float tsh[32][33];
  __shared__ float rs[4], rs2[4];
  int bid = blockIdx.x;
  const int tid = threadIdx.x;
  if (bid < 3072) {
    // ---- ln_y: one row per block ----
    const float* r = in + (long long)bid*1536;
    float v[6], s = 0.f, s2 = 0.f;
#pragma unroll
    for (int i = 0; i < 6; i++) { v[i] = r[tid + i*256]; s += v[i]; s2 += v[i]*v[i]; }
    for (int m = 1; m < 64; m <<= 1) { s += __shfl_xor(s, m); s2 += __shfl_xor(s2, m); }
    if ((tid & 63) == 0) { rs[tid>>6] = s; rs2[tid>>6] = s2; }
    __syncthreads();
    s = rs[0]+rs[1]+rs[2]+rs[3]; s2 = rs2[0]+rs2[1]+rs2[2]+rs2[3];
    const float mu  = s * (1.f/1536.f);
    const float var = s2 * (1.f/1536.f) - mu*mu;
    const float inv = rsqrtf(var + 1e-5f);
    short* o = out + (long long)bid*1536;
#pragma unroll
    for (int i = 0; i < 6; i++) { int c = tid + i*256; o[c] = f2bf((v[i]-mu)*inv*gam[c] + bet[c]); }
    return;
  }
  bid -= 3072;
  if (bid < b.NT) {
    // ---- weight transpose tile ----
    int op = 0;
#pragma unroll
    for (int o = 1; o < 8; o++) if (bid >= b.start[o]) op = o;
    const int loc = bid - b.start[op];
    const int Cd = b.C[op], Rd = b.R[op];
    const int ncx = Cd >> 5;
    const int cx = (loc % ncx) << 5, ry = (loc / ncx) << 5;
    const float* s = b.src[op];
    short* d = b.dst[op];
    const int tx = tid & 31, ty = tid >> 5;
#pragma unroll
    for (int k = 0; k < 4; k++)
      tsh[ty + k*8][tx] = s[(size_t)(ry + ty + k*8)*Cd + cx + tx];
    __syncthreads();
#pragma unroll
    for (int k = 0; k < 4; k++)
      d[(size_t)(cx + ty + k*8)*Rd + ry + tx] = f2bf(tsh[tx][ty + k*8]);
    return;
  }
  bid -= b.NT;
  // ---- relbias: n = bid (0..2046) ----
  const int n = bid;
  const int h = tid >> 5, l = tid & 31;
  const int d = l*2;
  float s = rpb[h*64+d]   * bf2f(relq[(size_t)n*512 + h*64 + d])
          + rpb[h*64+d+1] * bf2f(relq[(size_t)n*512 + h*64 + d+1]);
  for (int m = 1; m < 32; m <<= 1) s += __shfl_xor(s, m);
  if (l == 0) T[h*2047 + n] = s;
}

// ============ btrans2: v1b -> v1T and v2b -> v2T in one launch ============
__global__ __launch_bounds__(256) void btrans2(
    const short* __restrict__ v1b, short* __restrict__ v1T,
    const short* __restrict__ v2b, short* __restrict__ v2T)
{
  __shared__ short t[32][33];
  const int z = blockIdx.z, b = z >> 3, h = z & 7;
  int y = blockIdx.y;
  const short* S; short* D; int ld_;
  if (y < 32) { S = v1b + ((size_t)b*1024)*1536 + h*192; D = v1T + (size_t)z*196608; ld_ = 1024; }
  else { y -= 32; S = v2b + ((size_t)b*768)*1536 + h*192; D = v2T + (size_t)z*147456; ld_ = 768; }
  const int c0 = blockIdx.x*32, r0 = y*32;
  const int tx = threadIdx.x, ty = threadIdx.y;
#pragma unroll
  for (int k = 0; k < 4; k++)
    t[ty + k*8][tx] = S[(size_t)(r0 + ty + k*8)*1536 + c0 + tx];
  __syncthreads();
#pragma unroll
  for (int k = 0; k < 4; k++)
    D[(size_t)(c0 + ty + k*8)*ld_ + r0 + tx] = t[tx][ty + k*8];
}

// ============ prep3: y0->bf16 (blocks 0..4607) | posemb (4608..5119) | ln_x (5120..9215) ====
__global__ __launch_bounds__(256) void prep3(
    const float* __restrict__ y0, short* __restrict__ y0b,
    short* __restrict__ posb,
    const float* __restrict__ x, const float* __restrict__ lnxg,
    const float* __restrict__ lnxb, short* __restrict__ x1)
{
  __shared__ float rs[4], rs2[4];
  int bid = blockIdx.x;
  const int tid = threadIdx.x;
  if (bid < 4608) {
    const long long i = ((long long)bid*256 + tid)*4;
    const float4 v = *(const float4*)(y0 + i);
    s4v o = { f2bf(v.x), f2bf(v.y), f2bf(v.z), f2bf(v.w) };
    *(s4v*)(y0b + i) = o;
    return;
  }
  bid -= 4608;
  if (bid < 512) {
    const int i = bid*4 + (tid >> 6);
    const int j = tid & 63;
    if (i >= 2047) return;
    const float dist = (float)(i - 1023);
    const float absd = fabsf(dist);
    float fe = 0.f, fc = 0.f, prob = 0.f;
    if (j < 32) {
      const float hl = exp2f(3.f + 7.f*(float)j/31.f);
      fe = expf(-0.6931471805599453f/hl * absd);
      const float width = exp2f((float)(j+1)) - 1.f;
      fc = (width > absd) ? 1.f : 0.f;
      const float m = 32.f*(float)(j+1);
      const float conc = (m/16.f)*(m/16.f);
      const float rate = m/256.f;
      const float logp = (absd > 0.f ? (conc-1.f)*logf(absd) : -INFINITY) - rate*absd;
      const float logn = lgammaf(conc) - conc*logf(rate);
      prob = expf(logp - logn) + 1e-8f;
    }
    float mx = prob;
    for (int m = 1; m < 32; m <<= 1) mx = fmaxf(mx, __shfl_xor(mx, m));
    if (j < 32) {
      const float fg = prob / mx;
      const float sg = dist > 0.f ? 1.f : (dist < 0.f ? -1.f : 0.f);
      const size_t base = (size_t)i*192;
      posb[base + j]       = f2bf(fe);
      posb[base + 32 + j]  = f2bf(fc);
      posb[base + 64 + j]  = f2bf(fg);
      posb[base + 96 + j]  = f2bf(sg*fe);
      posb[base + 128 + j] = f2bf(sg*fc);
      posb[base + 160 + j] = f2bf(sg*fg);
    }
    return;
  }
  bid -= 512;
  const long long row = bid;
  const float* r = x + row*1536;
  float v[6], s = 0.f, s2 = 0.f;
#pragma unroll
  for (int i = 0; i < 6; i++) { v[i] = r[tid + i*256]; s += v[i]; s2 += v[i]*v[i]; }
  for (int m = 1; m < 64; m <<= 1) { s += __shfl_xor(s, m); s2 += __shfl_xor(s2, m); }
  if ((tid & 63) == 0) { rs[tid>>6] = s; rs2[tid>>6] = s2; }
  __syncthreads();
  s = rs[0]+rs[1]+rs[2]+rs[3]; s2 = rs2[0]+rs2[1]+rs2[2]+rs2[3];
  const float mu  = s * (1.f/1536.f);
  const float var = s2 * (1.f/1536.f) - mu*mu;
  const float inv = rsqrtf(var + 1e-5f);
  short* o = x1 + row*1536;
#pragma unroll
  for (int i = 0; i < 6; i++) { int c = tid + i*256; o[c] = f2bf((v[i]-mu)*inv*lnxg[c] + lnxb[c]); }
}

// ============ ln2_k: both FFN layernorms in one launch ====
__global__ __launch_bounds__(256) void ln2_k(
    const float* __restrict__ in1, const float* __restrict__ g1, const float* __restrict__ b1,
    short* __restrict__ o1,
    const float* __restrict__ in2, const float* __restrict__ g2, const float* __restrict__ b2,
    short* __restrict__ o2)
{
  long long row = blockIdx.x;
  const float* in; const float* gam; const float* bet; short* out;
  if (row < 4096) { in = in1; gam = g1; bet = b1; out = o1; }
  else { row -= 4096; in = in2; gam = g2; bet = b2; out = o2; }
  const float* r = in + row*1536;
  const int tid = threadIdx.x;
  float v[6], s = 0.f, s2 = 0.f;
#pragma unroll
  for (int i = 0; i < 6; i++) { v[i] = r[tid + i*256]; s += v[i]; s2 += v[i]*v[i]; }
  for (int m = 1; m < 64; m <<= 1) { s += __shfl_xor(s, m); s2 += __shfl_xor(s2, m); }
  __shared__ float rs[4], rs2[4];
  if ((tid & 63) == 0) { rs[tid>>6] = s; rs2[tid>>6] = s2; }
  __syncthreads();
  s = rs[0]+rs[1]+rs[2]+rs[3]; s2 = rs2[0]+rs2[1]+rs2[2]+rs2[3];
  const float mu  = s * (1.f/1536.f);
  const float var = s2 * (1.f/1536.f) - mu*mu;
  const float inv = rsqrtf(var + 1e-5f);
  short* o = out + row*1536;
#pragma unroll
  for (int i = 0; i < 6; i++) { int c = tid + i*256; o[c] = f2bf((v[i]-mu)*inv*gam[c] + bet[c]); }
}

// ============ fused scores -> BF16 logits =====
__global__ __launch_bounds__(256) void scores_k(
    const short* __restrict__ qb, const short* __restrict__ kb,
    const short* __restrict__ relq, const float* __restrict__ T,
    short* __restrict__ L)
{
  __shared__ __align__(16) short smem[21504];
  short* kt  = smem;                 // 64*72
  short* qt  = smem + 4608;          // 64*72
  short* rqt = smem + 4608;          // 128*72 (over qt)
  float* P   = (float*)(smem + 4608);// 64*132 f32 (over rqt)

  const int z = blockIdx.z, b = z >> 3, h = z & 7;
  const int j0 = blockIdx.x*64, i0 = blockIdx.y*64;
  const int tid = threadIdx.x, lane = tid & 63, wv = tid >> 6;
  const int fr = lane & 15, fq = lane >> 4;

  {
    const short* kg = kb + (size_t)(b*768  + j0)*512 + h*64;
    const short* qg = qb + (size_t)(b*1024 + i0)*512 + h*64;
    for (int c = tid; c < 512; c += 256) {
      const int r = c >> 3, ch = (c & 7)*8;
      *(s8v*)&kt[r*72 + ch] = *(const s8v*)&kg[(size_t)r*512 + ch];
      *(s8v*)&qt[r*72 + ch] = *(const s8v*)&qg[(size_t)r*512 + ch];
    }
  }
  __syncthreads();

  const int wi = (wv & 1)*32, wj = (wv >> 1)*32;
  f4v c2[2][2] = {};
#pragma unroll
  for (int ks = 0; ks < 2; ks++) {
    s8v aq[2], bk[2];
#pragma unroll
    for (int mi = 0; mi < 2; mi++) aq[mi] = *(const s8v*)&qt[(wi + mi*16 + fr)*72 + ks*32 + fq*8];
#pragma unroll
    for (int ni = 0; ni < 2; ni++) bk[ni] = *(const s8v*)&kt[(wj + ni*16 + fr)*72 + ks*32 + fq*8];
#pragma unroll
    for (int mi = 0; mi < 2; mi++)
#pragma unroll
      for (int ni = 0; ni < 2; ni++)
        c2[mi][ni] = __builtin_amdgcn_mfma_f32_16x16x32_bf16(aq[mi], bk[ni], c2[mi][ni], 0, 0, 0);
  }
  __syncthreads();

  const int nbase = 704 + i0 - j0;
  {
    const short* rg = relq + (size_t)nbase*512 + h*64;
    for (int c = tid; c < 1024; c += 256) {
      const int r = c >> 3, ch = (c & 7)*8;
      *(s8v*)&rqt[r*72 + ch] = *(const s8v*)&rg[(size_t)r*512 + ch];
    }
  }
  __syncthreads();

  const int wj2 = (wv & 1)*32, wn2 = (wv >> 1)*64;
  f4v pr[2][4] = {};
#pragma unroll
  for (int ks = 0; ks < 2; ks++) {
    s8v a2[2], b2[4];
#pragma unroll
    for (int mi = 0; mi < 2; mi++) a2[mi] = *(const s8v*)&kt[(wj2 + mi*16 + fr)*72 + ks*32 + fq*8];
#pragma unroll
    for (int ni = 0; ni < 4; ni++) b2[ni] = *(const s8v*)&rqt[(wn2 + ni*16 + fr)*72 + ks*32 + fq*8];
#pragma unroll
    for (int mi = 0; mi < 2; mi++)
#pragma unroll
      for (int ni = 0; ni < 4; ni++)
        pr[mi][ni] = __builtin_amdgcn_mfma_f32_16x16x32_bf16(a2[mi], b2[ni], pr[mi][ni], 0, 0, 0);
  }
  __syncthreads();

#pragma unroll
  for (int mi = 0; mi < 2; mi++)
#pragma unroll
    for (int ni = 0; ni < 4; ni++)
#pragma unroll
      for (int r = 0; r < 4; r++)
        P[(wj2 + mi*16 + fq*4 + r)*132 + wn2 + ni*16 + fr] = pr[mi][ni][r];
  __syncthreads();

  const float* Tt = T + h*2047 + nbase;
  short* Lb = L + ((size_t)z*1024 + i0)*768 + j0;
#pragma unroll
  for (int mi = 0; mi < 2; mi++)
#pragma unroll
    for (int ni = 0; ni < 2; ni++)
#pragma unroll
      for (int r = 0; r < 4; r++) {
        const int il = wi + mi*16 + fq*4 + r;
        const int jl = wj + ni*16 + fr;
        const int nl = 63 + il - jl;
        Lb[(size_t)il*768 + jl] = f2bf(c2[mi][ni][r] + 0.125f*P[jl*132 + nl] + Tt[nl]);
      }
}

// ============ softmax2d: bf16 logits -> attnb (row-major) + attnT (transposed) ============
__global__ __launch_bounds__(256) void softmax2d(const short* __restrict__ L,
    short* __restrict__ attnb, short* __restrict__ attnT)
{
  __shared__ __align__(16) short pt[32*776];    // 49,664 B; stride 776
  const int ic = blockIdx.x, z = blockIdx.y;
  const int t = threadIdx.x, wv = t >> 6, lane = t & 63;
  const int rl = wv*8 + (lane >> 3);            // local row 0..31
  const int cs = (lane & 7)*96;                 // col segment start
  const size_t rowg = ((size_t)z*1024 + ic*32 + rl)*768;

  s8v v[12];
#pragma unroll
  for (int k = 0; k < 12; k++) v[k] = *(const s8v*)&L[rowg + cs + k*8];

  float mx = -1e30f;
#pragma unroll
  for (int k = 0; k < 12; k++)
#pragma unroll
    for (int e = 0; e < 8; e++) mx = fmaxf(mx, bf2f(v[k][e]));
  mx = fmaxf(mx, __shfl_xor(mx, 1));
  mx = fmaxf(mx, __shfl_xor(mx, 2));
  mx = fmaxf(mx, __shfl_xor(mx, 4));

  float s = 0.f;
#pragma unroll
  for (int k = 0; k < 12; k++)
#pragma unroll
    for (int e = 0; e < 8; e++) s += __expf(bf2f(v[k][e]) - mx);
  s += __shfl_xor(s, 1);
  s += __shfl_xor(s, 2);
  s += __shfl_xor(s, 4);
  const float inv = 1.f / s;

  short* ab = attnb + rowg;
#pragma unroll
  for (int k = 0; k < 12; k++) {
    s8v o;
#pragma unroll
    for (int e = 0; e < 8; e++) o[e] = f2bf(__expf(bf2f(v[k][e]) - mx) * inv);
    *(s8v*)&ab[cs + k*8] = o;
    *(s8v*)&pt[rl*776 + cs + k*8] = o;
  }
  __syncthreads();

  short* aT = attnT + (size_t)z*786432 + (size_t)ic*32;
  const int i4 = (lane & 7)*4, jb = lane >> 3;
  for (int jj = 0; jj < 24; jj++) {
    const int j = wv*192 + jj*8 + jb;
    s4v o;
#pragma unroll
    for (int e = 0; e < 4; e++) o[e] = pt[(i4 + e)*776 + j];
    *(s4v*)&aT[(size_t)j*1024 + i4] = o;
  }
}

// ======================= host =======================
static void gemm(hipStream_t st, const short* A, const short* B, float* Cf, short* Cb,
                 const float* bias, const float* resid,
                 int M, int N, int K, int lda, int ldb, int ldc,
                 int batches = 1,
                 long long sAo = 0, long long sAi = 0, long long sBo = 0, long long sBi = 0,
                 long long sCo = 0, long long sCi = 0, float alpha = 1.f, int relu = 0)
{
  dim3 g((N + 127)/128, (M + 127)/128, batches);
  gemm_bt<<<g, dim3(256), 0, st>>>(A, B, Cf, Cb, bias, resid, M, N, K, lda, ldb, ldc,
                                   sAo, sAi, sBo, sBi, sCo, sCi, alpha, relu);
}

static void g256_3(hipStream_t st,
    const short* A0, const short* B0, float* C0f, short* C0b, const float* bias0, const float* res0,
    int M0, int N0, float al0,
    const short* A1, const short* B1, float* C1f, short* C1b, const float* bias1, const float* res1,
    int M1, int N1, float al1,
    const short* A2, const short* B2, float* C2f, short* C2b, const float* bias2, const float* res2,
    int M2, int N2, float al2,
    int K, int relu)
{
  const int nbm0 = M0 >> 8, nb0 = nbm0*(N0 >> 8);
  const int nbm1 = M1 >> 8, nb1 = nbm1*(N1 >> 8);
  const int nbm2 = M2 >> 8, nb2 = M2 ? nbm2*(N2 >> 8) : 0;
  gemm256<<<dim3(nb0 + nb1 + nb2), dim3(512), 0, st>>>(
      A0, B0, C0f, C0b, bias0, res0, nb0, nbm0, N0, al0,
      A1, B1, C1f, C1b, bias1, res1, nb0 + nb1, nbm1, N1, al1,
      A2, B2, C2f, C2b, bias2, res2, nbm2, N2, al2, K, relu);
}

static void g256(hipStream_t st,
    const short* A0, const short* B0, float* C0f, short* C0b, const float* bias0, const float* res0,
    int M0, int N0, float al0,
    const short* A1, const short* B1, float* C1f, short* C1b, const float* bias1, const float* res1,
    int M1, int N1, float al1,
    int K, int relu)
{
  g256_3(st, A0, B0, C0f, C0b, bias0, res0, M0, N0, al0,
         A1, B1, C1f, C1b, bias1, res1, M1, N1, al1,
         nullptr, nullptr, nullptr, nullptr, nullptr, nullptr, 0, 256, 1.f, K, relu);
}

extern "C" void kernel_launch(void* const* d_in, const int* in_sizes, int n_in,
                              void* d_out, int out_size, void* d_ws, size_t ws_size,
                              hipStream_t stream)
{
  (void)in_sizes; (void)n_in; (void)out_size; (void)ws_size;
  const float* x     = (const float*)d_in[0];
  const float* y0    = (const float*)d_in[1];
  const float* lnxg  = (const float*)d_in[3];
  const float* lnxb  = (const float*)d_in[4];
  const float* lnyg  = (const float*)d_in[5];
  const float* lnyb  = (const float*)d_in[6];
  const float* rpb   = (const float*)d_in[12];
  const float* bo1   = (const float*)d_in[14];
  const float* bo2   = (const float*)d_in[16];
  const float* fxg   = (const float*)d_in[17];
  const float* fxbb  = (const float*)d_in[18];
  const float* fxb1  = (const float*)d_in[20];
  const float* fxb2  = (const float*)d_in[22];
  const float* fyg   = (const float*)d_in[23];
  const float* fybb  = (const float*)d_in[24];
  const float* fyb1  = (const float*)d_in[26];
  const float* fyb2  = (const float*)d_in[28];

  char* base = (char*)d_ws;
  size_t off = 0;
  auto bump = [&](size_t b) -> char* { char* p = base + off; off += (b + 255) & ~(size_t)255; return p; };

  // ---- pooled weight buffers (bf16, transposed [N,K]) ----
  short* W_A  = (short*)bump(4718592);   // resT -> wo1T           (1536x1536)
  short* W_B  = (short*)bump(1572864);   // wqT                    (512x1536)
  short* W_B2 = (short*)bump(1572864);   // wkT                    (512x1536)
  short* W_C  = (short*)bump(4718592);   // wv1T -> wo2T           (1536x1536)
  short* W_D  = (short*)bump(196608);    // relT                   (512x192)
  short* W_E  = (short*)bump(9437184);   // fx1T                   (3072x1536)
  short* W_F  = (short*)bump(9437184);   // fx2T                   (1536x3072)

  char*  uB = bump(12582912);
  short* x1   = (short*)uB;
  short* v1T  = (short*)uB;
  char*  uC = bump(9437184);
  short* y1   = (short*)uC;
  short* out2 = (short*)uC;
  char*  uD = bump(9437184);
  short* y0b = (short*)uD;
  short* qb  = (short*)uD;
  short* kbB = (short*)(uD + 4194304);
  short* v2T = (short*)uD;
  float* Tbl   = (float*)bump(262016);
  short* posb  = (short*)bump(786048);
  short* relqb = (short*)bump(2096128);
  char*  uG = bump(12582912);
  short* v1b  = (short*)uG;
  short* out1 = (short*)uG;
  short* x4ln = (short*)uG;
  char*  uH = bump(9437184);   short* v2b = (short*)uH;  short* y4ln = (short*)uH;
  char*  uI = bump(100663296);
  short* wv2T    = (short*)uI;
  short* logits16 = (short*)uI;
  short* attnT   = (short*)(uI + 50331648);
  short* hx      = (short*)uI;
  short* hy      = (short*)(uI + 25165824);
  short* fy1T    = (short*)(uI + 46137344);
  short* fy2T    = (short*)(uI + 55574528);
  char*  U2 = bump(50331648);
  short* attnb = (short*)U2;
  float* y4    = (float*)U2;

  float* outx = (float*)d_out;
  float* outy = (float*)d_out + 6291456;
  float* x4  = outx;
  float* y_f = outy;

  auto addop = [&](WTB& b, int i, int idx, short* dst, int R, int C) {
    b.src[i] = (const float*)d_in[idx]; b.dst[i] = dst;
    b.R[i] = R; b.C[i] = C; b.start[i] = b.NT; b.NT += (R >> 5)*(C >> 5);
  };
  auto finwtb = [&](WTB& b, int n) {
    for (int i = n; i < 8; i++) { b.start[i] = 0x7fffffff; b.src[i] = nullptr; b.dst[i] = nullptr; b.R[i] = 32; b.C[i] = 32; }
  };

  // B1: all weights needed through v2qk + ffn-x
  WTB b1{}; b1.NT = 0;
  addop(b1, 0, 2,  W_A,  1536, 1536);   // res_w
  addop(b1, 1, 11, W_D,  192,  512);    // wrel
  addop(b1, 2, 9,  W_C,  1536, 1536);   // wv1
  addop(b1, 3, 10, wv2T, 1536, 1536);   // wv2
  addop(b1, 4, 7,  W_B,  1536, 512);    // wq
  addop(b1, 5, 8,  W_B2, 1536, 512);    // wk
  addop(b1, 6, 19, W_E,  1536, 3072);   // fx_w1
  addop(b1, 7, 21, W_F,  3072, 1536);   // fx_w2
  wtransN<<<dim3(b1.NT), dim3(32,8), 0, stream>>>(b1);

  // prep3: y0 -> bf16 | positional features | ln_x   (one launch)
  prep3<<<dim3(9216), dim3(256), 0, stream>>>(y0, y0b, posb, x, lnxg, lnxb, x1);
  // relq = pos @ wrel
  gemm(stream, posb, W_D, nullptr, relqb, nullptr, nullptr, 2047, 512, 192, 192, 192, 512);
  // launch1: res = y0@res_w -> y_f + v1 = x1@wv1
  g256(stream, y0b, W_A, y_f, nullptr, nullptr, nullptr, 3072, 1536, 1.f,
       x1, W_C, nullptr, v1b, nullptr, nullptr, 4096, 1536, 1.f, 1536, 0);
  // postl1: ln_y | B2 wtrans (wo1->W_A, wo2->W_C) | relbias -> Tbl   (one launch)
  WTB b2{}; b2.NT = 0;
  addop(b2, 0, 13, W_A, 1536, 1536);
  addop(b2, 1, 15, W_C, 1536, 1536);
  finwtb(b2, 2);
  postl1_k<<<dim3(3072 + b2.NT + 2047), dim3(256), 0, stream>>>(
      y_f, lnyg, lnyb, y1, b2, rpb, relqb, Tbl);
  // v2 + q + k
  g256_3(stream, y1, wv2T, nullptr, v2b, nullptr, nullptr, 3072, 1536, 1.f,
         x1, W_B, nullptr, qb, nullptr, nullptr, 4096, 512, 0.125f,
         y1, W_B2, nullptr, kbB, nullptr, nullptr, 3072, 512, 1.f, 1536, 0);
  // fused scores -> bf16 logits
  scores_k<<<dim3(12,16,32), 256, 0, stream>>>(qb, kbB, relqb, Tbl, logits16);
  // softmax2d -> attnb + attnT
  softmax2d<<<dim3(32,32), 256, 0, stream>>>(logits16, attnb, attnT);
  // btrans2: v1T (uB) + v2T (uD) in one launch
  btrans2<<<dim3(6,56,32), dim3(32,8), 0, stream>>>(v1b, v1T, v2b, v2T);
  // pv_k: out1 = attn@v2 (-> uG) and out2 = attn^T@v1 (-> uC) in one launch
  pv_k<<<dim3(2,14,32), 256, 0, stream>>>(attnb, v2T, out1, attnT, v1T, out2);
  // B3: fy1 -> fy1T, fy2 -> fy2T (uI attn regions dead)
  WTB b3{}; b3.NT = 0;
  addop(b3, 0, 25, fy1T, 1536, 3072);
  addop(b3, 1, 27, fy2T, 3072, 1536);
  finwtb(b3, 2);
  wtransN<<<dim3(b3.NT), dim3(32,8), 0, stream>>>(b3);
  // wo-pair: x4 = x + out1@wo1 + bo1 ; y4 = y + out2@wo2 + bo2
  g256(stream, out1, W_A, x4, nullptr, bo1, x, 4096, 1536, 1.f,
       out2, W_C, y4, nullptr, bo2, y_f, 3072, 1536, 1.f, 1536, 0);
  // merged FFN LayerNorms
  ln2_k<<<7168, 256, 0, stream>>>(x4, fxg, fxbb, x4ln, y4, fyg, fybb, y4ln);
  // ffn1: hidden = relu(ln @ w1 + b1)
  g256(stream, x4ln, W_E, nullptr, hx, fxb1, nullptr, 4096, 3072, 1.f,
       y4ln, fy1T, nullptr, hy, fyb1, nullptr, 3072, 3072, 1.f, 1536, 1);
  // ffn2: out = resid + h @ w2 + b2  (in-place on outx)
  g256(stream, hx, W_F, outx, nullptr, fxb2, x4, 4096, 1536, 1.f,
       hy, fy2T, outy, nullptr, fyb2, y4, 3072, 1536, 1.f, 3072, 0);
}

// Round 18
// 640.418 us; speedup vs baseline: 1.0598x; 1.0035x over previous
//
#include <hip/hip_runtime.h>
#include <stdint.h>
#include <math.h>

typedef __attribute__((ext_vector_type(8))) short s8v;
typedef __attribute__((ext_vector_type(4))) short s4v;
typedef __attribute__((ext_vector_type(4))) float f4v;

#define DEV static __device__ __forceinline__

DEV short f2bf(float f) {
  uint32_t u = __builtin_bit_cast(uint32_t, f);
  u += 0x7FFFu + ((u >> 16) & 1u);   // round-to-nearest-even
  return (short)(u >> 16);
}
DEV float bf2f(short s) {
  uint32_t u = ((uint32_t)(uint16_t)s) << 16;
  return __builtin_bit_cast(float, u);
}

#define GLD16(g, l) __builtin_amdgcn_global_load_lds( \
    (const __attribute__((address_space(1))) void*)(g), \
    (__attribute__((address_space(3))) void*)(l), 16, 0, 0)

// ================= 128x128 GEMM (m97 structure) for small/odd/batched shapes =========
__global__ __launch_bounds__(256) void gemm_bt(
    const short* __restrict__ A, const short* __restrict__ B,
    float* Cf, short* Cb,
    const float* __restrict__ bias, const float* resid,
    int M, int N, int K, int lda, int ldb, int ldc,
    long long sAo, long long sAi, long long sBo, long long sBi,
    long long sCo, long long sCi, float alpha, int relu)
{
  __shared__ __align__(16) short lA[128*32];
  __shared__ __align__(16) short lB[128*32];
  const int z = blockIdx.z, zo = z >> 3, zi = z & 7;
  const short* Ab = A + zo*sAo + zi*sAi;
  const short* Bb = B + zo*sBo + zi*sBi;
  const long long cOff = zo*sCo + zi*sCi;

  const int m0 = blockIdx.y*128, n0 = blockIdx.x*128;
  const int tid = threadIdx.x, lane = tid & 63, wv = tid >> 6;
  const int wm = (wv >> 1)*64, wn = (wv & 1)*64;
  const int fr = lane & 15, fq = lane >> 4;

  f4v acc[4][4] = {};

  const int rA0 = min(m0 + (tid >> 2), M - 1);
  const int rA1 = min(m0 + 64 + (tid >> 2), M - 1);
  const int rB0 = min(n0 + (tid >> 2), N - 1);
  const int rB1 = min(n0 + 64 + (tid >> 2), N - 1);
  const int pc = (tid & 3) * 8;
  const short* gA0 = Ab + (size_t)rA0*lda + pc;
  const short* gA1 = Ab + (size_t)rA1*lda + pc;
  const short* gB0 = Bb + (size_t)rB0*ldb + pc;
  const short* gB1 = Bb + (size_t)rB1*ldb + pc;
  short* dA0 = lA + (wv*64)*8;
  short* dA1 = lA + (256 + wv*64)*8;
  short* dB0 = lB + (wv*64)*8;
  short* dB1 = lB + (256 + wv*64)*8;

  for (int k0 = 0; k0 < K; k0 += 32) {
    GLD16(gA0 + k0, dA0);
    GLD16(gA1 + k0, dA1);
    GLD16(gB0 + k0, dB0);
    GLD16(gB1 + k0, dB1);
    __syncthreads();
    s8v af[4], bg[4];
#pragma unroll
    for (int i = 0; i < 4; i++) {
      af[i] = *(const s8v*)&lA[(wm + i*16 + fr)*32 + fq*8];
      bg[i] = *(const s8v*)&lB[(wn + i*16 + fr)*32 + fq*8];
    }
#pragma unroll
    for (int mi = 0; mi < 4; mi++)
#pragma unroll
      for (int ni = 0; ni < 4; ni++)
        acc[mi][ni] = __builtin_amdgcn_mfma_f32_16x16x32_bf16(af[mi], bg[ni], acc[mi][ni], 0, 0, 0);
    __syncthreads();
  }

#pragma unroll
  for (int mi = 0; mi < 4; mi++) {
    const int row = m0 + wm + mi*16 + fq*4;
#pragma unroll
    for (int ni = 0; ni < 4; ni++) {
      const int col = n0 + wn + ni*16 + fr;
      if (col >= N) continue;
      const float bv = bias ? bias[col] : 0.f;
#pragma unroll
      for (int r = 0; r < 4; r++) {
        if (row + r >= M) continue;
        float v = acc[mi][ni][r] * alpha + bv;
        const long long idx = cOff + (long long)(row + r)*ldc + col;
        if (resid) v += resid[idx];
        if (relu) v = fmaxf(v, 0.f);
        if (Cf) Cf[idx] = v;
        if (Cb) Cb[idx] = f2bf(v);
      }
    }
  }
}

// ================= pv_k: out1 = attn@v2 and out2 = attn^T@v1 in ONE launch ======
__global__ __launch_bounds__(256) void pv_k(
    const short* __restrict__ attnb, const short* __restrict__ v2T, short* __restrict__ out1,
    const short* __restrict__ attnT, const short* __restrict__ v1T, short* __restrict__ out2)
{
  __shared__ __align__(16) short lA[128*32];
  __shared__ __align__(16) short lB[128*32];
  const int z = blockIdx.z, b = z >> 3, h = z & 7;
  const short* A; const short* B; short* C; int M, K, lda, m0;
  if (blockIdx.y < 8) {
    A = attnb + (size_t)z*786432; B = v2T + (size_t)z*147456;
    C = out1 + ((size_t)b*1024)*1536 + h*192;
    M = 1024; K = 768; lda = 768; m0 = blockIdx.y*128;
  } else {
    A = attnT + (size_t)z*786432; B = v1T + (size_t)z*196608;
    C = out2 + ((size_t)b*768)*1536 + h*192;
    M = 768; K = 1024; lda = 1024; m0 = (blockIdx.y - 8)*128;
  }
  const int N = 192, ldc = 1536, ldb = lda;
  const int n0 = blockIdx.x*128;
  const int tid = threadIdx.x, lane = tid & 63, wv = tid >> 6;
  const int wm = (wv >> 1)*64, wn = (wv & 1)*64;
  const int fr = lane & 15, fq = lane >> 4;

  f4v acc[4][4] = {};

  const int rA0 = m0 + (tid >> 2);
  const int rA1 = m0 + 64 + (tid >> 2);
  const int rB0 = min(n0 + (tid >> 2), N - 1);
  const int rB1 = min(n0 + 64 + (tid >> 2), N - 1);
  const int pc = (tid & 3) * 8;
  const short* gA0 = A + (size_t)rA0*lda + pc;
  const short* gA1 = A + (size_t)rA1*lda + pc;
  const short* gB0 = B + (size_t)rB0*ldb + pc;
  const short* gB1 = B + (size_t)rB1*ldb + pc;
  short* dA0 = lA + (wv*64)*8;
  short* dA1 = lA + (256 + wv*64)*8;
  short* dB0 = lB + (wv*64)*8;
  short* dB1 = lB + (256 + wv*64)*8;

  for (int k0 = 0; k0 < K; k0 += 32) {
    GLD16(gA0 + k0, dA0);
    GLD16(gA1 + k0, dA1);
    GLD16(gB0 + k0, dB0);
    GLD16(gB1 + k0, dB1);
    __syncthreads();
    s8v af[4], bg[4];
#pragma unroll
    for (int i = 0; i < 4; i++) {
      af[i] = *(const s8v*)&lA[(wm + i*16 + fr)*32 + fq*8];
      bg[i] = *(const s8v*)&lB[(wn + i*16 + fr)*32 + fq*8];
    }
#pragma unroll
    for (int mi = 0; mi < 4; mi++)
#pragma unroll
      for (int ni = 0; ni < 4; ni++)
        acc[mi][ni] = __builtin_amdgcn_mfma_f32_16x16x32_bf16(af[mi], bg[ni], acc[mi][ni], 0, 0, 0);
    __syncthreads();
  }

#pragma unroll
  for (int mi = 0; mi < 4; mi++) {
    const int row = m0 + wm + mi*16 + fq*4;
#pragma unroll
    for (int ni = 0; ni < 4; ni++) {
      const int col = n0 + wn + ni*16 + fr;
      if (col >= N) continue;
#pragma unroll
      for (int r = 0; r < 4; r++)
        C[(size_t)(row + r)*ldc + col] = f2bf(acc[mi][ni][r]);
    }
  }
}

// ================= 256x256 8-phase GEMM (r6 single-barrier schedule) ======
#define ST_A(buf, ks, tt) do { const int ko = ((tt)<<6) + ((ks)<<5); \
    GLD16(gA0 + ko, ldA + ((buf)*2+(ks))*8192); \
    GLD16(gA1 + ko, ldA + ((buf)*2+(ks))*8192 + 4096); } while(0)
#define ST_B(buf, ks, tt) do { const int ko = ((tt)<<6) + ((ks)<<5); \
    GLD16(gB0 + ko, ldB + ((buf)*2+(ks))*8192); \
    GLD16(gB1 + ko, ldB + ((buf)*2+(ks))*8192 + 4096); } while(0)

#define PH256(buf, ks, mig, READB, DOWAIT, ...) do { \
    s8v av[4]; \
    const int rb = ((buf)*2+(ks))*8192; \
    _Pragma("unroll") for (int q2 = 0; q2 < 4; q2++) av[q2] = *(const s8v*)&smem[rb + aoff[(mig)*4+q2]]; \
    if (READB) { _Pragma("unroll") for (int q2 = 0; q2 < 4; q2++) bv[q2] = *(const s8v*)&smem[32768 + rb + boff[q2]]; } \
    __VA_ARGS__; \
    if (DOWAIT == 1) asm volatile("s_waitcnt vmcnt(6)" ::: "memory"); \
    if (DOWAIT == 2) asm volatile("s_waitcnt vmcnt(0)" ::: "memory"); \
    __builtin_amdgcn_s_barrier(); \
    asm volatile("s_waitcnt lgkmcnt(0)" ::: "memory"); \
    __builtin_amdgcn_s_setprio(1); \
    _Pragma("unroll") for (int q2 = 0; q2 < 4; q2++) \
      _Pragma("unroll") for (int u2 = 0; u2 < 4; u2++) \
        acc[(mig)*4+q2][u2] = __builtin_amdgcn_mfma_f32_16x16x32_bf16(av[q2], bv[u2], acc[(mig)*4+q2][u2], 0, 0, 0); \
    __builtin_amdgcn_s_setprio(0); \
  } while(0)

__global__ __launch_bounds__(512) void gemm256(
    const short* __restrict__ A0p, const short* __restrict__ B0p,
    float* C0f, short* C0b, const float* __restrict__ bias0, const float* res0,
    int nb0, int nbm0, int N0, float al0,
    const short* __restrict__ A1p, const short* __restrict__ B1p,
    float* C1f, short* C1b, const float* __restrict__ bias1, const float* res1,
    int nb01, int nbm1, int N1, float al1,
    const short* __restrict__ A2p, const short* __restrict__ B2p,
    float* C2f, short* C2b, const float* __restrict__ bias2, const float* res2,
    int nbm2, int N2, float al2,
    int K, int relu)
{
  __shared__ __align__(16) short smem[65536];   // 128 KiB
  const int total = gridDim.x;
  int bid = blockIdx.x;
  if ((total & 7) == 0) bid = (bid & 7)*(total >> 3) + (bid >> 3);   // bijective XCD swizzle
  const short* A; const short* B; float* Cf; short* Cb; const float* bias; const float* resid;
  int tile, nbm, N; float alpha;
  if (bid < nb0)       { A = A0p; B = B0p; Cf = C0f; Cb = C0b; bias = bias0; resid = res0;
                         tile = bid; nbm = nbm0; N = N0; alpha = al0; }
  else if (bid < nb01) { A = A1p; B = B1p; Cf = C1f; Cb = C1b; bias = bias1; resid = res1;
                         tile = bid - nb0; nbm = nbm1; N = N1; alpha = al1; }
  else                 { A = A2p; B = B2p; Cf = C2f; Cb = C2b; bias = bias2; resid = res2;
                         tile = bid - nb01; nbm = nbm2; N = N2; alpha = al2; }
  const int bm = tile % nbm, bn = tile / nbm;   // col-major: consecutive tiles share B panel
  const int m0 = bm << 8, n0 = bn << 8;
  const int t = threadIdx.x, lane = t & 63, w = t >> 6;
  const int wm = w >> 2, wn = w & 3;
  const int fr = lane & 15, fq = lane >> 4;
  const int ntk = K >> 6;                        // requires K % 128 == 0, K >= 256

  const int r0 = t >> 2, r1 = 128 + (t >> 2), gsw = t & 3;
  const int cs0 = (gsw ^ ((r0 >> 1) & 3)) << 3;
  const int cs1 = (gsw ^ ((r1 >> 1) & 3)) << 3;
  const short* gA0 = A + (size_t)(m0 + r0)*K + cs0;
  const short* gA1 = A + (size_t)(m0 + r1)*K + cs1;
  const short* gB0 = B + (size_t)(n0 + r0)*K + cs0;
  const short* gB1 = B + (size_t)(n0 + r1)*K + cs1;
  short* const ldA = smem + w*512;
  short* const ldB = smem + 32768 + w*512;

  int aoff[8], boff[4];
#pragma unroll
  for (int mi = 0; mi < 8; mi++) { const int r = wm*128 + mi*16 + fr; aoff[mi] = r*32 + ((fq ^ ((r >> 1) & 3)) << 3); }
#pragma unroll
  for (int ni = 0; ni < 4; ni++) { const int r = wn*64 + ni*16 + fr; boff[ni] = r*32 + ((fq ^ ((r >> 1) & 3)) << 3); }

  f4v acc[8][4] = {};
  s8v bv[4];

  ST_A(0,0,0); ST_B(0,0,0); ST_A(0,1,0); ST_B(0,1,0);
  ST_B(1,0,1); ST_A(1,0,1); ST_B(1,1,1);
  asm volatile("s_waitcnt vmcnt(6)" ::: "memory");
  __builtin_amdgcn_s_barrier();
  asm volatile("" ::: "memory");

  for (int it = 0, nit = (ntk >> 1) - 1; it < nit; ++it) {
    const int t1 = 2*it + 1, t2 = 2*it + 2, t3 = 2*it + 3;
    PH256(0,0,0, 1,0, ST_A(1,1,t1));   // ph1
    PH256(0,0,1, 0,0, ST_B(0,0,t2));   // ph2
    PH256(0,1,0, 1,0, ST_A(0,0,t2));   // ph3
    PH256(0,1,1, 0,1, ST_B(0,1,t2));   // ph4 + vmcnt(6)
    PH256(1,0,0, 1,0, ST_A(0,1,t2));   // ph5
    PH256(1,0,1, 0,0, ST_B(1,0,t3));   // ph6
    PH256(1,1,0, 1,0, ST_A(1,0,t3));   // ph7
    PH256(1,1,1, 0,1, ST_B(1,1,t3));   // ph8 + vmcnt(6)
  }
  PH256(0,0,0, 1,0, ST_A(1,1,ntk-1));
  PH256(0,0,1, 0,0, );
  PH256(0,1,0, 1,0, );
  PH256(0,1,1, 0,2, );                 // vmcnt(0): buf1 fully resident
  PH256(1,0,0, 1,0, );
  PH256(1,0,1, 0,0, );
  PH256(1,1,0, 1,0, );
  PH256(1,1,1, 0,0, );

#pragma unroll
  for (int mi = 0; mi < 8; mi++) {
    const int row = m0 + wm*128 + mi*16 + fq*4;
#pragma unroll
    for (int ni = 0; ni < 4; ni++) {
      const int col = n0 + wn*64 + ni*16 + fr;
      const float bvv = bias ? bias[col] : 0.f;
#pragma unroll
      for (int r = 0; r < 4; r++) {
        float v = acc[mi][ni][r]*alpha + bvv;
        const size_t idx = (size_t)(row + r)*N + col;
        if (resid) v += resid[idx];
        if (relu) v = fmaxf(v, 0.f);
        if (Cf) Cf[idx] = v;
        else Cb[idx] = f2bf(v);
      }
    }
  }
}

// ============ batched weight transpose: up to 8 f32[R,C] -> bf16[C,R], 1 tile/block ======
struct WTB {
  const float* src[8]; short* dst[8];
  int R[8], C[8], start[8];
  int NT;
};

__global__ __launch_bounds__(256) void wtransN(WTB b)
{
  __shared__ float t[32][33];
  const int id = blockIdx.x;
  if (id >= b.NT) return;
  int op = 0;
#pragma unroll
  for (int o = 1; o < 8; o++) if (id >= b.start[o]) op = o;
  const int loc = id - b.start[op];
  const int Cd = b.C[op], Rd = b.R[op];
  const int ncx = Cd >> 5;
  const int cx = (loc % ncx) << 5, ry = (loc / ncx) << 5;
  const float* s = b.src[op];
  short* d = b.dst[op];
  const int tx = threadIdx.x, ty = threadIdx.y;
#pragma unroll
  for (int k = 0; k < 4; k++)
    t[ty + k*8][tx] = s[(size_t)(ry + ty + k*8)*Cd + cx + tx];
  __syncthreads();
#pragma unroll
  for (int k = 0; k < 4; k++)
    d[(size_t)(cx + ty + k*8)*Rd + ry + tx] = f2bf(t[tx][ty + k*8]);
}

// ============ postl1_k: ln_y (0..3071) | B2 wtrans (next b.NT) | relbias (last 2047) ======
__global__ __launch_bounds__(256) void postl1_k(
    const float* __restrict__ in, const float* __restrict__ gam,
    const float* __restrict__ bet, short* __restrict__ out,
    WTB b,
    const float* __restrict__ rpb, const short* __restrict__ relq, float* __restrict__ T)
{
  __shared__ float tsh[32][33];
  __shared__ float rs[4], rs2[4];
  int bid = blockIdx.x;
  const int tid = threadIdx.x;
  if (bid < 3072) {
    const float* r = in + (long long)bid*1536;
    float v[6], s = 0.f, s2 = 0.f;
#pragma unroll
    for (int i = 0; i < 6; i++) { v[i] = r[tid + i*256]; s += v[i]; s2 += v[i]*v[i]; }
    for (int m = 1; m < 64; m <<= 1) { s += __shfl_xor(s, m); s2 += __shfl_xor(s2, m); }
    if ((tid & 63) == 0) { rs[tid>>6] = s; rs2[tid>>6] = s2; }
    __syncthreads();
    s = rs[0]+rs[1]+rs[2]+rs[3]; s2 = rs2[0]+rs2[1]+rs2[2]+rs2[3];
    const float mu  = s * (1.f/1536.f);
    const float var = s2 * (1.f/1536.f) - mu*mu;
    const float inv = rsqrtf(var + 1e-5f);
    short* o = out + (long long)bid*1536;
#pragma unroll
    for (int i = 0; i < 6; i++) { int c = tid + i*256; o[c] = f2bf((v[i]-mu)*inv*gam[c] + bet[c]); }
    return;
  }
  bid -= 3072;
  if (bid < b.NT) {
    int op = 0;
#pragma unroll
    for (int o = 1; o < 8; o++) if (bid >= b.start[o]) op = o;
    const int loc = bid - b.start[op];
    const int Cd = b.C[op], Rd = b.R[op];
    const int ncx = Cd >> 5;
    const int cx = (loc % ncx) << 5, ry = (loc / ncx) << 5;
    const float* s = b.src[op];
    short* d = b.dst[op];
    const int tx = tid & 31, ty = tid >> 5;
#pragma unroll
    for (int k = 0; k < 4; k++)
      tsh[ty + k*8][tx] = s[(size_t)(ry + ty + k*8)*Cd + cx + tx];
    __syncthreads();
#pragma unroll
    for (int k = 0; k < 4; k++)
      d[(size_t)(cx + ty + k*8)*Rd + ry + tx] = f2bf(tsh[tx][ty + k*8]);
    return;
  }
  bid -= b.NT;
  const int n = bid;
  const int h = tid >> 5, l = tid & 31;
  const int d = l*2;
  float s = rpb[h*64+d]   * bf2f(relq[(size_t)n*512 + h*64 + d])
          + rpb[h*64+d+1] * bf2f(relq[(size_t)n*512 + h*64 + d+1]);
  for (int m = 1; m < 32; m <<= 1) s += __shfl_xor(s, m);
  if (l == 0) T[h*2047 + n] = s;
}

// ============ btrans2: v1b -> v1T and v2b -> v2T in one launch ============
__global__ __launch_bounds__(256) void btrans2(
    const short* __restrict__ v1b, short* __restrict__ v1T,
    const short* __restrict__ v2b, short* __restrict__ v2T)
{
  __shared__ short t[32][33];
  const int z = blockIdx.z, b = z >> 3, h = z & 7;
  int y = blockIdx.y;
  const short* S; short* D; int ld_;
  if (y < 32) { S = v1b + ((size_t)b*1024)*1536 + h*192; D = v1T + (size_t)z*196608; ld_ = 1024; }
  else { y -= 32; S = v2b + ((size_t)b*768)*1536 + h*192; D = v2T + (size_t)z*147456; ld_ = 768; }
  const int c0 = blockIdx.x*32, r0 = y*32;
  const int tx = threadIdx.x, ty = threadIdx.y;
#pragma unroll
  for (int k = 0; k < 4; k++)
    t[ty + k*8][tx] = S[(size_t)(r0 + ty + k*8)*1536 + c0 + tx];
  __syncthreads();
#pragma unroll
  for (int k = 0; k < 4; k++)
    D[(size_t)(c0 + ty + k*8)*ld_ + r0 + tx] = t[tx][ty + k*8];
}

// ============ prep3: y0->bf16 (blocks 0..4607) | posemb (4608..5119) | ln_x (5120..9215) ====
__global__ __launch_bounds__(256) void prep3(
    const float* __restrict__ y0, short* __restrict__ y0b,
    short* __restrict__ posb,
    const float* __restrict__ x, const float* __restrict__ lnxg,
    const float* __restrict__ lnxb, short* __restrict__ x1)
{
  __shared__ float rs[4], rs2[4];
  int bid = blockIdx.x;
  const int tid = threadIdx.x;
  if (bid < 4608) {
    const long long i = ((long long)bid*256 + tid)*4;
    const float4 v = *(const float4*)(y0 + i);
    s4v o = { f2bf(v.x), f2bf(v.y), f2bf(v.z), f2bf(v.w) };
    *(s4v*)(y0b + i) = o;
    return;
  }
  bid -= 4608;
  if (bid < 512) {
    const int i = bid*4 + (tid >> 6);
    const int j = tid & 63;
    if (i >= 2047) return;
    const float dist = (float)(i - 1023);
    const float absd = fabsf(dist);
    float fe = 0.f, fc = 0.f, prob = 0.f;
    if (j < 32) {
      const float hl = exp2f(3.f + 7.f*(float)j/31.f);
      fe = expf(-0.6931471805599453f/hl * absd);
      const float width = exp2f((float)(j+1)) - 1.f;
      fc = (width > absd) ? 1.f : 0.f;
      const float m = 32.f*(float)(j+1);
      const float conc = (m/16.f)*(m/16.f);
      const float rate = m/256.f;
      const float logp = (absd > 0.f ? (conc-1.f)*logf(absd) : -INFINITY) - rate*absd;
      const float logn = lgammaf(conc) - conc*logf(rate);
      prob = expf(logp - logn) + 1e-8f;
    }
    float mx = prob;
    for (int m = 1; m < 32; m <<= 1) mx = fmaxf(mx, __shfl_xor(mx, m));
    if (j < 32) {
      const float fg = prob / mx;
      const float sg = dist > 0.f ? 1.f : (dist < 0.f ? -1.f : 0.f);
      const size_t base = (size_t)i*192;
      posb[base + j]       = f2bf(fe);
      posb[base + 32 + j]  = f2bf(fc);
      posb[base + 64 + j]  = f2bf(fg);
      posb[base + 96 + j]  = f2bf(sg*fe);
      posb[base + 128 + j] = f2bf(sg*fc);
      posb[base + 160 + j] = f2bf(sg*fg);
    }
    return;
  }
  bid -= 512;
  const long long row = bid;
  const float* r = x + row*1536;
  float v[6], s = 0.f, s2 = 0.f;
#pragma unroll
  for (int i = 0; i < 6; i++) { v[i] = r[tid + i*256]; s += v[i]; s2 += v[i]*v[i]; }
  for (int m = 1; m < 64; m <<= 1) { s += __shfl_xor(s, m); s2 += __shfl_xor(s2, m); }
  if ((tid & 63) == 0) { rs[tid>>6] = s; rs2[tid>>6] = s2; }
  __syncthreads();
  s = rs[0]+rs[1]+rs[2]+rs[3]; s2 = rs2[0]+rs2[1]+rs2[2]+rs2[3];
  const float mu  = s * (1.f/1536.f);
  const float var = s2 * (1.f/1536.f) - mu*mu;
  const float inv = rsqrtf(var + 1e-5f);
  short* o = x1 + row*1536;
#pragma unroll
  for (int i = 0; i < 6; i++) { int c = tid + i*256; o[c] = f2bf((v[i]-mu)*inv*lnxg[c] + lnxb[c]); }
}

// ============ ln2b3_k: B3 wtrans (0..b.NT-1) | both FFN layernorms (next 7168) ====
__global__ __launch_bounds__(256) void ln2b3_k(
    WTB b,
    const float* __restrict__ in1, const float* __restrict__ g1, const float* __restrict__ b1,
    short* __restrict__ o1,
    const float* __restrict__ in2, const float* __restrict__ g2, const float* __restrict__ b2,
    short* __restrict__ o2)
{
  __shared__ float tsh[32][33];
  __shared__ float rs[4], rs2[4];
  int bid = blockIdx.x;
  const int tid = threadIdx.x;
  if (bid < b.NT) {
    int op = 0;
#pragma unroll
    for (int o = 1; o < 8; o++) if (bid >= b.start[o]) op = o;
    const int loc = bid - b.start[op];
    const int Cd = b.C[op], Rd = b.R[op];
    const int ncx = Cd >> 5;
    const int cx = (loc % ncx) << 5, ry = (loc / ncx) << 5;
    const float* s = b.src[op];
    short* d = b.dst[op];
    const int tx = tid & 31, ty = tid >> 5;
#pragma unroll
    for (int k = 0; k < 4; k++)
      tsh[ty + k*8][tx] = s[(size_t)(ry + ty + k*8)*Cd + cx + tx];
    __syncthreads();
#pragma unroll
    for (int k = 0; k < 4; k++)
      d[(size_t)(cx + ty + k*8)*Rd + ry + tx] = f2bf(tsh[tx][ty + k*8]);
    return;
  }
  long long row = bid - b.NT;
  const float* in; const float* gam; const float* bet; short* out;
  if (row < 4096) { in = in1; gam = g1; bet = b1; out = o1; }
  else { row -= 4096; in = in2; gam = g2; bet = b2; out = o2; }
  const float* r = in + row*1536;
  float v[6], s = 0.f, s2 = 0.f;
#pragma unroll
  for (int i = 0; i < 6; i++) { v[i] = r[tid + i*256]; s += v[i]; s2 += v[i]*v[i]; }
  for (int m = 1; m < 64; m <<= 1) { s += __shfl_xor(s, m); s2 += __shfl_xor(s2, m); }
  if ((tid & 63) == 0) { rs[tid>>6] = s; rs2[tid>>6] = s2; }
  __syncthreads();
  s = rs[0]+rs[1]+rs[2]+rs[3]; s2 = rs2[0]+rs2[1]+rs2[2]+rs2[3];
  const float mu  = s * (1.f/1536.f);
  const float var = s2 * (1.f/1536.f) - mu*mu;
  const float inv = rsqrtf(var + 1e-5f);
  short* o = out + row*1536;
#pragma unroll
  for (int i = 0; i < 6; i++) { int c = tid + i*256; o[c] = f2bf((v[i]-mu)*inv*gam[c] + bet[c]); }
}

// ============ fused scores -> BF16 logits =====
__global__ __launch_bounds__(256) void scores_k(
    const short* __restrict__ qb, const short* __restrict__ kb,
    const short* __restrict__ relq, const float* __restrict__ T,
    short* __restrict__ L)
{
  __shared__ __align__(16) short smem[21504];
  short* kt  = smem;                 // 64*72
  short* qt  = smem + 4608;          // 64*72
  short* rqt = smem + 4608;          // 128*72 (over qt)
  float* P   = (float*)(smem + 4608);// 64*132 f32 (over rqt)

  const int z = blockIdx.z, b = z >> 3, h = z & 7;
  const int j0 = blockIdx.x*64, i0 = blockIdx.y*64;
  const int tid = threadIdx.x, lane = tid & 63, wv = tid >> 6;
  const int fr = lane & 15, fq = lane >> 4;

  {
    const short* kg = kb + (size_t)(b*768  + j0)*512 + h*64;
    const short* qg = qb + (size_t)(b*1024 + i0)*512 + h*64;
    for (int c = tid; c < 512; c += 256) {
      const int r = c >> 3, ch = (c & 7)*8;
      *(s8v*)&kt[r*72 + ch] = *(const s8v*)&kg[(size_t)r*512 + ch];
      *(s8v*)&qt[r*72 + ch] = *(const s8v*)&qg[(size_t)r*512 + ch];
    }
  }
  __syncthreads();

  const int wi = (wv & 1)*32, wj = (wv >> 1)*32;
  f4v c2[2][2] = {};
#pragma unroll
  for (int ks = 0; ks < 2; ks++) {
    s8v aq[2], bk[2];
#pragma unroll
    for (int mi = 0; mi < 2; mi++) aq[mi] = *(const s8v*)&qt[(wi + mi*16 + fr)*72 + ks*32 + fq*8];
#pragma unroll
    for (int ni = 0; ni < 2; ni++) bk[ni] = *(const s8v*)&kt[(wj + ni*16 + fr)*72 + ks*32 + fq*8];
#pragma unroll
    for (int mi = 0; mi < 2; mi++)
#pragma unroll
      for (int ni = 0; ni < 2; ni++)
        c2[mi][ni] = __builtin_amdgcn_mfma_f32_16x16x32_bf16(aq[mi], bk[ni], c2[mi][ni], 0, 0, 0);
  }
  __syncthreads();

  const int nbase = 704 + i0 - j0;
  {
    const short* rg = relq + (size_t)nbase*512 + h*64;
    for (int c = tid; c < 1024; c += 256) {
      const int r = c >> 3, ch = (c & 7)*8;
      *(s8v*)&rqt[r*72 + ch] = *(const s8v*)&rg[(size_t)r*512 + ch];
    }
  }
  __syncthreads();

  const int wj2 = (wv & 1)*32, wn2 = (wv >> 1)*64;
  f4v pr[2][4] = {};
#pragma unroll
  for (int ks = 0; ks < 2; ks++) {
    s8v a2[2], b2[4];
#pragma unroll
    for (int mi = 0; mi < 2; mi++) a2[mi] = *(const s8v*)&kt[(wj2 + mi*16 + fr)*72 + ks*32 + fq*8];
#pragma unroll
    for (int ni = 0; ni < 4; ni++) b2[ni] = *(const s8v*)&rqt[(wn2 + ni*16 + fr)*72 + ks*32 + fq*8];
#pragma unroll
    for (int mi = 0; mi < 2; mi++)
#pragma unroll
      for (int ni = 0; ni < 4; ni++)
        pr[mi][ni] = __builtin_amdgcn_mfma_f32_16x16x32_bf16(a2[mi], b2[ni], pr[mi][ni], 0, 0, 0);
  }
  __syncthreads();

#pragma unroll
  for (int mi = 0; mi < 2; mi++)
#pragma unroll
    for (int ni = 0; ni < 4; ni++)
#pragma unroll
      for (int r = 0; r < 4; r++)
        P[(wj2 + mi*16 + fq*4 + r)*132 + wn2 + ni*16 + fr] = pr[mi][ni][r];
  __syncthreads();

  const float* Tt = T + h*2047 + nbase;
  short* Lb = L + ((size_t)z*1024 + i0)*768 + j0;
#pragma unroll
  for (int mi = 0; mi < 2; mi++)
#pragma unroll
    for (int ni = 0; ni < 2; ni++)
#pragma unroll
      for (int r = 0; r < 4; r++) {
        const int il = wi + mi*16 + fq*4 + r;
        const int jl = wj + ni*16 + fr;
        const int nl = 63 + il - jl;
        Lb[(size_t)il*768 + jl] = f2bf(c2[mi][ni][r] + 0.125f*P[jl*132 + nl] + Tt[nl]);
      }
}

// ============ softmax2d: bf16 logits -> attnb (row-major) + attnT (transposed) ============
__global__ __launch_bounds__(256) void softmax2d(const short* __restrict__ L,
    short* __restrict__ attnb, short* __restrict__ attnT)
{
  __shared__ __align__(16) short pt[32*776];    // 49,664 B; stride 776
  const int ic = blockIdx.x, z = blockIdx.y;
  const int t = threadIdx.x, wv = t >> 6, lane = t & 63;
  const int rl = wv*8 + (lane >> 3);            // local row 0..31
  const int cs = (lane & 7)*96;                 // col segment start
  const size_t rowg = ((size_t)z*1024 + ic*32 + rl)*768;

  s8v v[12];
#pragma unroll
  for (int k = 0; k < 12; k++) v[k] = *(const s8v*)&L[rowg + cs + k*8];

  float mx = -1e30f;
#pragma unroll
  for (int k = 0; k < 12; k++)
#pragma unroll
    for (int e = 0; e < 8; e++) mx = fmaxf(mx, bf2f(v[k][e]));
  mx = fmaxf(mx, __shfl_xor(mx, 1));
  mx = fmaxf(mx, __shfl_xor(mx, 2));
  mx = fmaxf(mx, __shfl_xor(mx, 4));

  float s = 0.f;
#pragma unroll
  for (int k = 0; k < 12; k++)
#pragma unroll
    for (int e = 0; e < 8; e++) s += __expf(bf2f(v[k][e]) - mx);
  s += __shfl_xor(s, 1);
  s += __shfl_xor(s, 2);
  s += __shfl_xor(s, 4);
  const float inv = 1.f / s;

  short* ab = attnb + rowg;
#pragma unroll
  for (int k = 0; k < 12; k++) {
    s8v o;
#pragma unroll
    for (int e = 0; e < 8; e++) o[e] = f2bf(__expf(bf2f(v[k][e]) - mx) * inv);
    *(s8v*)&ab[cs + k*8] = o;
    *(s8v*)&pt[rl*776 + cs + k*8] = o;
  }
  __syncthreads();

  short* aT = attnT + (size_t)z*786432 + (size_t)ic*32;
  const int i4 = (lane & 7)*4, jb = lane >> 3;
  for (int jj = 0; jj < 24; jj++) {
    const int j = wv*192 + jj*8 + jb;
    s4v o;
#pragma unroll
    for (int e = 0; e < 4; e++) o[e] = pt[(i4 + e)*776 + j];
    *(s4v*)&aT[(size_t)j*1024 + i4] = o;
  }
}

// ======================= host =======================
static void gemm(hipStream_t st, const short* A, const short* B, float* Cf, short* Cb,
                 const float* bias, const float* resid,
                 int M, int N, int K, int lda, int ldb, int ldc,
                 int batches = 1,
                 long long sAo = 0, long long sAi = 0, long long sBo = 0, long long sBi = 0,
                 long long sCo = 0, long long sCi = 0, float alpha = 1.f, int relu = 0)
{
  dim3 g((N + 127)/128, (M + 127)/128, batches);
  gemm_bt<<<g, dim3(256), 0, st>>>(A, B, Cf, Cb, bias, resid, M, N, K, lda, ldb, ldc,
                                   sAo, sAi, sBo, sBi, sCo, sCi, alpha, relu);
}

static void g256_3(hipStream_t st,
    const short* A0, const short* B0, float* C0f, short* C0b, const float* bias0, const float* res0,
    int M0, int N0, float al0,
    const short* A1, const short* B1, float* C1f, short* C1b, const float* bias1, const float* res1,
    int M1, int N1, float al1,
    const short* A2, const short* B2, float* C2f, short* C2b, const float* bias2, const float* res2,
    int M2, int N2, float al2,
    int K, int relu)
{
  const int nbm0 = M0 >> 8, nb0 = nbm0*(N0 >> 8);
  const int nbm1 = M1 >> 8, nb1 = nbm1*(N1 >> 8);
  const int nbm2 = M2 >> 8, nb2 = M2 ? nbm2*(N2 >> 8) : 0;
  gemm256<<<dim3(nb0 + nb1 + nb2), dim3(512), 0, st>>>(
      A0, B0, C0f, C0b, bias0, res0, nb0, nbm0, N0, al0,
      A1, B1, C1f, C1b, bias1, res1, nb0 + nb1, nbm1, N1, al1,
      A2, B2, C2f, C2b, bias2, res2, nbm2, N2, al2, K, relu);
}

static void g256(hipStream_t st,
    const short* A0, const short* B0, float* C0f, short* C0b, const float* bias0, const float* res0,
    int M0, int N0, float al0,
    const short* A1, const short* B1, float* C1f, short* C1b, const float* bias1, const float* res1,
    int M1, int N1, float al1,
    int K, int relu)
{
  g256_3(st, A0, B0, C0f, C0b, bias0, res0, M0, N0, al0,
         A1, B1, C1f, C1b, bias1, res1, M1, N1, al1,
         nullptr, nullptr, nullptr, nullptr, nullptr, nullptr, 0, 256, 1.f, K, relu);
}

extern "C" void kernel_launch(void* const* d_in, const int* in_sizes, int n_in,
                              void* d_out, int out_size, void* d_ws, size_t ws_size,
                              hipStream_t stream)
{
  (void)in_sizes; (void)n_in; (void)out_size; (void)ws_size;
  const float* x     = (const float*)d_in[0];
  const float* y0    = (const float*)d_in[1];
  const float* lnxg  = (const float*)d_in[3];
  const float* lnxb  = (const float*)d_in[4];
  const float* lnyg  = (const float*)d_in[5];
  const float* lnyb  = (const float*)d_in[6];
  const float* rpb   = (const float*)d_in[12];
  const float* bo1   = (const float*)d_in[14];
  const float* bo2   = (const float*)d_in[16];
  const float* fxg   = (const float*)d_in[17];
  const float* fxbb  = (const float*)d_in[18];
  const float* fxb1  = (const float*)d_in[20];
  const float* fxb2  = (const float*)d_in[22];
  const float* fyg   = (const float*)d_in[23];
  const float* fybb  = (const float*)d_in[24];
  const float* fyb1  = (const float*)d_in[26];
  const float* fyb2  = (const float*)d_in[28];

  char* base = (char*)d_ws;
  size_t off = 0;
  auto bump = [&](size_t b) -> char* { char* p = base + off; off += (b + 255) & ~(size_t)255; return p; };

  // ---- pooled weight buffers (bf16, transposed [N,K]) ----
  short* W_A  = (short*)bump(4718592);   // resT -> wo1T           (1536x1536)
  short* W_B  = (short*)bump(1572864);   // wqT                    (512x1536)
  short* W_B2 = (short*)bump(1572864);   // wkT                    (512x1536)
  short* W_C  = (short*)bump(4718592);   // wv1T -> wo2T           (1536x1536)
  short* W_D  = (short*)bump(196608);    // relT                   (512x192)
  short* W_E  = (short*)bump(9437184);   // fx1T                   (3072x1536)
  short* W_F  = (short*)bump(9437184);   // fx2T                   (1536x3072)

  char*  uB = bump(12582912);
  short* x1   = (short*)uB;
  short* v1T  = (short*)uB;
  char*  uC = bump(9437184);
  short* y1   = (short*)uC;
  short* out2 = (short*)uC;
  char*  uD = bump(9437184);
  short* y0b = (short*)uD;
  short* qb  = (short*)uD;
  short* kbB = (short*)(uD + 4194304);
  short* v2T = (short*)uD;
  float* Tbl   = (float*)bump(262016);
  short* posb  = (short*)bump(786048);
  short* relqb = (short*)bump(2096128);
  char*  uG = bump(12582912);
  short* v1b  = (short*)uG;
  short* out1 = (short*)uG;
  short* x4ln = (short*)uG;
  char*  uH = bump(9437184);   short* v2b = (short*)uH;  short* y4ln = (short*)uH;
  char*  uI = bump(100663296);
  short* wv2T    = (short*)uI;
  short* logits16 = (short*)uI;
  short* attnT   = (short*)(uI + 50331648);
  short* hx      = (short*)uI;
  short* hy      = (short*)(uI + 25165824);
  short* fy1T    = (short*)(uI + 46137344);
  short* fy2T    = (short*)(uI + 55574528);
  char*  U2 = bump(50331648);
  short* attnb = (short*)U2;
  float* y4    = (float*)U2;

  float* outx = (float*)d_out;
  float* outy = (float*)d_out + 6291456;
  float* x4  = outx;
  float* y_f = outy;

  auto addop = [&](WTB& b, int i, int idx, short* dst, int R, int C) {
    b.src[i] = (const float*)d_in[idx]; b.dst[i] = dst;
    b.R[i] = R; b.C[i] = C; b.start[i] = b.NT; b.NT += (R >> 5)*(C >> 5);
  };
  auto finwtb = [&](WTB& b, int n) {
    for (int i = n; i < 8; i++) { b.start[i] = 0x7fffffff; b.src[i] = nullptr; b.dst[i] = nullptr; b.R[i] = 32; b.C[i] = 32; }
  };

  // B1: all weights needed through v2qk + ffn-x
  WTB b1{}; b1.NT = 0;
  addop(b1, 0, 2,  W_A,  1536, 1536);   // res_w
  addop(b1, 1, 11, W_D,  192,  512);    // wrel
  addop(b1, 2, 9,  W_C,  1536, 1536);   // wv1
  addop(b1, 3, 10, wv2T, 1536, 1536);   // wv2
  addop(b1, 4, 7,  W_B,  1536, 512);    // wq
  addop(b1, 5, 8,  W_B2, 1536, 512);    // wk
  addop(b1, 6, 19, W_E,  1536, 3072);   // fx_w1
  addop(b1, 7, 21, W_F,  3072, 1536);   // fx_w2
  wtransN<<<dim3(b1.NT), dim3(32,8), 0, stream>>>(b1);

  // prep3: y0 -> bf16 | positional features | ln_x   (one launch)
  prep3<<<dim3(9216), dim3(256), 0, stream>>>(y0, y0b, posb, x, lnxg, lnxb, x1);
  // relq = pos @ wrel
  gemm(stream, posb, W_D, nullptr, relqb, nullptr, nullptr, 2047, 512, 192, 192, 192, 512);
  // launch1: res = y0@res_w -> y_f + v1 = x1@wv1
  g256(stream, y0b, W_A, y_f, nullptr, nullptr, nullptr, 3072, 1536, 1.f,
       x1, W_C, nullptr, v1b, nullptr, nullptr, 4096, 1536, 1.f, 1536, 0);
  // postl1: ln_y | B2 wtrans (wo1->W_A, wo2->W_C) | relbias -> Tbl   (one launch)
  WTB b2{}; b2.NT = 0;
  addop(b2, 0, 13, W_A, 1536, 1536);
  addop(b2, 1, 15, W_C, 1536, 1536);
  finwtb(b2, 2);
  postl1_k<<<dim3(3072 + b2.NT + 2047), dim3(256), 0, stream>>>(
      y_f, lnyg, lnyb, y1, b2, rpb, relqb, Tbl);
  // v2 + q + k
  g256_3(stream, y1, wv2T, nullptr, v2b, nullptr, nullptr, 3072, 1536, 1.f,
         x1, W_B, nullptr, qb, nullptr, nullptr, 4096, 512, 0.125f,
         y1, W_B2, nullptr, kbB, nullptr, nullptr, 3072, 512, 1.f, 1536, 0);
  // fused scores -> bf16 logits
  scores_k<<<dim3(12,16,32), 256, 0, stream>>>(qb, kbB, relqb, Tbl, logits16);
  // softmax2d -> attnb + attnT
  softmax2d<<<dim3(32,32), 256, 0, stream>>>(logits16, attnb, attnT);
  // btrans2: v1T (uB) + v2T (uD) in one launch
  btrans2<<<dim3(6,56,32), dim3(32,8), 0, stream>>>(v1b, v1T, v2b, v2T);
  // pv_k: out1 = attn@v2 (-> uG) and out2 = attn^T@v1 (-> uC) in one launch
  pv_k<<<dim3(2,14,32), 256, 0, stream>>>(attnb, v2T, out1, attnT, v1T, out2);
  // wo-pair: x4 = x + out1@wo1 + bo1 ; y4 = y + out2@wo2 + bo2
  g256(stream, out1, W_A, x4, nullptr, bo1, x, 4096, 1536, 1.f,
       out2, W_C, y4, nullptr, bo2, y_f, 3072, 1536, 1.f, 1536, 0);
  // ln2b3: B3 wtrans (fy1 -> fy1T, fy2 -> fy2T; uI attn regions dead) | FFN LayerNorms
  WTB b3{}; b3.NT = 0;
  addop(b3, 0, 25, fy1T, 1536, 3072);
  addop(b3, 1, 27, fy2T, 3072, 1536);
  finwtb(b3, 2);
  ln2b3_k<<<dim3(b3.NT + 7168), dim3(256), 0, stream>>>(
      b3, x4, fxg, fxbb, x4ln, y4, fyg, fybb, y4ln);
  // ffn1: hidden = relu(ln @ w1 + b1)
  g256(stream, x4ln, W_E, nullptr, hx, fxb1, nullptr, 4096, 3072, 1.f,
       y4ln, fy1T, nullptr, hy, fyb1, nullptr, 3072, 3072, 1.f, 1536, 1);
  // ffn2: out = resid + h @ w2 + b2  (in-place on outx)
  g256(stream, hx, W_F, outx, nullptr, fxb2, x4, 4096, 1536, 1.f,
       hy, fy2T, outy, nullptr, fyb2, y4, 3072, 1536, 1.f, 3072, 0);
}